// Round 2
// baseline (5354.123 us; speedup 1.0000x reference)
//
#include <hip/hip_runtime.h>
#include <cstdint>
#include <cstddef>

// Sizes (fixed by problem, but N/E/G derived at launch)
static constexpr int HD = 200;   // hidden
static constexpr int NH = 8;     // heads
static constexpr int CD = 25;    // per-head dim
static constexpr int NL = 4;     // layers

// ---------------- CSR build ----------------
__global__ __launch_bounds__(256) void k_hist(const int* __restrict__ dst, int* __restrict__ cnt, int E) {
  int e = blockIdx.x * 256 + threadIdx.x;
  if (e < E) atomicAdd(&cnt[dst[e]], 1);
}

__global__ __launch_bounds__(256) void k_scan1(const int* __restrict__ cnt, int* __restrict__ off,
                                               int* __restrict__ partial, int N) {
  __shared__ int sm[256];
  int t = threadIdx.x, i = blockIdx.x * 256 + t;
  int v = (i < N) ? cnt[i] : 0;
  sm[t] = v; __syncthreads();
  for (int o = 1; o < 256; o <<= 1) {
    int add = (t >= o) ? sm[t - o] : 0;
    __syncthreads();
    sm[t] += add;
    __syncthreads();
  }
  if (i < N) off[i] = sm[t] - v;            // exclusive
  if (t == 255) partial[blockIdx.x] = sm[255];
}

__global__ __launch_bounds__(512) void k_scan2(int* __restrict__ partial, int nb, int* __restrict__ off, int N) {
  __shared__ int sm[512];
  int t = threadIdx.x;
  int v = (t < nb) ? partial[t] : 0;
  sm[t] = v; __syncthreads();
  for (int o = 1; o < 512; o <<= 1) {
    int add = (t >= o) ? sm[t - o] : 0;
    __syncthreads();
    sm[t] += add;
    __syncthreads();
  }
  if (t < nb) partial[t] = sm[t] - v;       // exclusive block offsets
  if (t == 511) off[N] = sm[511];           // total == E
}

__global__ __launch_bounds__(256) void k_scan3(int* __restrict__ off, const int* __restrict__ partial, int N) {
  int i = blockIdx.x * 256 + threadIdx.x;
  if (i < N) off[i] += partial[i >> 8];
}

__global__ __launch_bounds__(256) void k_scatter(const int* __restrict__ dst, const int* __restrict__ off,
                                                 int* __restrict__ cur, int* __restrict__ eid, int E) {
  int e = blockIdx.x * 256 + threadIdx.x;
  if (e < E) {
    int d = dst[e];
    int p = atomicAdd(&cur[d], 1);
    eid[off[d] + p] = e;
  }
}

// sort each node's edge list ascending -> deterministic float accumulation order everywhere downstream
__global__ __launch_bounds__(256) void k_sort(const int* __restrict__ off, int* __restrict__ eid, int N) {
  int n = blockIdx.x * 256 + threadIdx.x;
  if (n >= N) return;
  int o0 = off[n], o1 = off[n + 1];
  for (int i = o0 + 1; i < o1; ++i) {
    int v = eid[i]; int j = i - 1;
    while (j >= o0 && eid[j] > v) { eid[j + 1] = eid[j]; --j; }
    eid[j + 1] = v;
  }
}

// ---------------- edge-attention precompute (algebraic reductions) ----------------
__global__ __launch_bounds__(128) void k_meanea(const float* __restrict__ ea, const int* __restrict__ off,
                                                const int* __restrict__ eid, float* __restrict__ mea, int N) {
  int n = blockIdx.x * 128 + threadIdx.x;
  if (n >= N) return;
  int o0 = off[n], o1 = off[n + 1];
  float s0 = 0, s1 = 0, s2 = 0, s3 = 0, s4 = 0, s5 = 0;
  for (int p = o0; p < o1; ++p) {
    const float* r = ea + (size_t)eid[p] * 6;
    s0 += r[0]; s1 += r[1]; s2 += r[2]; s3 += r[3]; s4 += r[4]; s5 += r[5];
  }
  float inv = (o1 > o0) ? 1.f / (float)(o1 - o0) : 0.f;
  float* m = mea + (size_t)n * 6;
  m[0] = s0 * inv; m[1] = s1 * inv; m[2] = s2 * inv; m[3] = s3 * inv; m[4] = s4 * inv; m[5] = s5 * inv;
}

// w_e[l][k][h] = sum_c lin_edge_w[l][k][h*25+c] * att_edge[l][h][c]
__global__ __launch_bounds__(256) void k_we(const float* __restrict__ lew, const float* __restrict__ ae,
                                            float* __restrict__ we) {
  int tid = blockIdx.x * 256 + threadIdx.x;
  if (tid >= NL * HD * 8) return;
  int l = tid / (HD * 8); int r = tid % (HD * 8); int k = r >> 3; int hh = r & 7;
  const float* W = lew + (size_t)l * HD * HD + (size_t)k * HD + hh * CD;
  const float* a = ae + l * NH * CD + hh * CD;
  float s = 0.f;
#pragma unroll
  for (int c = 0; c < CD; ++c) s += W[c] * a[c];
  we[tid] = s;   // layout l*1600 + k*8 + hh
}

// M[l][f][h] = sum_k edge_emb_w[f][k] * w_e[l][k][h];  cvec[l][h] = sum_k edge_emb_b[k]*w_e[l][k][h]
__global__ __launch_bounds__(256) void k_M(const float* __restrict__ ew, const float* __restrict__ eb,
                                           const float* __restrict__ we, float* __restrict__ Mm,
                                           float* __restrict__ cv) {
  int tid = threadIdx.x;
  if (tid < NL * 6 * 8) {
    int l = tid / 48, r = tid % 48, f = r / 8, hh = r % 8;
    float s = 0.f;
    for (int k = 0; k < HD; ++k) s += ew[f * HD + k] * we[l * 1600 + k * 8 + hh];
    Mm[tid] = s;   // l*48 + f*8 + hh
  } else if (tid < NL * 6 * 8 + NL * 8) {
    int u = tid - NL * 6 * 8, l = u / 8, hh = u % 8;
    float s = 0.f;
    for (int k = 0; k < HD; ++k) s += eb[k] * we[l * 1600 + k * 8 + hh];
    cv[u] = s;
  }
}

// a_e for real edges, all layers: ae[l][e][h] = edge_attr[e] . M[l][:,h] + cvec[l][h]
__global__ __launch_bounds__(256) void k_ae_edge(const float* __restrict__ ea, const float* __restrict__ Mm,
                                                 const float* __restrict__ cv, float* __restrict__ ae, int E) {
  int e = blockIdx.x * 256 + threadIdx.x;
  if (e >= E) return;
  float v[6];
#pragma unroll
  for (int f = 0; f < 6; ++f) v[f] = ea[(size_t)e * 6 + f];
  for (int l = 0; l < NL; ++l)
#pragma unroll
    for (int hh = 0; hh < 8; ++hh) {
      float s = cv[l * 8 + hh];
#pragma unroll
      for (int f = 0; f < 6; ++f) s += v[f] * Mm[l * 48 + f * 8 + hh];
      ae[(size_t)l * E * 8 + (size_t)e * 8 + hh] = s;
    }
}

// a_e for self loops: loop_attr = deg>0 ? mean_ea@We + be : 0  ->  ae_s = loop_attr @ w_e
__global__ __launch_bounds__(256) void k_ae_self(const float* __restrict__ mea, const int* __restrict__ cnt,
                                                 const float* __restrict__ Mm, const float* __restrict__ cv,
                                                 float* __restrict__ aes, int N) {
  int n = blockIdx.x * 256 + threadIdx.x;
  if (n >= N) return;
  bool has = cnt[n] > 0;
  float v[6];
#pragma unroll
  for (int f = 0; f < 6; ++f) v[f] = mea[(size_t)n * 6 + f];
  for (int l = 0; l < NL; ++l)
#pragma unroll
    for (int hh = 0; hh < 8; ++hh) {
      float s = 0.f;
      if (has) {
        s = cv[l * 8 + hh];
#pragma unroll
        for (int f = 0; f < 6; ++f) s += v[f] * Mm[l * 48 + f * 8 + hh];
      }
      aes[(size_t)l * N * 8 + (size_t)n * 8 + hh] = s;
    }
}

// ---------------- GEMM v2: C[M,200] = A[M,K] @ B[K,200] (+bias) (+accumulate) ----------------
// BM=64, BN=200 (full), BK=8, 320 threads. Per-thread 4 rows x 10 cols.
// A: global->registers (2x float4 per row, heavy L1 broadcast reuse across the 20
//    threads sharing a row-group). B: LDS double-buffered via register prefetch
//    (issue-early / write-late), ONE barrier per K-step.
__global__ __launch_bounds__(320, 4) void k_gemm_v2(const float* __restrict__ A, const float* __restrict__ B,
                                                    const float* __restrict__ bias, float* __restrict__ C,
                                                    int M, int K, int accumulate) {
  __shared__ float Bs[2][8][HD];
  const int t = threadIdx.x;
  const int cg = t % 20;           // col group: cols [cg*10, cg*10+10)
  const int rg = t / 20;           // row group: rows [rg*4, rg*4+4)
  const int c0 = cg * 10;
  const int row0 = blockIdx.x * 64 + rg * 4;

  // B staging: 8x200 floats = 400 float4 chunks; thread covers chunk t and t+320.
  const int ck1 = t / 50,          cc1 = (t % 50) * 4;
  const int ck2 = (t + 320) / 50,  cc2 = ((t + 320) % 50) * 4;
  const bool has2 = (t + 320) < 400;

  // Clamped A row pointers (tail rows re-read row M-1; results discarded on store)
  const float* Ap0 = A + (size_t)((row0 + 0 < M) ? row0 + 0 : M - 1) * K;
  const float* Ap1 = A + (size_t)((row0 + 1 < M) ? row0 + 1 : M - 1) * K;
  const float* Ap2 = A + (size_t)((row0 + 2 < M) ? row0 + 2 : M - 1) * K;
  const float* Ap3 = A + (size_t)((row0 + 3 < M) ? row0 + 3 : M - 1) * K;

  float acc[4][10] = {};
  const int nIter = K >> 3;

  float4 b1v, b2v;
  // prologue: stage tile 0
  b1v = *(const float4*)(B + (size_t)ck1 * HD + cc1);
  if (has2) b2v = *(const float4*)(B + (size_t)ck2 * HD + cc2);
  *(float4*)(&Bs[0][ck1][cc1]) = b1v;
  if (has2) *(float4*)(&Bs[0][ck2][cc2]) = b2v;
  __syncthreads();

  for (int it = 0; it < nIter; ++it) {
    const int cur = it & 1;
    const int kbase = it * 8;
    // issue next B tile loads early (latency hides under FMA block)
    if (it + 1 < nIter) {
      const float* Bn = B + (size_t)(kbase + 8) * HD;
      b1v = *(const float4*)(Bn + (size_t)ck1 * HD + cc1);
      if (has2) b2v = *(const float4*)(Bn + (size_t)ck2 * HD + cc2);
    }
    // A regs for this K-step: 4 rows x 8 k
    float ar[4][8];
    {
      float4 lo, hi;
      lo = *(const float4*)(Ap0 + kbase); hi = *(const float4*)(Ap0 + kbase + 4);
      ar[0][0]=lo.x; ar[0][1]=lo.y; ar[0][2]=lo.z; ar[0][3]=lo.w;
      ar[0][4]=hi.x; ar[0][5]=hi.y; ar[0][6]=hi.z; ar[0][7]=hi.w;
      lo = *(const float4*)(Ap1 + kbase); hi = *(const float4*)(Ap1 + kbase + 4);
      ar[1][0]=lo.x; ar[1][1]=lo.y; ar[1][2]=lo.z; ar[1][3]=lo.w;
      ar[1][4]=hi.x; ar[1][5]=hi.y; ar[1][6]=hi.z; ar[1][7]=hi.w;
      lo = *(const float4*)(Ap2 + kbase); hi = *(const float4*)(Ap2 + kbase + 4);
      ar[2][0]=lo.x; ar[2][1]=lo.y; ar[2][2]=lo.z; ar[2][3]=lo.w;
      ar[2][4]=hi.x; ar[2][5]=hi.y; ar[2][6]=hi.z; ar[2][7]=hi.w;
      lo = *(const float4*)(Ap3 + kbase); hi = *(const float4*)(Ap3 + kbase + 4);
      ar[3][0]=lo.x; ar[3][1]=lo.y; ar[3][2]=lo.z; ar[3][3]=lo.w;
      ar[3][4]=hi.x; ar[3][5]=hi.y; ar[3][6]=hi.z; ar[3][7]=hi.w;
    }
#pragma unroll
    for (int kk = 0; kk < 8; ++kk) {
#pragma unroll
      for (int j = 0; j < 10; ++j) {
        const float b = Bs[cur][kk][c0 + j];
        acc[0][j] += ar[0][kk] * b;
        acc[1][j] += ar[1][kk] * b;
        acc[2][j] += ar[2][kk] * b;
        acc[3][j] += ar[3][kk] * b;
      }
    }
    // write next tile (other buffer) late; one barrier per K-step
    if (it + 1 < nIter) {
      *(float4*)(&Bs[cur ^ 1][ck1][cc1]) = b1v;
      if (has2) *(float4*)(&Bs[cur ^ 1][ck2][cc2]) = b2v;
    }
    __syncthreads();
  }

#pragma unroll
  for (int i = 0; i < 4; ++i) {
    const int r = row0 + i;
    if (r < M) {
#pragma unroll
      for (int j = 0; j < 10; ++j) {
        const int c = c0 + j;
        float v = acc[i][j];
        if (bias) v += bias[c];
        if (accumulate) v += C[(size_t)r * HD + c];
        C[(size_t)r * HD + c] = v;
      }
    }
  }
}

// a_src[n,h] = sum_c xs[n,h*25+c]*att_src[h,c]; same for a_dst
__global__ __launch_bounds__(256) void k_asrcdst(const float* __restrict__ xs, const float* __restrict__ as_l,
                                                 const float* __restrict__ ad_l, float* __restrict__ a_src,
                                                 float* __restrict__ a_dst, int N) {
  int tid = blockIdx.x * 256 + threadIdx.x;
  if (tid >= N * 8) return;
  int n = tid >> 3, hh = tid & 7;
  const float* xr = xs + (size_t)n * HD + hh * CD;
  const float* sa = as_l + hh * CD;
  const float* da = ad_l + hh * CD;
  float s = 0.f, d = 0.f;
#pragma unroll
  for (int c = 0; c < CD; ++c) { float v = xr[c]; s += v * sa[c]; d += v * da[c]; }
  a_src[tid] = s; a_dst[tid] = d;
}

// ---------------- per-dst-node softmax aggregation; one wave per node ----------------
__global__ __launch_bounds__(256) void k_aggr(const float* __restrict__ xs, const float* __restrict__ a_src,
                                              const float* __restrict__ a_dst, const float* __restrict__ ae_e,
                                              const float* __restrict__ ae_s, const float* __restrict__ gb,
                                              const int* __restrict__ off, const int* __restrict__ eid,
                                              const int* __restrict__ esrc, float* __restrict__ h_out, int N) {
  int lane = threadIdx.x & 63;
  int node = blockIdx.x * 4 + (threadIdx.x >> 6);
  if (node >= N) return;
  int o0 = off[node], o1 = off[node + 1];
  // column->head mapping for this lane's 4 owned columns (lane, +64, +128, +192)
  int hh0 = lane / 25, hh1 = (lane + 64) / 25, hh2 = (lane + 128) / 25, hh3 = (lane + 192) / 25;
  float adsth = 0.f, aself = 0.f, aes = 0.f, mx = -1e30f;
  if (lane < 8) {
    adsth = a_dst[(size_t)node * 8 + lane];
    aself = a_src[(size_t)node * 8 + lane];
    aes   = ae_s[(size_t)node * 8 + lane];
    float l0 = aself + adsth + aes;
    mx = (l0 >= 0.f) ? l0 : 0.2f * l0;
  }
  // pass 1: max logit per head (lanes 0..7)
  for (int p = o0; p < o1; ++p) {
    int e = eid[p], s = esrc[e];
    if (lane < 8) {
      float l0 = a_src[(size_t)s * 8 + lane] + adsth + ae_e[(size_t)e * 8 + lane];
      l0 = (l0 >= 0.f) ? l0 : 0.2f * l0;
      mx = fmaxf(mx, l0);
    }
  }
  // pass 2: exp-weights (lanes 0..7), broadcast via shuffle, accumulate columns
  float acc0 = 0.f, acc1 = 0.f, acc2 = 0.f, acc3 = 0.f, ssum = 0.f;
  {
    float w = 0.f;
    if (lane < 8) {
      float l0 = aself + adsth + aes;
      l0 = (l0 >= 0.f) ? l0 : 0.2f * l0;
      w = expf(l0 - mx); ssum += w;
    }
    float wa = __shfl(w, hh0), wb = __shfl(w, hh1), wc = __shfl(w, hh2), wd = __shfl(w, hh3);
    const float* xr = xs + (size_t)node * HD;
    acc0 += wa * xr[lane]; acc1 += wb * xr[lane + 64]; acc2 += wc * xr[lane + 128];
    if (lane < 8) acc3 += wd * xr[lane + 192];
  }
  for (int p = o0; p < o1; ++p) {
    int e = eid[p], s = esrc[e];
    float w = 0.f;
    if (lane < 8) {
      float l0 = a_src[(size_t)s * 8 + lane] + adsth + ae_e[(size_t)e * 8 + lane];
      l0 = (l0 >= 0.f) ? l0 : 0.2f * l0;
      w = expf(l0 - mx); ssum += w;
    }
    float wa = __shfl(w, hh0), wb = __shfl(w, hh1), wc = __shfl(w, hh2), wd = __shfl(w, hh3);
    const float* xr = xs + (size_t)s * HD;
    acc0 += wa * xr[lane]; acc1 += wb * xr[lane + 64]; acc2 += wc * xr[lane + 128];
    if (lane < 8) acc3 += wd * xr[lane + 192];
  }
  float sa = __shfl(ssum, hh0) + 1e-16f, sb = __shfl(ssum, hh1) + 1e-16f;
  float sc = __shfl(ssum, hh2) + 1e-16f, sd = __shfl(ssum, hh3) + 1e-16f;
  float* ho = h_out + (size_t)node * HD;
  ho[lane]       = acc0 / sa + gb[lane];
  ho[lane + 64]  = acc1 / sb + gb[lane + 64];
  ho[lane + 128] = acc2 / sc + gb[lane + 128];
  if (lane < 8) ho[lane + 192] = acc3 / sd + gb[lane + 192];
}

// graph start offsets from sorted batch
__global__ __launch_bounds__(256) void k_gstart(const int* __restrict__ batch, int* __restrict__ gstart,
                                                int N, int G) {
  int i = blockIdx.x * 256 + threadIdx.x;
  if (i >= N) return;
  int b = batch[i];
  int pb = (i == 0) ? -1 : batch[i - 1];
  for (int g = pb + 1; g <= b; ++g) gstart[g] = i;
  if (i == N - 1) for (int g = b + 1; g <= G; ++g) gstart[g] = N;
}

__global__ __launch_bounds__(256) void k_pool(const float* __restrict__ h, const int* __restrict__ gstart,
                                              float* __restrict__ pooled, int G) {
  int g = blockIdx.x, c = threadIdx.x;
  if (c >= HD) return;
  int s0 = gstart[g], s1 = gstart[g + 1];
  float acc = 0.f;
  for (int i = s0; i < s1; ++i) acc += h[(size_t)i * HD + c];
  pooled[(size_t)g * HD + c] = acc;
}

// task heads: one wave per (t,g)
__global__ __launch_bounds__(256) void k_heads(const float* __restrict__ ro, const float* __restrict__ w1,
                                               const float* __restrict__ b1, const float* __restrict__ w2,
                                               const float* __restrict__ b2, float* __restrict__ out, int G) {
  int lane = threadIdx.x & 63;
  int idx = blockIdx.x * 4 + (threadIdx.x >> 6);
  if (idx >= 5 * G) return;
  int t = idx / G, g = idx % G;
  const float* r = ro + (size_t)g * HD;
  const float* W = w1 + (size_t)t * HD * 100;
  bool has2 = lane < 36;
  float h0 = 0.f, h1 = 0.f;
  for (int k = 0; k < HD; ++k) {
    float rv = r[k];
    h0 += rv * W[k * 100 + lane];
    if (has2) h1 += rv * W[k * 100 + 64 + lane];
  }
  h0 += b1[t * 100 + lane];
  h0 = h0 > 0.f ? h0 : 0.f;
  float p = h0 * w2[t * 100 + lane];
  if (has2) {
    h1 += b1[t * 100 + 64 + lane];
    h1 = h1 > 0.f ? h1 : 0.f;
    p += h1 * w2[t * 100 + 64 + lane];
  }
  for (int o = 32; o >= 1; o >>= 1) p += __shfl_down(p, o);
  if (lane == 0) {
    float z = p + b2[t];
    bool sig = (t == 0) | (t == 3) | (t == 4);   // SIG = {1,0,0,1,1}
    out[idx] = sig ? 1.f / (1.f + expf(-z)) : z;
  }
}

extern "C" void kernel_launch(void* const* d_in, const int* in_sizes, int n_in,
                              void* d_out, int out_size, void* d_ws, size_t ws_size,
                              hipStream_t stream) {
  const float* x         = (const float*)d_in[0];
  const float* edge_attr = (const float*)d_in[1];
  const float* node_w    = (const float*)d_in[2];
  const float* node_b    = (const float*)d_in[3];
  const float* edge_w    = (const float*)d_in[4];
  const float* edge_b    = (const float*)d_in[5];
  const float* lin_w     = (const float*)d_in[6];
  const float* lin_edge_w= (const float*)d_in[7];
  const float* att_src   = (const float*)d_in[8];
  const float* att_dst   = (const float*)d_in[9];
  const float* att_edge  = (const float*)d_in[10];
  const float* gat_bias  = (const float*)d_in[11];
  const float* readout_w = (const float*)d_in[12];
  const float* readout_b = (const float*)d_in[13];
  const float* head_w1   = (const float*)d_in[14];
  const float* head_b1   = (const float*)d_in[15];
  const float* head_w2   = (const float*)d_in[16];
  const float* head_b2   = (const float*)d_in[17];
  const int*   edge_index= (const int*)d_in[18];
  const int*   batch     = (const int*)d_in[19];

  const int N = in_sizes[0] / 64;
  const int E = in_sizes[1] / 6;
  const int G = out_size / 5;
  const int* srcI = edge_index;
  const int* dstI = edge_index + E;

  char* wsb = (char*)d_ws;
  size_t o = 0;
  auto alloc = [&](size_t bytes) -> void* {
    void* p = wsb + o;
    o = (o + bytes + 255) & ~(size_t)255;
    return p;
  };
  float* h       = (float*)alloc((size_t)N * HD * 4);
  float* xs      = (float*)alloc((size_t)N * HD * 4);
  float* a_src   = (float*)alloc((size_t)N * 8 * 4);
  float* a_dst   = (float*)alloc((size_t)N * 8 * 4);
  float* ae_e    = (float*)alloc((size_t)NL * E * 8 * 4);
  float* ae_s    = (float*)alloc((size_t)NL * N * 8 * 4);
  float* mean_ea = (float*)alloc((size_t)N * 6 * 4);
  float* we      = (float*)alloc((size_t)NL * HD * 8 * 4);
  float* Mm      = (float*)alloc((size_t)NL * 6 * 8 * 4);
  float* cv      = (float*)alloc((size_t)NL * 8 * 4);
  int* cnt       = (int*)alloc((size_t)N * 4);
  int* cur       = (int*)alloc((size_t)N * 4);
  int* off       = (int*)alloc((size_t)(N + 1) * 4);
  int* partial   = (int*)alloc(512 * 4);
  int* eid       = (int*)alloc((size_t)E * 4);
  int* gstart    = (int*)alloc((size_t)(G + 1) * 4);
  float* pooled  = (float*)alloc((size_t)G * HD * 4);
  float* readouts= (float*)alloc((size_t)G * HD * 4);
  (void)ws_size; (void)n_in;

  hipMemsetAsync(cnt, 0, (size_t)N * 4, stream);
  hipMemsetAsync(cur, 0, (size_t)N * 4, stream);
  hipMemsetAsync(readouts, 0, (size_t)G * HD * 4, stream);

  int nb = (N + 255) / 256;
  k_hist<<<(E + 255) / 256, 256, 0, stream>>>(dstI, cnt, E);
  k_scan1<<<nb, 256, 0, stream>>>(cnt, off, partial, N);
  k_scan2<<<1, 512, 0, stream>>>(partial, nb, off, N);
  k_scan3<<<nb, 256, 0, stream>>>(off, partial, N);
  k_scatter<<<(E + 255) / 256, 256, 0, stream>>>(dstI, off, cur, eid, E);
  k_sort<<<nb, 256, 0, stream>>>(off, eid, N);
  k_meanea<<<(N + 127) / 128, 128, 0, stream>>>(edge_attr, off, eid, mean_ea, N);
  k_we<<<(NL * HD * 8 + 255) / 256, 256, 0, stream>>>(lin_edge_w, att_edge, we);
  k_M<<<1, 256, 0, stream>>>(edge_w, edge_b, we, Mm, cv);
  k_ae_edge<<<(E + 255) / 256, 256, 0, stream>>>(edge_attr, Mm, cv, ae_e, E);
  k_ae_self<<<(N + 255) / 256, 256, 0, stream>>>(mean_ea, cnt, Mm, cv, ae_s, N);
  k_gemm_v2<<<(N + 63) / 64, 320, 0, stream>>>(x, node_w, node_b, h, N, 64, 0);
  k_gstart<<<nb, 256, 0, stream>>>(batch, gstart, N, G);

  for (int l = 0; l < NL; ++l) {
    k_gemm_v2<<<(N + 63) / 64, 320, 0, stream>>>(h, lin_w + (size_t)l * HD * HD, nullptr, xs, N, HD, 0);
    k_asrcdst<<<(N * 8 + 255) / 256, 256, 0, stream>>>(xs, att_src + l * NH * CD, att_dst + l * NH * CD,
                                                       a_src, a_dst, N);
    k_aggr<<<(N + 3) / 4, 256, 0, stream>>>(xs, a_src, a_dst, ae_e + (size_t)l * E * 8,
                                            ae_s + (size_t)l * N * 8, gat_bias + l * HD,
                                            off, eid, srcI, h, N);
    k_pool<<<G, 256, 0, stream>>>(h, gstart, pooled, G);
    k_gemm_v2<<<(G + 63) / 64, 320, 0, stream>>>(pooled, readout_w + (size_t)l * HD * HD,
                                                 readout_b + l * HD, readouts, G, HD, 1);
  }
  k_heads<<<(5 * G + 3) / 4, 256, 0, stream>>>(readouts, head_w1, head_b1, head_w2, head_b2,
                                               (float*)d_out, G);
}

// Round 3
// 2496.145 us; speedup vs baseline: 2.1450x; 2.1450x over previous
//
#include <hip/hip_runtime.h>
#include <cstdint>
#include <cstddef>

// Sizes (fixed by problem, but N/E/G derived at launch)
static constexpr int HD = 200;   // hidden
static constexpr int NH = 8;     // heads
static constexpr int CD = 25;    // per-head dim
static constexpr int NL = 4;     // layers

// ---------------- CSR build ----------------
__global__ __launch_bounds__(256) void k_hist(const int* __restrict__ dst, int* __restrict__ cnt, int E) {
  int e = blockIdx.x * 256 + threadIdx.x;
  if (e < E) atomicAdd(&cnt[dst[e]], 1);
}

__global__ __launch_bounds__(256) void k_scan1(const int* __restrict__ cnt, int* __restrict__ off,
                                               int* __restrict__ partial, int N) {
  __shared__ int sm[256];
  int t = threadIdx.x, i = blockIdx.x * 256 + t;
  int v = (i < N) ? cnt[i] : 0;
  sm[t] = v; __syncthreads();
  for (int o = 1; o < 256; o <<= 1) {
    int add = (t >= o) ? sm[t - o] : 0;
    __syncthreads();
    sm[t] += add;
    __syncthreads();
  }
  if (i < N) off[i] = sm[t] - v;            // exclusive
  if (t == 255) partial[blockIdx.x] = sm[255];
}

__global__ __launch_bounds__(512) void k_scan2(int* __restrict__ partial, int nb, int* __restrict__ off, int N) {
  __shared__ int sm[512];
  int t = threadIdx.x;
  int v = (t < nb) ? partial[t] : 0;
  sm[t] = v; __syncthreads();
  for (int o = 1; o < 512; o <<= 1) {
    int add = (t >= o) ? sm[t - o] : 0;
    __syncthreads();
    sm[t] += add;
    __syncthreads();
  }
  if (t < nb) partial[t] = sm[t] - v;       // exclusive block offsets
  if (t == 511) off[N] = sm[511];           // total == E
}

__global__ __launch_bounds__(256) void k_scan3(int* __restrict__ off, const int* __restrict__ partial, int N) {
  int i = blockIdx.x * 256 + threadIdx.x;
  if (i < N) off[i] += partial[i >> 8];
}

__global__ __launch_bounds__(256) void k_scatter(const int* __restrict__ dst, const int* __restrict__ off,
                                                 int* __restrict__ cur, int* __restrict__ eid, int E) {
  int e = blockIdx.x * 256 + threadIdx.x;
  if (e < E) {
    int d = dst[e];
    int p = atomicAdd(&cur[d], 1);
    eid[off[d] + p] = e;
  }
}

// sort each node's edge list ascending -> deterministic float accumulation order everywhere downstream
__global__ __launch_bounds__(256) void k_sort(const int* __restrict__ off, int* __restrict__ eid, int N) {
  int n = blockIdx.x * 256 + threadIdx.x;
  if (n >= N) return;
  int o0 = off[n], o1 = off[n + 1];
  for (int i = o0 + 1; i < o1; ++i) {
    int v = eid[i]; int j = i - 1;
    while (j >= o0 && eid[j] > v) { eid[j + 1] = eid[j]; --j; }
    eid[j + 1] = v;
  }
}

// ---------------- edge-attention precompute (algebraic reductions) ----------------
__global__ __launch_bounds__(128) void k_meanea(const float* __restrict__ ea, const int* __restrict__ off,
                                                const int* __restrict__ eid, float* __restrict__ mea, int N) {
  int n = blockIdx.x * 128 + threadIdx.x;
  if (n >= N) return;
  int o0 = off[n], o1 = off[n + 1];
  float s0 = 0, s1 = 0, s2 = 0, s3 = 0, s4 = 0, s5 = 0;
  for (int p = o0; p < o1; ++p) {
    const float* r = ea + (size_t)eid[p] * 6;
    s0 += r[0]; s1 += r[1]; s2 += r[2]; s3 += r[3]; s4 += r[4]; s5 += r[5];
  }
  float inv = (o1 > o0) ? 1.f / (float)(o1 - o0) : 0.f;
  float* m = mea + (size_t)n * 6;
  m[0] = s0 * inv; m[1] = s1 * inv; m[2] = s2 * inv; m[3] = s3 * inv; m[4] = s4 * inv; m[5] = s5 * inv;
}

// w_e[l][k][h] = sum_c lin_edge_w[l][k][h*25+c] * att_edge[l][h][c]
__global__ __launch_bounds__(256) void k_we(const float* __restrict__ lew, const float* __restrict__ ae,
                                            float* __restrict__ we) {
  int tid = blockIdx.x * 256 + threadIdx.x;
  if (tid >= NL * HD * 8) return;
  int l = tid / (HD * 8); int r = tid % (HD * 8); int k = r >> 3; int hh = r & 7;
  const float* W = lew + (size_t)l * HD * HD + (size_t)k * HD + hh * CD;
  const float* a = ae + l * NH * CD + hh * CD;
  float s = 0.f;
#pragma unroll
  for (int c = 0; c < CD; ++c) s += W[c] * a[c];
  we[tid] = s;   // layout l*1600 + k*8 + hh
}

// M[l][f][h] = sum_k edge_emb_w[f][k] * w_e[l][k][h];  cvec[l][h] = sum_k edge_emb_b[k]*w_e[l][k][h]
__global__ __launch_bounds__(256) void k_M(const float* __restrict__ ew, const float* __restrict__ eb,
                                           const float* __restrict__ we, float* __restrict__ Mm,
                                           float* __restrict__ cv) {
  int tid = threadIdx.x;
  if (tid < NL * 6 * 8) {
    int l = tid / 48, r = tid % 48, f = r / 8, hh = r % 8;
    float s = 0.f;
    for (int k = 0; k < HD; ++k) s += ew[f * HD + k] * we[l * 1600 + k * 8 + hh];
    Mm[tid] = s;   // l*48 + f*8 + hh
  } else if (tid < NL * 6 * 8 + NL * 8) {
    int u = tid - NL * 6 * 8, l = u / 8, hh = u % 8;
    float s = 0.f;
    for (int k = 0; k < HD; ++k) s += eb[k] * we[l * 1600 + k * 8 + hh];
    cv[u] = s;
  }
}

// a_e for real edges, all layers: ae[l][e][h] = edge_attr[e] . M[l][:,h] + cvec[l][h]
__global__ __launch_bounds__(256) void k_ae_edge(const float* __restrict__ ea, const float* __restrict__ Mm,
                                                 const float* __restrict__ cv, float* __restrict__ ae, int E) {
  int e = blockIdx.x * 256 + threadIdx.x;
  if (e >= E) return;
  float v[6];
#pragma unroll
  for (int f = 0; f < 6; ++f) v[f] = ea[(size_t)e * 6 + f];
  for (int l = 0; l < NL; ++l)
#pragma unroll
    for (int hh = 0; hh < 8; ++hh) {
      float s = cv[l * 8 + hh];
#pragma unroll
      for (int f = 0; f < 6; ++f) s += v[f] * Mm[l * 48 + f * 8 + hh];
      ae[(size_t)l * E * 8 + (size_t)e * 8 + hh] = s;
    }
}

// a_e for self loops: loop_attr = deg>0 ? mean_ea@We + be : 0  ->  ae_s = loop_attr @ w_e
__global__ __launch_bounds__(256) void k_ae_self(const float* __restrict__ mea, const int* __restrict__ cnt,
                                                 const float* __restrict__ Mm, const float* __restrict__ cv,
                                                 float* __restrict__ aes, int N) {
  int n = blockIdx.x * 256 + threadIdx.x;
  if (n >= N) return;
  bool has = cnt[n] > 0;
  float v[6];
#pragma unroll
  for (int f = 0; f < 6; ++f) v[f] = mea[(size_t)n * 6 + f];
  for (int l = 0; l < NL; ++l)
#pragma unroll
    for (int hh = 0; hh < 8; ++hh) {
      float s = 0.f;
      if (has) {
        s = cv[l * 8 + hh];
#pragma unroll
        for (int f = 0; f < 6; ++f) s += v[f] * Mm[l * 48 + f * 8 + hh];
      }
      aes[(size_t)l * N * 8 + (size_t)n * 8 + hh] = s;
    }
}

// ---------------- GEMM v3: C[M,200] = A[M,K] @ B[K,200] (+bias) (+accumulate) ----------------
// BM=64, BN=200 (full), BK=8, 320 threads, per-thread 4 rows x 10 cols.
// Both A and B staged in LDS, double-buffered, register-prefetch (issue-early /
// write-late), ONE barrier per K-step. A stored TRANSPOSED As[kk][row] so the
// 4-row fragment is a single aligned ds_read_b128. No occupancy floor (round-2's
// __launch_bounds__(320,4) capped VGPRs -> scratch spills -> 1.9 GB HBM writes).
__global__ __launch_bounds__(320) void k_gemm_v3(const float* __restrict__ A, const float* __restrict__ B,
                                                 const float* __restrict__ bias, float* __restrict__ C,
                                                 int M, int K, int accumulate) {
  __shared__ float As[2][8][64];    // [buf][k][row]
  __shared__ float Bs[2][8][HD];    // [buf][k][col]
  const int t = threadIdx.x;
  const int cg = t % 20;            // col group: cols [cg*10, cg*10+10)
  const int rg = t / 20;            // row group: rows [rg*4, rg*4+4)
  const int c0 = cg * 10;
  const int row0 = blockIdx.x * 64;

  // A staging: 64 rows x 8 k = 128 float4 chunks; threads 0..127, one each.
  const bool aldr = t < 128;
  const int ar_ = t >> 1;                 // row within tile
  const int ak_ = (t & 1) * 4;            // k offset within tile
  const int agr = row0 + ar_;             // global row (guarded)
  // B staging: 8x200 = 400 float4 chunks; thread covers chunk t and t+320.
  const int ck1 = t / 50,          cc1 = (t % 50) * 4;
  const int ck2 = (t + 320) / 50,  cc2 = ((t + 320) % 50) * 4;
  const bool bldr2 = (t + 320) < 400;

  float acc[4][10] = {};
  const int nIter = K >> 3;

  float4 av, b1v, b2v;
  // prologue: stage tile 0 into buf 0
  if (aldr) {
    av = (agr < M) ? *(const float4*)(A + (size_t)agr * K + ak_)
                   : make_float4(0.f, 0.f, 0.f, 0.f);
    As[0][ak_ + 0][ar_] = av.x; As[0][ak_ + 1][ar_] = av.y;
    As[0][ak_ + 2][ar_] = av.z; As[0][ak_ + 3][ar_] = av.w;
  }
  b1v = *(const float4*)(B + (size_t)ck1 * HD + cc1);
  if (bldr2) b2v = *(const float4*)(B + (size_t)ck2 * HD + cc2);
  *(float4*)(&Bs[0][ck1][cc1]) = b1v;
  if (bldr2) *(float4*)(&Bs[0][ck2][cc2]) = b2v;
  __syncthreads();

  for (int it = 0; it < nIter; ++it) {
    const int cur = it & 1;
    // issue next-tile global loads early (latency hides under the FMA block)
    const bool more = (it + 1) < nIter;
    if (more) {
      const int kb = (it + 1) * 8;
      if (aldr)
        av = (agr < M) ? *(const float4*)(A + (size_t)agr * K + kb + ak_)
                       : make_float4(0.f, 0.f, 0.f, 0.f);
      const float* Bn = B + (size_t)kb * HD;
      b1v = *(const float4*)(Bn + (size_t)ck1 * HD + cc1);
      if (bldr2) b2v = *(const float4*)(Bn + (size_t)ck2 * HD + cc2);
    }
#pragma unroll
    for (int kk = 0; kk < 8; ++kk) {
      const float4 af = *(const float4*)(&As[cur][kk][rg * 4]);   // one ds_read_b128
#pragma unroll
      for (int j = 0; j < 10; ++j) {
        const float b = Bs[cur][kk][c0 + j];
        acc[0][j] += af.x * b;
        acc[1][j] += af.y * b;
        acc[2][j] += af.z * b;
        acc[3][j] += af.w * b;
      }
    }
    // write next tile into the other buffer late; one barrier per K-step
    if (more) {
      const int nxt = cur ^ 1;
      if (aldr) {
        As[nxt][ak_ + 0][ar_] = av.x; As[nxt][ak_ + 1][ar_] = av.y;
        As[nxt][ak_ + 2][ar_] = av.z; As[nxt][ak_ + 3][ar_] = av.w;
      }
      *(float4*)(&Bs[nxt][ck1][cc1]) = b1v;
      if (bldr2) *(float4*)(&Bs[nxt][ck2][cc2]) = b2v;
    }
    __syncthreads();
  }

#pragma unroll
  for (int i = 0; i < 4; ++i) {
    const int r = row0 + rg * 4 + i;
    if (r < M) {
#pragma unroll
      for (int j = 0; j < 10; ++j) {
        const int c = c0 + j;
        float v = acc[i][j];
        if (bias) v += bias[c];
        if (accumulate) v += C[(size_t)r * HD + c];
        C[(size_t)r * HD + c] = v;
      }
    }
  }
}

// a_src[n,h] = sum_c xs[n,h*25+c]*att_src[h,c]; same for a_dst
__global__ __launch_bounds__(256) void k_asrcdst(const float* __restrict__ xs, const float* __restrict__ as_l,
                                                 const float* __restrict__ ad_l, float* __restrict__ a_src,
                                                 float* __restrict__ a_dst, int N) {
  int tid = blockIdx.x * 256 + threadIdx.x;
  if (tid >= N * 8) return;
  int n = tid >> 3, hh = tid & 7;
  const float* xr = xs + (size_t)n * HD + hh * CD;
  const float* sa = as_l + hh * CD;
  const float* da = ad_l + hh * CD;
  float s = 0.f, d = 0.f;
#pragma unroll
  for (int c = 0; c < CD; ++c) { float v = xr[c]; s += v * sa[c]; d += v * da[c]; }
  a_src[tid] = s; a_dst[tid] = d;
}

// ---------------- per-dst-node softmax aggregation; one wave per node ----------------
__global__ __launch_bounds__(256) void k_aggr(const float* __restrict__ xs, const float* __restrict__ a_src,
                                              const float* __restrict__ a_dst, const float* __restrict__ ae_e,
                                              const float* __restrict__ ae_s, const float* __restrict__ gb,
                                              const int* __restrict__ off, const int* __restrict__ eid,
                                              const int* __restrict__ esrc, float* __restrict__ h_out, int N) {
  int lane = threadIdx.x & 63;
  int node = blockIdx.x * 4 + (threadIdx.x >> 6);
  if (node >= N) return;
  int o0 = off[node], o1 = off[node + 1];
  // column->head mapping for this lane's 4 owned columns (lane, +64, +128, +192)
  int hh0 = lane / 25, hh1 = (lane + 64) / 25, hh2 = (lane + 128) / 25, hh3 = (lane + 192) / 25;
  float adsth = 0.f, aself = 0.f, aes = 0.f, mx = -1e30f;
  if (lane < 8) {
    adsth = a_dst[(size_t)node * 8 + lane];
    aself = a_src[(size_t)node * 8 + lane];
    aes   = ae_s[(size_t)node * 8 + lane];
    float l0 = aself + adsth + aes;
    mx = (l0 >= 0.f) ? l0 : 0.2f * l0;
  }
  // pass 1: max logit per head (lanes 0..7)
  for (int p = o0; p < o1; ++p) {
    int e = eid[p], s = esrc[e];
    if (lane < 8) {
      float l0 = a_src[(size_t)s * 8 + lane] + adsth + ae_e[(size_t)e * 8 + lane];
      l0 = (l0 >= 0.f) ? l0 : 0.2f * l0;
      mx = fmaxf(mx, l0);
    }
  }
  // pass 2: exp-weights (lanes 0..7), broadcast via shuffle, accumulate columns
  float acc0 = 0.f, acc1 = 0.f, acc2 = 0.f, acc3 = 0.f, ssum = 0.f;
  {
    float w = 0.f;
    if (lane < 8) {
      float l0 = aself + adsth + aes;
      l0 = (l0 >= 0.f) ? l0 : 0.2f * l0;
      w = expf(l0 - mx); ssum += w;
    }
    float wa = __shfl(w, hh0), wb = __shfl(w, hh1), wc = __shfl(w, hh2), wd = __shfl(w, hh3);
    const float* xr = xs + (size_t)node * HD;
    acc0 += wa * xr[lane]; acc1 += wb * xr[lane + 64]; acc2 += wc * xr[lane + 128];
    if (lane < 8) acc3 += wd * xr[lane + 192];
  }
  for (int p = o0; p < o1; ++p) {
    int e = eid[p], s = esrc[e];
    float w = 0.f;
    if (lane < 8) {
      float l0 = a_src[(size_t)s * 8 + lane] + adsth + ae_e[(size_t)e * 8 + lane];
      l0 = (l0 >= 0.f) ? l0 : 0.2f * l0;
      w = expf(l0 - mx); ssum += w;
    }
    float wa = __shfl(w, hh0), wb = __shfl(w, hh1), wc = __shfl(w, hh2), wd = __shfl(w, hh3);
    const float* xr = xs + (size_t)s * HD;
    acc0 += wa * xr[lane]; acc1 += wb * xr[lane + 64]; acc2 += wc * xr[lane + 128];
    if (lane < 8) acc3 += wd * xr[lane + 192];
  }
  float sa = __shfl(ssum, hh0) + 1e-16f, sb = __shfl(ssum, hh1) + 1e-16f;
  float sc = __shfl(ssum, hh2) + 1e-16f, sd = __shfl(ssum, hh3) + 1e-16f;
  float* ho = h_out + (size_t)node * HD;
  ho[lane]       = acc0 / sa + gb[lane];
  ho[lane + 64]  = acc1 / sb + gb[lane + 64];
  ho[lane + 128] = acc2 / sc + gb[lane + 128];
  if (lane < 8) ho[lane + 192] = acc3 / sd + gb[lane + 192];
}

// graph start offsets from sorted batch
__global__ __launch_bounds__(256) void k_gstart(const int* __restrict__ batch, int* __restrict__ gstart,
                                                int N, int G) {
  int i = blockIdx.x * 256 + threadIdx.x;
  if (i >= N) return;
  int b = batch[i];
  int pb = (i == 0) ? -1 : batch[i - 1];
  for (int g = pb + 1; g <= b; ++g) gstart[g] = i;
  if (i == N - 1) for (int g = b + 1; g <= G; ++g) gstart[g] = N;
}

__global__ __launch_bounds__(256) void k_pool(const float* __restrict__ h, const int* __restrict__ gstart,
                                              float* __restrict__ pooled, int G) {
  int g = blockIdx.x, c = threadIdx.x;
  if (c >= HD) return;
  int s0 = gstart[g], s1 = gstart[g + 1];
  float acc = 0.f;
  for (int i = s0; i < s1; ++i) acc += h[(size_t)i * HD + c];
  pooled[(size_t)g * HD + c] = acc;
}

// task heads: one wave per (t,g)
__global__ __launch_bounds__(256) void k_heads(const float* __restrict__ ro, const float* __restrict__ w1,
                                               const float* __restrict__ b1, const float* __restrict__ w2,
                                               const float* __restrict__ b2, float* __restrict__ out, int G) {
  int lane = threadIdx.x & 63;
  int idx = blockIdx.x * 4 + (threadIdx.x >> 6);
  if (idx >= 5 * G) return;
  int t = idx / G, g = idx % G;
  const float* r = ro + (size_t)g * HD;
  const float* W = w1 + (size_t)t * HD * 100;
  bool has2 = lane < 36;
  float h0 = 0.f, h1 = 0.f;
  for (int k = 0; k < HD; ++k) {
    float rv = r[k];
    h0 += rv * W[k * 100 + lane];
    if (has2) h1 += rv * W[k * 100 + 64 + lane];
  }
  h0 += b1[t * 100 + lane];
  h0 = h0 > 0.f ? h0 : 0.f;
  float p = h0 * w2[t * 100 + lane];
  if (has2) {
    h1 += b1[t * 100 + 64 + lane];
    h1 = h1 > 0.f ? h1 : 0.f;
    p += h1 * w2[t * 100 + 64 + lane];
  }
  for (int o = 32; o >= 1; o >>= 1) p += __shfl_down(p, o);
  if (lane == 0) {
    float z = p + b2[t];
    bool sig = (t == 0) | (t == 3) | (t == 4);   // SIG = {1,0,0,1,1}
    out[idx] = sig ? 1.f / (1.f + expf(-z)) : z;
  }
}

extern "C" void kernel_launch(void* const* d_in, const int* in_sizes, int n_in,
                              void* d_out, int out_size, void* d_ws, size_t ws_size,
                              hipStream_t stream) {
  const float* x         = (const float*)d_in[0];
  const float* edge_attr = (const float*)d_in[1];
  const float* node_w    = (const float*)d_in[2];
  const float* node_b    = (const float*)d_in[3];
  const float* edge_w    = (const float*)d_in[4];
  const float* edge_b    = (const float*)d_in[5];
  const float* lin_w     = (const float*)d_in[6];
  const float* lin_edge_w= (const float*)d_in[7];
  const float* att_src   = (const float*)d_in[8];
  const float* att_dst   = (const float*)d_in[9];
  const float* att_edge  = (const float*)d_in[10];
  const float* gat_bias  = (const float*)d_in[11];
  const float* readout_w = (const float*)d_in[12];
  const float* readout_b = (const float*)d_in[13];
  const float* head_w1   = (const float*)d_in[14];
  const float* head_b1   = (const float*)d_in[15];
  const float* head_w2   = (const float*)d_in[16];
  const float* head_b2   = (const float*)d_in[17];
  const int*   edge_index= (const int*)d_in[18];
  const int*   batch     = (const int*)d_in[19];

  const int N = in_sizes[0] / 64;
  const int E = in_sizes[1] / 6;
  const int G = out_size / 5;
  const int* srcI = edge_index;
  const int* dstI = edge_index + E;

  char* wsb = (char*)d_ws;
  size_t o = 0;
  auto alloc = [&](size_t bytes) -> void* {
    void* p = wsb + o;
    o = (o + bytes + 255) & ~(size_t)255;
    return p;
  };
  float* h       = (float*)alloc((size_t)N * HD * 4);
  float* xs      = (float*)alloc((size_t)N * HD * 4);
  float* a_src   = (float*)alloc((size_t)N * 8 * 4);
  float* a_dst   = (float*)alloc((size_t)N * 8 * 4);
  float* ae_e    = (float*)alloc((size_t)NL * E * 8 * 4);
  float* ae_s    = (float*)alloc((size_t)NL * N * 8 * 4);
  float* mean_ea = (float*)alloc((size_t)N * 6 * 4);
  float* we      = (float*)alloc((size_t)NL * HD * 8 * 4);
  float* Mm      = (float*)alloc((size_t)NL * 6 * 8 * 4);
  float* cv      = (float*)alloc((size_t)NL * 8 * 4);
  int* cnt       = (int*)alloc((size_t)N * 4);
  int* cur       = (int*)alloc((size_t)N * 4);
  int* off       = (int*)alloc((size_t)(N + 1) * 4);
  int* partial   = (int*)alloc(512 * 4);
  int* eid       = (int*)alloc((size_t)E * 4);
  int* gstart    = (int*)alloc((size_t)(G + 1) * 4);
  float* pooled  = (float*)alloc((size_t)G * HD * 4);
  float* readouts= (float*)alloc((size_t)G * HD * 4);
  (void)ws_size; (void)n_in;

  hipMemsetAsync(cnt, 0, (size_t)N * 4, stream);
  hipMemsetAsync(cur, 0, (size_t)N * 4, stream);
  hipMemsetAsync(readouts, 0, (size_t)G * HD * 4, stream);

  int nb = (N + 255) / 256;
  k_hist<<<(E + 255) / 256, 256, 0, stream>>>(dstI, cnt, E);
  k_scan1<<<nb, 256, 0, stream>>>(cnt, off, partial, N);
  k_scan2<<<1, 512, 0, stream>>>(partial, nb, off, N);
  k_scan3<<<nb, 256, 0, stream>>>(off, partial, N);
  k_scatter<<<(E + 255) / 256, 256, 0, stream>>>(dstI, off, cur, eid, E);
  k_sort<<<nb, 256, 0, stream>>>(off, eid, N);
  k_meanea<<<(N + 127) / 128, 128, 0, stream>>>(edge_attr, off, eid, mean_ea, N);
  k_we<<<(NL * HD * 8 + 255) / 256, 256, 0, stream>>>(lin_edge_w, att_edge, we);
  k_M<<<1, 256, 0, stream>>>(edge_w, edge_b, we, Mm, cv);
  k_ae_edge<<<(E + 255) / 256, 256, 0, stream>>>(edge_attr, Mm, cv, ae_e, E);
  k_ae_self<<<(N + 255) / 256, 256, 0, stream>>>(mean_ea, cnt, Mm, cv, ae_s, N);
  k_gemm_v3<<<(N + 63) / 64, 320, 0, stream>>>(x, node_w, node_b, h, N, 64, 0);
  k_gstart<<<nb, 256, 0, stream>>>(batch, gstart, N, G);

  for (int l = 0; l < NL; ++l) {
    k_gemm_v3<<<(N + 63) / 64, 320, 0, stream>>>(h, lin_w + (size_t)l * HD * HD, nullptr, xs, N, HD, 0);
    k_asrcdst<<<(N * 8 + 255) / 256, 256, 0, stream>>>(xs, att_src + l * NH * CD, att_dst + l * NH * CD,
                                                       a_src, a_dst, N);
    k_aggr<<<(N + 3) / 4, 256, 0, stream>>>(xs, a_src, a_dst, ae_e + (size_t)l * E * 8,
                                            ae_s + (size_t)l * N * 8, gat_bias + l * HD,
                                            off, eid, srcI, h, N);
    k_pool<<<G, 256, 0, stream>>>(h, gstart, pooled, G);
    k_gemm_v3<<<(G + 63) / 64, 320, 0, stream>>>(pooled, readout_w + (size_t)l * HD * HD,
                                                 readout_b + l * HD, readouts, G, HD, 1);
  }
  k_heads<<<(5 * G + 3) / 4, 256, 0, stream>>>(readouts, head_w1, head_b1, head_w2, head_b2,
                                               (float*)d_out, G);
}

// Round 5
// 1719.869 us; speedup vs baseline: 3.1131x; 1.4514x over previous
//
#include <hip/hip_runtime.h>
#include <cstdint>
#include <cstddef>

// Sizes (fixed by problem, but N/E/G derived at launch)
static constexpr int HD = 200;   // hidden
static constexpr int NH = 8;     // heads
static constexpr int CD = 25;    // per-head dim
static constexpr int NL = 4;     // layers
static constexpr int NTILE = 13; // 13 x 16 = 208 >= 200 output cols

typedef unsigned int u32;
typedef unsigned int u32x4 __attribute__((ext_vector_type(4)));
typedef float f32x4 __attribute__((ext_vector_type(4)));
typedef __bf16 bf16x8 __attribute__((ext_vector_type(8)));

union U8cast { u32x4 u; bf16x8 b; };
__device__ inline bf16x8 as_bf16x8(u32x4 v) { U8cast x; x.u = v; return x.b; }

// truncation split: a = hi + lo + eps, |eps| <= 2^-16 |a|.
// packs two elements into one u32 (elem0 low 16, elem1 high 16).
__device__ inline void split2(float a0, float a1, u32& hi, u32& lo) {
  u32 u0 = __builtin_bit_cast(u32, a0), u1 = __builtin_bit_cast(u32, a1);
  u32 h0 = u0 & 0xffff0000u, h1 = u1 & 0xffff0000u;
  hi = (u0 >> 16) | h1;
  float r0 = a0 - __builtin_bit_cast(float, h0);
  float r1 = a1 - __builtin_bit_cast(float, h1);
  lo = (__builtin_bit_cast(u32, r0) >> 16) | (__builtin_bit_cast(u32, r1) & 0xffff0000u);
}

// build hi/lo bf16x8 frags from 8 consecutive fp32 (16B-aligned)
__device__ inline void mk_frags(const float* __restrict__ ap, bf16x8& hi8, bf16x8& lo8) {
  f32x4 x0 = *(const f32x4*)ap;
  f32x4 x1 = *(const f32x4*)(ap + 4);
  u32x4 h, l;
  u32 th, tl;
  split2(x0[0], x0[1], th, tl); h[0] = th; l[0] = tl;
  split2(x0[2], x0[3], th, tl); h[1] = th; l[1] = tl;
  split2(x1[0], x1[1], th, tl); h[2] = th; l[2] = tl;
  split2(x1[2], x1[3], th, tl); h[3] = th; l[3] = tl;
  hi8 = as_bf16x8(h); lo8 = as_bf16x8(l);
}

// ---------------- CSR build ----------------
__global__ __launch_bounds__(256) void k_hist(const int* __restrict__ dst, int* __restrict__ cnt, int E) {
  int e = blockIdx.x * 256 + threadIdx.x;
  if (e < E) atomicAdd(&cnt[dst[e]], 1);
}

__global__ __launch_bounds__(256) void k_scan1(const int* __restrict__ cnt, int* __restrict__ off,
                                               int* __restrict__ partial, int N) {
  __shared__ int sm[256];
  int t = threadIdx.x, i = blockIdx.x * 256 + t;
  int v = (i < N) ? cnt[i] : 0;
  sm[t] = v; __syncthreads();
  for (int o = 1; o < 256; o <<= 1) {
    int add = (t >= o) ? sm[t - o] : 0;
    __syncthreads();
    sm[t] += add;
    __syncthreads();
  }
  if (i < N) off[i] = sm[t] - v;            // exclusive
  if (t == 255) partial[blockIdx.x] = sm[255];
}

__global__ __launch_bounds__(512) void k_scan2(int* __restrict__ partial, int nb, int* __restrict__ off, int N) {
  __shared__ int sm[512];
  int t = threadIdx.x;
  int v = (t < nb) ? partial[t] : 0;
  sm[t] = v; __syncthreads();
  for (int o = 1; o < 512; o <<= 1) {
    int add = (t >= o) ? sm[t - o] : 0;
    __syncthreads();
    sm[t] += add;
    __syncthreads();
  }
  if (t < nb) partial[t] = sm[t] - v;       // exclusive block offsets
  if (t == 511) off[N] = sm[511];           // total == E
}

__global__ __launch_bounds__(256) void k_scan3(int* __restrict__ off, const int* __restrict__ partial, int N) {
  int i = blockIdx.x * 256 + threadIdx.x;
  if (i < N) off[i] += partial[i >> 8];
}

__global__ __launch_bounds__(256) void k_scatter(const int* __restrict__ dst, const int* __restrict__ off,
                                                 int* __restrict__ cur, int* __restrict__ eid, int E) {
  int e = blockIdx.x * 256 + threadIdx.x;
  if (e < E) {
    int d = dst[e];
    int p = atomicAdd(&cur[d], 1);
    eid[off[d] + p] = e;
  }
}

// sort each node's edge list ascending -> deterministic float accumulation order everywhere downstream
__global__ __launch_bounds__(256) void k_sort(const int* __restrict__ off, int* __restrict__ eid, int N) {
  int n = blockIdx.x * 256 + threadIdx.x;
  if (n >= N) return;
  int o0 = off[n], o1 = off[n + 1];
  for (int i = o0 + 1; i < o1; ++i) {
    int v = eid[i]; int j = i - 1;
    while (j >= o0 && eid[j] > v) { eid[j + 1] = eid[j]; --j; }
    eid[j + 1] = v;
  }
}

// ---------------- edge-attention precompute (algebraic reductions) ----------------
__global__ __launch_bounds__(128) void k_meanea(const float* __restrict__ ea, const int* __restrict__ off,
                                                const int* __restrict__ eid, float* __restrict__ mea, int N) {
  int n = blockIdx.x * 128 + threadIdx.x;
  if (n >= N) return;
  int o0 = off[n], o1 = off[n + 1];
  float s0 = 0, s1 = 0, s2 = 0, s3 = 0, s4 = 0, s5 = 0;
  for (int p = o0; p < o1; ++p) {
    const float* r = ea + (size_t)eid[p] * 6;
    s0 += r[0]; s1 += r[1]; s2 += r[2]; s3 += r[3]; s4 += r[4]; s5 += r[5];
  }
  float inv = (o1 > o0) ? 1.f / (float)(o1 - o0) : 0.f;
  float* m = mea + (size_t)n * 6;
  m[0] = s0 * inv; m[1] = s1 * inv; m[2] = s2 * inv; m[3] = s3 * inv; m[4] = s4 * inv; m[5] = s5 * inv;
}

// w_e[l][k][h] = sum_c lin_edge_w[l][k][h*25+c] * att_edge[l][h][c]
__global__ __launch_bounds__(256) void k_we(const float* __restrict__ lew, const float* __restrict__ ae,
                                            float* __restrict__ we) {
  int tid = blockIdx.x * 256 + threadIdx.x;
  if (tid >= NL * HD * 8) return;
  int l = tid / (HD * 8); int r = tid % (HD * 8); int k = r >> 3; int hh = r & 7;
  const float* W = lew + (size_t)l * HD * HD + (size_t)k * HD + hh * CD;
  const float* a = ae + l * NH * CD + hh * CD;
  float s = 0.f;
#pragma unroll
  for (int c = 0; c < CD; ++c) s += W[c] * a[c];
  we[tid] = s;   // layout l*1600 + k*8 + hh
}

// M[l][f][h] = sum_k edge_emb_w[f][k] * w_e[l][k][h];  cvec[l][h] = sum_k edge_emb_b[k]*w_e[l][k][h]
__global__ __launch_bounds__(256) void k_M(const float* __restrict__ ew, const float* __restrict__ eb,
                                           const float* __restrict__ we, float* __restrict__ Mm,
                                           float* __restrict__ cv) {
  int tid = threadIdx.x;
  if (tid < NL * 6 * 8) {
    int l = tid / 48, r = tid % 48, f = r / 8, hh = r % 8;
    float s = 0.f;
    for (int k = 0; k < HD; ++k) s += ew[f * HD + k] * we[l * 1600 + k * 8 + hh];
    Mm[tid] = s;   // l*48 + f*8 + hh
  } else if (tid < NL * 6 * 8 + NL * 8) {
    int u = tid - NL * 6 * 8, l = u / 8, hh = u % 8;
    float s = 0.f;
    for (int k = 0; k < HD; ++k) s += eb[k] * we[l * 1600 + k * 8 + hh];
    cv[u] = s;
  }
}

// a_e for real edges, all layers: ae[l][e][h] = edge_attr[e] . M[l][:,h] + cvec[l][h]
__global__ __launch_bounds__(256) void k_ae_edge(const float* __restrict__ ea, const float* __restrict__ Mm,
                                                 const float* __restrict__ cv, float* __restrict__ ae, int E) {
  int e = blockIdx.x * 256 + threadIdx.x;
  if (e >= E) return;
  float v[6];
#pragma unroll
  for (int f = 0; f < 6; ++f) v[f] = ea[(size_t)e * 6 + f];
  for (int l = 0; l < NL; ++l)
#pragma unroll
    for (int hh = 0; hh < 8; ++hh) {
      float s = cv[l * 8 + hh];
#pragma unroll
      for (int f = 0; f < 6; ++f) s += v[f] * Mm[l * 48 + f * 8 + hh];
      ae[(size_t)l * E * 8 + (size_t)e * 8 + hh] = s;
    }
}

// a_e for self loops: loop_attr = deg>0 ? mean_ea@We + be : 0  ->  ae_s = loop_attr @ w_e
__global__ __launch_bounds__(256) void k_ae_self(const float* __restrict__ mea, const int* __restrict__ cnt,
                                                 const float* __restrict__ Mm, const float* __restrict__ cv,
                                                 float* __restrict__ aes, int N) {
  int n = blockIdx.x * 256 + threadIdx.x;
  if (n >= N) return;
  bool has = cnt[n] > 0;
  float v[6];
#pragma unroll
  for (int f = 0; f < 6; ++f) v[f] = mea[(size_t)n * 6 + f];
  for (int l = 0; l < NL; ++l)
#pragma unroll
    for (int hh = 0; hh < 8; ++hh) {
      float s = 0.f;
      if (has) {
        s = cv[l * 8 + hh];
#pragma unroll
        for (int f = 0; f < 6; ++f) s += v[f] * Mm[l * 48 + f * 8 + hh];
      }
      aes[(size_t)l * N * 8 + (size_t)n * 8 + hh] = s;
    }
}

// ---------------- weight split: W[l][K][200] -> WhiT/WloT [l][208 cols][Kpad] bf16 ----------------
// out[c][k] = trunc-split of W[k][c]; zero-padded for c>=200 or k>=K.
__global__ __launch_bounds__(256) void k_split_w(const float* __restrict__ W, u32* __restrict__ hiT,
                                                 u32* __restrict__ loT, int K, int Kpad, int inStride) {
  int l = blockIdx.y;
  int cpr = Kpad >> 1;                       // u32 per column
  int tot = 208 * cpr;
  int idx = blockIdx.x * 256 + threadIdx.x;
  if (idx >= tot) return;
  int c = idx / cpr, kp = (idx % cpr) * 2;
  const float* Wl = W + (size_t)l * inStride;
  float a0 = (c < HD && kp < K) ? Wl[(size_t)kp * HD + c] : 0.f;
  float a1 = (c < HD && kp + 1 < K) ? Wl[(size_t)(kp + 1) * HD + c] : 0.f;
  u32 hi, lo; split2(a0, a1, hi, lo);
  size_t ob = (size_t)l * tot + idx;
  hiT[ob] = hi; loT[ob] = lo;
}

// ---------------- MFMA GEMM: C[M,200] = A[M,K] @ B[K,200] (+bias) (+accumulate) ----------------
// Split-bf16: C ~= Ahi*Bhi + Ahi*Blo + Alo*Bhi (rel err ~2^-16).
// 128 threads = 2 waves; wave owns 32 rows (2 M-tiles of 16) x 13 N-tiles of 16.
// No LDS. B pre-split frag-ready in [208][Kpad] bf16 planes (L2-resident);
// A read fp32 + split on the fly. mfma_f32_16x16x32_bf16:
//   A: row=lane&15, k=8*(lane>>4)+j ; B: col=lane&15, same k ; D: col=lane&15, row=4*(lane>>4)+reg.
__global__ __launch_bounds__(128) void k_gemm_mf(const float* __restrict__ A, const u32* __restrict__ BhiT,
                                                 const u32* __restrict__ BloT, const float* __restrict__ bias,
                                                 float* __restrict__ C, int M, int K, int accumulate) {
  const int lane = threadIdx.x & 63;
  const int w = threadIdx.x >> 6;           // 0..1
  const int lr = lane & 15, kg = lane >> 4;
  const int Kpad = (K + 31) & ~31;
  const int nStep = Kpad >> 5;
  const int bstride = Kpad >> 1;            // u32 per B column

  const int rowA0 = blockIdx.x * 64 + w * 32 + lr;       // M-tile 0 row this lane loads
  const int rowA1 = rowA0 + 16;                          // M-tile 1
  const float* Ap0 = A + (size_t)((rowA0 < M) ? rowA0 : (M - 1)) * K;
  const float* Ap1 = A + (size_t)((rowA1 < M) ? rowA1 : (M - 1)) * K;

  f32x4 acc[2][NTILE];
#pragma unroll
  for (int mt = 0; mt < 2; ++mt)
#pragma unroll
    for (int t = 0; t < NTILE; ++t) acc[mt][t] = (f32x4)0.f;

  u32x4 zz; zz[0] = 0; zz[1] = 0; zz[2] = 0; zz[3] = 0;
  const bf16x8 zfrag = as_bf16x8(zz);

  for (int ks = 0; ks < nStep; ++ks) {
    const int kb = ks * 32;
    const int k0 = kb + kg * 8;             // this lane's 8 consecutive k
    bf16x8 ah0, al0, ah1, al1;
    if (k0 < K) {                           // K%8==0 in all our shapes -> full 8 valid
      mk_frags(Ap0 + k0, ah0, al0);
      mk_frags(Ap1 + k0, ah1, al1);
    } else {
      ah0 = zfrag; al0 = zfrag; ah1 = zfrag; al1 = zfrag;
    }
    const u32* Bh = BhiT + (kb >> 1) + kg * 4;
    const u32* Bl = BloT + (kb >> 1) + kg * 4;
#pragma unroll
    for (int t = 0; t < NTILE; ++t) {
      const size_t cb = (size_t)(t * 16 + lr) * bstride;
      bf16x8 bh = as_bf16x8(*(const u32x4*)(Bh + cb));
      bf16x8 bl = as_bf16x8(*(const u32x4*)(Bl + cb));
      acc[0][t] = __builtin_amdgcn_mfma_f32_16x16x32_bf16(ah0, bh, acc[0][t], 0, 0, 0);
      acc[0][t] = __builtin_amdgcn_mfma_f32_16x16x32_bf16(ah0, bl, acc[0][t], 0, 0, 0);
      acc[0][t] = __builtin_amdgcn_mfma_f32_16x16x32_bf16(al0, bh, acc[0][t], 0, 0, 0);
      acc[1][t] = __builtin_amdgcn_mfma_f32_16x16x32_bf16(ah1, bh, acc[1][t], 0, 0, 0);
      acc[1][t] = __builtin_amdgcn_mfma_f32_16x16x32_bf16(ah1, bl, acc[1][t], 0, 0, 0);
      acc[1][t] = __builtin_amdgcn_mfma_f32_16x16x32_bf16(al1, bh, acc[1][t], 0, 0, 0);
    }
  }

  // epilogue: D col = lane&15, row = 4*(lane>>4)+reg (within 16-row tile)
#pragma unroll
  for (int mt = 0; mt < 2; ++mt) {
    const int rbase = blockIdx.x * 64 + w * 32 + mt * 16 + kg * 4;
#pragma unroll
    for (int t = 0; t < NTILE; ++t) {
      const int c = t * 16 + lr;
      if (c < HD) {
        const float badd = bias ? bias[c] : 0.f;
#pragma unroll
        for (int j = 0; j < 4; ++j) {
          const int r = rbase + j;
          if (r < M) {
            float v = acc[mt][t][j] + badd;
            if (accumulate) v += C[(size_t)r * HD + c];
            C[(size_t)r * HD + c] = v;
          }
        }
      }
    }
  }
}

// a_src[n,h] = sum_c xs[n,h*25+c]*att_src[h,c]; same for a_dst
__global__ __launch_bounds__(256) void k_asrcdst(const float* __restrict__ xs, const float* __restrict__ as_l,
                                                 const float* __restrict__ ad_l, float* __restrict__ a_src,
                                                 float* __restrict__ a_dst, int N) {
  int tid = blockIdx.x * 256 + threadIdx.x;
  if (tid >= N * 8) return;
  int n = tid >> 3, hh = tid & 7;
  const float* xr = xs + (size_t)n * HD + hh * CD;
  const float* sa = as_l + hh * CD;
  const float* da = ad_l + hh * CD;
  float s = 0.f, d = 0.f;
#pragma unroll
  for (int c = 0; c < CD; ++c) { float v = xr[c]; s += v * sa[c]; d += v * da[c]; }
  a_src[tid] = s; a_dst[tid] = d;
}

// ---------------- per-dst-node softmax aggregation; one wave per node ----------------
__global__ __launch_bounds__(256) void k_aggr(const float* __restrict__ xs, const float* __restrict__ a_src,
                                              const float* __restrict__ a_dst, const float* __restrict__ ae_e,
                                              const float* __restrict__ ae_s, const float* __restrict__ gb,
                                              const int* __restrict__ off, const int* __restrict__ eid,
                                              const int* __restrict__ esrc, float* __restrict__ h_out, int N) {
  int lane = threadIdx.x & 63;
  int node = blockIdx.x * 4 + (threadIdx.x >> 6);
  if (node >= N) return;
  int o0 = off[node], o1 = off[node + 1];
  // column->head mapping for this lane's 4 owned columns (lane, +64, +128, +192)
  int hh0 = lane / 25, hh1 = (lane + 64) / 25, hh2 = (lane + 128) / 25, hh3 = (lane + 192) / 25;
  float adsth = 0.f, aself = 0.f, aes = 0.f, mx = -1e30f;
  if (lane < 8) {
    adsth = a_dst[(size_t)node * 8 + lane];
    aself = a_src[(size_t)node * 8 + lane];
    aes   = ae_s[(size_t)node * 8 + lane];
    float l0 = aself + adsth + aes;
    mx = (l0 >= 0.f) ? l0 : 0.2f * l0;
  }
  // pass 1: max logit per head (lanes 0..7)
  for (int p = o0; p < o1; ++p) {
    int e = eid[p], s = esrc[e];
    if (lane < 8) {
      float l0 = a_src[(size_t)s * 8 + lane] + adsth + ae_e[(size_t)e * 8 + lane];
      l0 = (l0 >= 0.f) ? l0 : 0.2f * l0;
      mx = fmaxf(mx, l0);
    }
  }
  // pass 2: exp-weights (lanes 0..7), broadcast via shuffle, accumulate columns
  float acc0 = 0.f, acc1 = 0.f, acc2 = 0.f, acc3 = 0.f, ssum = 0.f;
  {
    float w = 0.f;
    if (lane < 8) {
      float l0 = aself + adsth + aes;
      l0 = (l0 >= 0.f) ? l0 : 0.2f * l0;
      w = expf(l0 - mx); ssum += w;
    }
    float wa = __shfl(w, hh0), wb = __shfl(w, hh1), wc = __shfl(w, hh2), wd = __shfl(w, hh3);
    const float* xr = xs + (size_t)node * HD;
    acc0 += wa * xr[lane]; acc1 += wb * xr[lane + 64]; acc2 += wc * xr[lane + 128];
    if (lane < 8) acc3 += wd * xr[lane + 192];
  }
  for (int p = o0; p < o1; ++p) {
    int e = eid[p], s = esrc[e];
    float w = 0.f;
    if (lane < 8) {
      float l0 = a_src[(size_t)s * 8 + lane] + adsth + ae_e[(size_t)e * 8 + lane];
      l0 = (l0 >= 0.f) ? l0 : 0.2f * l0;
      w = expf(l0 - mx); ssum += w;
    }
    float wa = __shfl(w, hh0), wb = __shfl(w, hh1), wc = __shfl(w, hh2), wd = __shfl(w, hh3);
    const float* xr = xs + (size_t)s * HD;
    acc0 += wa * xr[lane]; acc1 += wb * xr[lane + 64]; acc2 += wc * xr[lane + 128];
    if (lane < 8) acc3 += wd * xr[lane + 192];
  }
  float sa = __shfl(ssum, hh0) + 1e-16f, sb = __shfl(ssum, hh1) + 1e-16f;
  float sc = __shfl(ssum, hh2) + 1e-16f, sd = __shfl(ssum, hh3) + 1e-16f;
  float* ho = h_out + (size_t)node * HD;
  ho[lane]       = acc0 / sa + gb[lane];
  ho[lane + 64]  = acc1 / sb + gb[lane + 64];
  ho[lane + 128] = acc2 / sc + gb[lane + 128];
  if (lane < 8) ho[lane + 192] = acc3 / sd + gb[lane + 192];
}

// graph start offsets from sorted batch
__global__ __launch_bounds__(256) void k_gstart(const int* __restrict__ batch, int* __restrict__ gstart,
                                                int N, int G) {
  int i = blockIdx.x * 256 + threadIdx.x;
  if (i >= N) return;
  int b = batch[i];
  int pb = (i == 0) ? -1 : batch[i - 1];
  for (int g = pb + 1; g <= b; ++g) gstart[g] = i;
  if (i == N - 1) for (int g = b + 1; g <= G; ++g) gstart[g] = N;
}

__global__ __launch_bounds__(256) void k_pool(const float* __restrict__ h, const int* __restrict__ gstart,
                                              float* __restrict__ pooled, int G) {
  int g = blockIdx.x, c = threadIdx.x;
  if (c >= HD) return;
  int s0 = gstart[g], s1 = gstart[g + 1];
  float acc = 0.f;
  for (int i = s0; i < s1; ++i) acc += h[(size_t)i * HD + c];
  pooled[(size_t)g * HD + c] = acc;
}

// task heads: one wave per (t,g)
__global__ __launch_bounds__(256) void k_heads(const float* __restrict__ ro, const float* __restrict__ w1,
                                               const float* __restrict__ b1, const float* __restrict__ w2,
                                               const float* __restrict__ b2, float* __restrict__ out, int G) {
  int lane = threadIdx.x & 63;
  int idx = blockIdx.x * 4 + (threadIdx.x >> 6);
  if (idx >= 5 * G) return;
  int t = idx / G, g = idx % G;
  const float* r = ro + (size_t)g * HD;
  const float* W = w1 + (size_t)t * HD * 100;
  bool has2 = lane < 36;
  float h0 = 0.f, h1 = 0.f;
  for (int k = 0; k < HD; ++k) {
    float rv = r[k];
    h0 += rv * W[k * 100 + lane];
    if (has2) h1 += rv * W[k * 100 + 64 + lane];
  }
  h0 += b1[t * 100 + lane];
  h0 = h0 > 0.f ? h0 : 0.f;
  float p = h0 * w2[t * 100 + lane];
  if (has2) {
    h1 += b1[t * 100 + 64 + lane];
    h1 = h1 > 0.f ? h1 : 0.f;
    p += h1 * w2[t * 100 + 64 + lane];
  }
  for (int o = 32; o >= 1; o >>= 1) p += __shfl_down(p, o);
  if (lane == 0) {
    float z = p + b2[t];
    bool sig = (t == 0) | (t == 3) | (t == 4);   // SIG = {1,0,0,1,1}
    out[idx] = sig ? 1.f / (1.f + expf(-z)) : z;
  }
}

extern "C" void kernel_launch(void* const* d_in, const int* in_sizes, int n_in,
                              void* d_out, int out_size, void* d_ws, size_t ws_size,
                              hipStream_t stream) {
  const float* x         = (const float*)d_in[0];
  const float* edge_attr = (const float*)d_in[1];
  const float* node_w    = (const float*)d_in[2];
  const float* node_b    = (const float*)d_in[3];
  const float* edge_w    = (const float*)d_in[4];
  const float* edge_b    = (const float*)d_in[5];
  const float* lin_w     = (const float*)d_in[6];
  const float* lin_edge_w= (const float*)d_in[7];
  const float* att_src   = (const float*)d_in[8];
  const float* att_dst   = (const float*)d_in[9];
  const float* att_edge  = (const float*)d_in[10];
  const float* gat_bias  = (const float*)d_in[11];
  const float* readout_w = (const float*)d_in[12];
  const float* readout_b = (const float*)d_in[13];
  const float* head_w1   = (const float*)d_in[14];
  const float* head_b1   = (const float*)d_in[15];
  const float* head_w2   = (const float*)d_in[16];
  const float* head_b2   = (const float*)d_in[17];
  const int*   edge_index= (const int*)d_in[18];
  const int*   batch     = (const int*)d_in[19];

  const int N = in_sizes[0] / 64;
  const int E = in_sizes[1] / 6;
  const int G = out_size / 5;
  const int* srcI = edge_index;
  const int* dstI = edge_index + E;

  char* wsb = (char*)d_ws;
  size_t o = 0;
  auto alloc = [&](size_t bytes) -> void* {
    void* p = wsb + o;
    o = (o + bytes + 255) & ~(size_t)255;
    return p;
  };
  float* h       = (float*)alloc((size_t)N * HD * 4);
  float* xs      = (float*)alloc((size_t)N * HD * 4);
  float* a_src   = (float*)alloc((size_t)N * 8 * 4);
  float* a_dst   = (float*)alloc((size_t)N * 8 * 4);
  float* ae_e    = (float*)alloc((size_t)NL * E * 8 * 4);
  float* ae_s    = (float*)alloc((size_t)NL * N * 8 * 4);
  float* mean_ea = (float*)alloc((size_t)N * 6 * 4);
  float* we      = (float*)alloc((size_t)NL * HD * 8 * 4);
  float* Mm      = (float*)alloc((size_t)NL * 6 * 8 * 4);
  float* cv      = (float*)alloc((size_t)NL * 8 * 4);
  int* cnt       = (int*)alloc((size_t)N * 4);
  int* cur       = (int*)alloc((size_t)N * 4);
  int* off       = (int*)alloc((size_t)(N + 1) * 4);
  int* partial   = (int*)alloc(512 * 4);
  int* eid       = (int*)alloc((size_t)E * 4);
  int* gstart    = (int*)alloc((size_t)(G + 1) * 4);
  float* pooled  = (float*)alloc((size_t)G * HD * 4);
  float* readouts= (float*)alloc((size_t)G * HD * 4);
  // split-weight planes (u32 = 2 bf16)
  u32* nodeW_hi  = (u32*)alloc(208 * 32 * 4);            // [208][64] bf16
  u32* nodeW_lo  = (u32*)alloc(208 * 32 * 4);
  u32* linW_hi   = (u32*)alloc((size_t)NL * 208 * 112 * 4);   // [l][208][224] bf16
  u32* linW_lo   = (u32*)alloc((size_t)NL * 208 * 112 * 4);
  u32* roW_hi    = (u32*)alloc((size_t)NL * 208 * 112 * 4);
  u32* roW_lo    = (u32*)alloc((size_t)NL * 208 * 112 * 4);
  (void)ws_size; (void)n_in;

  hipMemsetAsync(cnt, 0, (size_t)N * 4, stream);
  hipMemsetAsync(cur, 0, (size_t)N * 4, stream);
  hipMemsetAsync(readouts, 0, (size_t)G * HD * 4, stream);

  int nb = (N + 255) / 256;
  k_hist<<<(E + 255) / 256, 256, 0, stream>>>(dstI, cnt, E);
  k_scan1<<<nb, 256, 0, stream>>>(cnt, off, partial, N);
  k_scan2<<<1, 512, 0, stream>>>(partial, nb, off, N);
  k_scan3<<<nb, 256, 0, stream>>>(off, partial, N);
  k_scatter<<<(E + 255) / 256, 256, 0, stream>>>(dstI, off, cur, eid, E);
  k_sort<<<nb, 256, 0, stream>>>(off, eid, N);
  k_meanea<<<(N + 127) / 128, 128, 0, stream>>>(edge_attr, off, eid, mean_ea, N);
  k_we<<<(NL * HD * 8 + 255) / 256, 256, 0, stream>>>(lin_edge_w, att_edge, we);
  k_M<<<1, 256, 0, stream>>>(edge_w, edge_b, we, Mm, cv);
  k_ae_edge<<<(E + 255) / 256, 256, 0, stream>>>(edge_attr, Mm, cv, ae_e, E);
  k_ae_self<<<(N + 255) / 256, 256, 0, stream>>>(mean_ea, cnt, Mm, cv, ae_s, N);

  // weight splits
  {
    dim3 g1((208 * 32 + 255) / 256, 1);
    k_split_w<<<g1, 256, 0, stream>>>(node_w, nodeW_hi, nodeW_lo, 64, 64, 0);
    dim3 g2((208 * 112 + 255) / 256, NL);
    k_split_w<<<g2, 256, 0, stream>>>(lin_w, linW_hi, linW_lo, HD, 224, HD * HD);
    k_split_w<<<g2, 256, 0, stream>>>(readout_w, roW_hi, roW_lo, HD, 224, HD * HD);
  }

  const int gemmBlocksN = (N + 63) / 64;
  k_gemm_mf<<<gemmBlocksN, 128, 0, stream>>>(x, nodeW_hi, nodeW_lo, node_b, h, N, 64, 0);
  k_gstart<<<nb, 256, 0, stream>>>(batch, gstart, N, G);

  for (int l = 0; l < NL; ++l) {
    k_gemm_mf<<<gemmBlocksN, 128, 0, stream>>>(h, linW_hi + (size_t)l * 208 * 112,
                                               linW_lo + (size_t)l * 208 * 112, nullptr, xs, N, HD, 0);
    k_asrcdst<<<(N * 8 + 255) / 256, 256, 0, stream>>>(xs, att_src + l * NH * CD, att_dst + l * NH * CD,
                                                       a_src, a_dst, N);
    k_aggr<<<(N + 3) / 4, 256, 0, stream>>>(xs, a_src, a_dst, ae_e + (size_t)l * E * 8,
                                            ae_s + (size_t)l * N * 8, gat_bias + l * HD,
                                            off, eid, srcI, h, N);
    k_pool<<<G, 256, 0, stream>>>(h, gstart, pooled, G);
    k_gemm_mf<<<(G + 63) / 64, 128, 0, stream>>>(pooled, roW_hi + (size_t)l * 208 * 112,
                                                 roW_lo + (size_t)l * 208 * 112, readout_b + l * HD,
                                                 readouts, G, HD, 1);
  }
  k_heads<<<(5 * G + 3) / 4, 256, 0, stream>>>(readouts, head_w1, head_b1, head_w2, head_b2,
                                               (float*)d_out, G);
}

// Round 6
// 1551.055 us; speedup vs baseline: 3.4519x; 1.1088x over previous
//
#include <hip/hip_runtime.h>
#include <cstdint>
#include <cstddef>

// Sizes (fixed by problem, but N/E/G derived at launch)
static constexpr int HD = 200;   // hidden
static constexpr int NH = 8;     // heads
static constexpr int CD = 25;    // per-head dim
static constexpr int NL = 4;     // layers
static constexpr int NTILE = 13; // 13 x 16 = 208 >= 200 output cols

typedef unsigned int u32;
typedef unsigned int u32x4 __attribute__((ext_vector_type(4)));
typedef float f32x4 __attribute__((ext_vector_type(4)));
typedef __bf16 bf16x8 __attribute__((ext_vector_type(8)));

union U8cast { u32x4 u; bf16x8 b; };
__device__ inline bf16x8 as_bf16x8(u32x4 v) { U8cast x; x.u = v; return x.b; }

// truncation split: a = hi + lo + eps, |eps| <= 2^-16 |a|.
// packs two elements into one u32 (elem0 low 16, elem1 high 16).
__device__ inline void split2(float a0, float a1, u32& hi, u32& lo) {
  u32 u0 = __builtin_bit_cast(u32, a0), u1 = __builtin_bit_cast(u32, a1);
  u32 h0 = u0 & 0xffff0000u, h1 = u1 & 0xffff0000u;
  hi = (u0 >> 16) | h1;
  float r0 = a0 - __builtin_bit_cast(float, h0);
  float r1 = a1 - __builtin_bit_cast(float, h1);
  lo = (__builtin_bit_cast(u32, r0) >> 16) | (__builtin_bit_cast(u32, r1) & 0xffff0000u);
}

// build hi/lo bf16x8 frags from 8 consecutive fp32 (16B-aligned)
__device__ inline void mk_frags(const float* __restrict__ ap, bf16x8& hi8, bf16x8& lo8) {
  f32x4 x0 = *(const f32x4*)ap;
  f32x4 x1 = *(const f32x4*)(ap + 4);
  u32x4 h, l;
  u32 th, tl;
  split2(x0[0], x0[1], th, tl); h[0] = th; l[0] = tl;
  split2(x0[2], x0[3], th, tl); h[1] = th; l[1] = tl;
  split2(x1[0], x1[1], th, tl); h[2] = th; l[2] = tl;
  split2(x1[2], x1[3], th, tl); h[3] = th; l[3] = tl;
  hi8 = as_bf16x8(h); lo8 = as_bf16x8(l);
}

// ---------------- CSR build ----------------
__global__ __launch_bounds__(256) void k_hist(const int* __restrict__ dst, int* __restrict__ cnt, int E) {
  int e = blockIdx.x * 256 + threadIdx.x;
  if (e < E) atomicAdd(&cnt[dst[e]], 1);
}

__global__ __launch_bounds__(256) void k_scan1(const int* __restrict__ cnt, int* __restrict__ off,
                                               int* __restrict__ partial, int N) {
  __shared__ int sm[256];
  int t = threadIdx.x, i = blockIdx.x * 256 + t;
  int v = (i < N) ? cnt[i] : 0;
  sm[t] = v; __syncthreads();
  for (int o = 1; o < 256; o <<= 1) {
    int add = (t >= o) ? sm[t - o] : 0;
    __syncthreads();
    sm[t] += add;
    __syncthreads();
  }
  if (i < N) off[i] = sm[t] - v;            // exclusive
  if (t == 255) partial[blockIdx.x] = sm[255];
}

__global__ __launch_bounds__(512) void k_scan2(int* __restrict__ partial, int nb, int* __restrict__ off, int N) {
  __shared__ int sm[512];
  int t = threadIdx.x;
  int v = (t < nb) ? partial[t] : 0;
  sm[t] = v; __syncthreads();
  for (int o = 1; o < 512; o <<= 1) {
    int add = (t >= o) ? sm[t - o] : 0;
    __syncthreads();
    sm[t] += add;
    __syncthreads();
  }
  if (t < nb) partial[t] = sm[t] - v;       // exclusive block offsets
  if (t == 511) off[N] = sm[511];           // total == E
}

__global__ __launch_bounds__(256) void k_scan3(int* __restrict__ off, const int* __restrict__ partial, int N) {
  int i = blockIdx.x * 256 + threadIdx.x;
  if (i < N) off[i] += partial[i >> 8];
}

__global__ __launch_bounds__(256) void k_scatter(const int* __restrict__ dst, const int* __restrict__ off,
                                                 int* __restrict__ cur, int* __restrict__ eid, int E) {
  int e = blockIdx.x * 256 + threadIdx.x;
  if (e < E) {
    int d = dst[e];
    int p = atomicAdd(&cur[d], 1);
    eid[off[d] + p] = e;
  }
}

// sort each node's edge list ascending -> deterministic float accumulation order everywhere downstream
__global__ __launch_bounds__(256) void k_sort(const int* __restrict__ off, int* __restrict__ eid, int N) {
  int n = blockIdx.x * 256 + threadIdx.x;
  if (n >= N) return;
  int o0 = off[n], o1 = off[n + 1];
  for (int i = o0 + 1; i < o1; ++i) {
    int v = eid[i]; int j = i - 1;
    while (j >= o0 && eid[j] > v) { eid[j + 1] = eid[j]; --j; }
    eid[j + 1] = v;
  }
}

// ---------------- edge-attention precompute (algebraic reductions) ----------------
__global__ __launch_bounds__(128) void k_meanea(const float* __restrict__ ea, const int* __restrict__ off,
                                                const int* __restrict__ eid, float* __restrict__ mea, int N) {
  int n = blockIdx.x * 128 + threadIdx.x;
  if (n >= N) return;
  int o0 = off[n], o1 = off[n + 1];
  float s0 = 0, s1 = 0, s2 = 0, s3 = 0, s4 = 0, s5 = 0;
  for (int p = o0; p < o1; ++p) {
    const float* r = ea + (size_t)eid[p] * 6;
    s0 += r[0]; s1 += r[1]; s2 += r[2]; s3 += r[3]; s4 += r[4]; s5 += r[5];
  }
  float inv = (o1 > o0) ? 1.f / (float)(o1 - o0) : 0.f;
  float* m = mea + (size_t)n * 6;
  m[0] = s0 * inv; m[1] = s1 * inv; m[2] = s2 * inv; m[3] = s3 * inv; m[4] = s4 * inv; m[5] = s5 * inv;
}

// w_e[l][k][h] = sum_c lin_edge_w[l][k][h*25+c] * att_edge[l][h][c]
__global__ __launch_bounds__(256) void k_we(const float* __restrict__ lew, const float* __restrict__ ae,
                                            float* __restrict__ we) {
  int tid = blockIdx.x * 256 + threadIdx.x;
  if (tid >= NL * HD * 8) return;
  int l = tid / (HD * 8); int r = tid % (HD * 8); int k = r >> 3; int hh = r & 7;
  const float* W = lew + (size_t)l * HD * HD + (size_t)k * HD + hh * CD;
  const float* a = ae + l * NH * CD + hh * CD;
  float s = 0.f;
#pragma unroll
  for (int c = 0; c < CD; ++c) s += W[c] * a[c];
  we[tid] = s;   // layout l*1600 + k*8 + hh
}

// M[l][f][h] = sum_k edge_emb_w[f][k] * w_e[l][k][h];  cvec[l][h] = sum_k edge_emb_b[k]*w_e[l][k][h]
__global__ __launch_bounds__(256) void k_M(const float* __restrict__ ew, const float* __restrict__ eb,
                                           const float* __restrict__ we, float* __restrict__ Mm,
                                           float* __restrict__ cv) {
  int tid = threadIdx.x;
  if (tid < NL * 6 * 8) {
    int l = tid / 48, r = tid % 48, f = r / 8, hh = r % 8;
    float s = 0.f;
    for (int k = 0; k < HD; ++k) s += ew[f * HD + k] * we[l * 1600 + k * 8 + hh];
    Mm[tid] = s;   // l*48 + f*8 + hh
  } else if (tid < NL * 6 * 8 + NL * 8) {
    int u = tid - NL * 6 * 8, l = u / 8, hh = u % 8;
    float s = 0.f;
    for (int k = 0; k < HD; ++k) s += eb[k] * we[l * 1600 + k * 8 + hh];
    cv[u] = s;
  }
}

// a_e for real edges, all layers: ae[l][e][h] = edge_attr[e] . M[l][:,h] + cvec[l][h]
__global__ __launch_bounds__(256) void k_ae_edge(const float* __restrict__ ea, const float* __restrict__ Mm,
                                                 const float* __restrict__ cv, float* __restrict__ ae, int E) {
  int e = blockIdx.x * 256 + threadIdx.x;
  if (e >= E) return;
  float v[6];
#pragma unroll
  for (int f = 0; f < 6; ++f) v[f] = ea[(size_t)e * 6 + f];
  for (int l = 0; l < NL; ++l)
#pragma unroll
    for (int hh = 0; hh < 8; ++hh) {
      float s = cv[l * 8 + hh];
#pragma unroll
      for (int f = 0; f < 6; ++f) s += v[f] * Mm[l * 48 + f * 8 + hh];
      ae[(size_t)l * E * 8 + (size_t)e * 8 + hh] = s;
    }
}

// a_e for self loops: loop_attr = deg>0 ? mean_ea@We + be : 0  ->  ae_s = loop_attr @ w_e
__global__ __launch_bounds__(256) void k_ae_self(const float* __restrict__ mea, const int* __restrict__ cnt,
                                                 const float* __restrict__ Mm, const float* __restrict__ cv,
                                                 float* __restrict__ aes, int N) {
  int n = blockIdx.x * 256 + threadIdx.x;
  if (n >= N) return;
  bool has = cnt[n] > 0;
  float v[6];
#pragma unroll
  for (int f = 0; f < 6; ++f) v[f] = mea[(size_t)n * 6 + f];
  for (int l = 0; l < NL; ++l)
#pragma unroll
    for (int hh = 0; hh < 8; ++hh) {
      float s = 0.f;
      if (has) {
        s = cv[l * 8 + hh];
#pragma unroll
        for (int f = 0; f < 6; ++f) s += v[f] * Mm[l * 48 + f * 8 + hh];
      }
      aes[(size_t)l * N * 8 + (size_t)n * 8 + hh] = s;
    }
}

// ---------------- weight split: W[l][K][200] -> WhiT/WloT [l][208 cols][Kpad] bf16 ----------------
// out[c][k] = trunc-split of W[k][c]; zero-padded for c>=200 or k>=K.
__global__ __launch_bounds__(256) void k_split_w(const float* __restrict__ W, u32* __restrict__ hiT,
                                                 u32* __restrict__ loT, int K, int Kpad, int inStride) {
  int l = blockIdx.y;
  int cpr = Kpad >> 1;                       // u32 per column
  int tot = 208 * cpr;
  int idx = blockIdx.x * 256 + threadIdx.x;
  if (idx >= tot) return;
  int c = idx / cpr, kp = (idx % cpr) * 2;
  const float* Wl = W + (size_t)l * inStride;
  float a0 = (c < HD && kp < K) ? Wl[(size_t)kp * HD + c] : 0.f;
  float a1 = (c < HD && kp + 1 < K) ? Wl[(size_t)(kp + 1) * HD + c] : 0.f;
  u32 hi, lo; split2(a0, a1, hi, lo);
  size_t ob = (size_t)l * tot + idx;
  hiT[ob] = hi; loT[ob] = lo;
}

// head W1 split: head_w1 [5][200][100] -> planes [t][112 cols][224 k] bf16
__global__ __launch_bounds__(256) void k_split_hw(const float* __restrict__ W, u32* __restrict__ hiT,
                                                  u32* __restrict__ loT) {
  int t = blockIdx.y;
  int idx = blockIdx.x * 256 + threadIdx.x;
  if (idx >= 112 * 112) return;              // col * (224/2 u32)
  int c = idx / 112, kp = (idx % 112) * 2;
  const float* Wt = W + (size_t)t * HD * 100;
  float a0 = (c < 100 && kp < HD) ? Wt[(size_t)kp * 100 + c] : 0.f;
  float a1 = (c < 100 && kp + 1 < HD) ? Wt[(size_t)(kp + 1) * 100 + c] : 0.f;
  u32 hi, lo; split2(a0, a1, hi, lo);
  size_t ob = (size_t)t * 112 * 112 + idx;
  hiT[ob] = hi; loT[ob] = lo;
}

// ---------------- MFMA GEMM: C[M,200] = A[M,K] @ B[K,200] (+bias) (+accumulate) ----------------
// Split-bf16: C ~= Ahi*Bhi + Ahi*Blo + Alo*Bhi (rel err ~2^-16).
// 128 threads = 2 waves; wave owns 32 rows (2 M-tiles of 16) x 13 N-tiles of 16.
// No LDS. B pre-split frag-ready in [208][Kpad] bf16 planes (L2-resident);
// A read fp32 + split on the fly. mfma_f32_16x16x32_bf16:
//   A: row=lane&15, k=8*(lane>>4)+j ; B: col=lane&15, same k ; D: col=lane&15, row=4*(lane>>4)+reg.
__global__ __launch_bounds__(128) void k_gemm_mf(const float* __restrict__ A, const u32* __restrict__ BhiT,
                                                 const u32* __restrict__ BloT, const float* __restrict__ bias,
                                                 float* __restrict__ C, int M, int K, int accumulate) {
  const int lane = threadIdx.x & 63;
  const int w = threadIdx.x >> 6;           // 0..1
  const int lr = lane & 15, kg = lane >> 4;
  const int Kpad = (K + 31) & ~31;
  const int nStep = Kpad >> 5;
  const int bstride = Kpad >> 1;            // u32 per B column

  const int rowA0 = blockIdx.x * 64 + w * 32 + lr;       // M-tile 0 row this lane loads
  const int rowA1 = rowA0 + 16;                          // M-tile 1
  const float* Ap0 = A + (size_t)((rowA0 < M) ? rowA0 : (M - 1)) * K;
  const float* Ap1 = A + (size_t)((rowA1 < M) ? rowA1 : (M - 1)) * K;

  f32x4 acc[2][NTILE];
#pragma unroll
  for (int mt = 0; mt < 2; ++mt)
#pragma unroll
    for (int t = 0; t < NTILE; ++t) acc[mt][t] = (f32x4)0.f;

  u32x4 zz; zz[0] = 0; zz[1] = 0; zz[2] = 0; zz[3] = 0;
  const bf16x8 zfrag = as_bf16x8(zz);

  for (int ks = 0; ks < nStep; ++ks) {
    const int kb = ks * 32;
    const int k0 = kb + kg * 8;             // this lane's 8 consecutive k
    bf16x8 ah0, al0, ah1, al1;
    if (k0 < K) {                           // K%8==0 in all our shapes -> full 8 valid
      mk_frags(Ap0 + k0, ah0, al0);
      mk_frags(Ap1 + k0, ah1, al1);
    } else {
      ah0 = zfrag; al0 = zfrag; ah1 = zfrag; al1 = zfrag;
    }
    const u32* Bh = BhiT + (kb >> 1) + kg * 4;
    const u32* Bl = BloT + (kb >> 1) + kg * 4;
#pragma unroll
    for (int t = 0; t < NTILE; ++t) {
      const size_t cb = (size_t)(t * 16 + lr) * bstride;
      bf16x8 bh = as_bf16x8(*(const u32x4*)(Bh + cb));
      bf16x8 bl = as_bf16x8(*(const u32x4*)(Bl + cb));
      acc[0][t] = __builtin_amdgcn_mfma_f32_16x16x32_bf16(ah0, bh, acc[0][t], 0, 0, 0);
      acc[0][t] = __builtin_amdgcn_mfma_f32_16x16x32_bf16(ah0, bl, acc[0][t], 0, 0, 0);
      acc[0][t] = __builtin_amdgcn_mfma_f32_16x16x32_bf16(al0, bh, acc[0][t], 0, 0, 0);
      acc[1][t] = __builtin_amdgcn_mfma_f32_16x16x32_bf16(ah1, bh, acc[1][t], 0, 0, 0);
      acc[1][t] = __builtin_amdgcn_mfma_f32_16x16x32_bf16(ah1, bl, acc[1][t], 0, 0, 0);
      acc[1][t] = __builtin_amdgcn_mfma_f32_16x16x32_bf16(al1, bh, acc[1][t], 0, 0, 0);
    }
  }

  // epilogue: D col = lane&15, row = 4*(lane>>4)+reg (within 16-row tile)
#pragma unroll
  for (int mt = 0; mt < 2; ++mt) {
    const int rbase = blockIdx.x * 64 + w * 32 + mt * 16 + kg * 4;
#pragma unroll
    for (int t = 0; t < NTILE; ++t) {
      const int c = t * 16 + lr;
      if (c < HD) {
        const float badd = bias ? bias[c] : 0.f;
#pragma unroll
        for (int j = 0; j < 4; ++j) {
          const int r = rbase + j;
          if (r < M) {
            float v = acc[mt][t][j] + badd;
            if (accumulate) v += C[(size_t)r * HD + c];
            C[(size_t)r * HD + c] = v;
          }
        }
      }
    }
  }
}

// ---------------- head GEMM: z[t] = relu(readouts @ W1[t] + b1[t]), z [5][G][112] ----------------
// Same split-bf16 no-LDS structure; 7 N-tiles (112 >= 100 cols), task = blockIdx.y.
__global__ __launch_bounds__(128) void k_headgemm(const float* __restrict__ A, const u32* __restrict__ hwHi,
                                                  const u32* __restrict__ hwLo, const float* __restrict__ b1,
                                                  float* __restrict__ z, int M) {
  const int task = blockIdx.y;
  const int lane = threadIdx.x & 63;
  const int w = threadIdx.x >> 6;
  const int lr = lane & 15, kg = lane >> 4;
  const int K = HD;                          // 200
  const int nStep = 7;                       // 224/32
  const int bstride = 112;                   // u32 per col (224 bf16)

  const int rowA0 = blockIdx.x * 64 + w * 32 + lr;
  const int rowA1 = rowA0 + 16;
  const float* Ap0 = A + (size_t)((rowA0 < M) ? rowA0 : (M - 1)) * K;
  const float* Ap1 = A + (size_t)((rowA1 < M) ? rowA1 : (M - 1)) * K;
  const u32* BhT = hwHi + (size_t)task * 112 * 112;
  const u32* BlT = hwLo + (size_t)task * 112 * 112;

  f32x4 acc[2][7];
#pragma unroll
  for (int mt = 0; mt < 2; ++mt)
#pragma unroll
    for (int t = 0; t < 7; ++t) acc[mt][t] = (f32x4)0.f;

  u32x4 zz; zz[0] = 0; zz[1] = 0; zz[2] = 0; zz[3] = 0;
  const bf16x8 zfrag = as_bf16x8(zz);

  for (int ks = 0; ks < nStep; ++ks) {
    const int kb = ks * 32;
    const int k0 = kb + kg * 8;
    bf16x8 ah0, al0, ah1, al1;
    if (k0 < K) {
      mk_frags(Ap0 + k0, ah0, al0);
      mk_frags(Ap1 + k0, ah1, al1);
    } else {
      ah0 = zfrag; al0 = zfrag; ah1 = zfrag; al1 = zfrag;
    }
    const u32* Bh = BhT + (kb >> 1) + kg * 4;
    const u32* Bl = BlT + (kb >> 1) + kg * 4;
#pragma unroll
    for (int t = 0; t < 7; ++t) {
      const size_t cb = (size_t)(t * 16 + lr) * bstride;
      bf16x8 bh = as_bf16x8(*(const u32x4*)(Bh + cb));
      bf16x8 bl = as_bf16x8(*(const u32x4*)(Bl + cb));
      acc[0][t] = __builtin_amdgcn_mfma_f32_16x16x32_bf16(ah0, bh, acc[0][t], 0, 0, 0);
      acc[0][t] = __builtin_amdgcn_mfma_f32_16x16x32_bf16(ah0, bl, acc[0][t], 0, 0, 0);
      acc[0][t] = __builtin_amdgcn_mfma_f32_16x16x32_bf16(al0, bh, acc[0][t], 0, 0, 0);
      acc[1][t] = __builtin_amdgcn_mfma_f32_16x16x32_bf16(ah1, bh, acc[1][t], 0, 0, 0);
      acc[1][t] = __builtin_amdgcn_mfma_f32_16x16x32_bf16(ah1, bl, acc[1][t], 0, 0, 0);
      acc[1][t] = __builtin_amdgcn_mfma_f32_16x16x32_bf16(al1, bh, acc[1][t], 0, 0, 0);
    }
  }

#pragma unroll
  for (int mt = 0; mt < 2; ++mt) {
    const int rbase = blockIdx.x * 64 + w * 32 + mt * 16 + kg * 4;
#pragma unroll
    for (int t = 0; t < 7; ++t) {
      const int c = t * 16 + lr;
      if (c < 100) {
        const float badd = b1[task * 100 + c];
#pragma unroll
        for (int j = 0; j < 4; ++j) {
          const int r = rbase + j;
          if (r < M) {
            float v = acc[mt][t][j] + badd;
            z[((size_t)task * M + r) * 112 + c] = v > 0.f ? v : 0.f;
          }
        }
      }
    }
  }
}

// heads epilogue: one wave per (t,g): out = sig?(dot(z_row, w2)+b2)
__global__ __launch_bounds__(256) void k_heads2(const float* __restrict__ z, const float* __restrict__ w2,
                                                const float* __restrict__ b2, float* __restrict__ out, int G) {
  int lane = threadIdx.x & 63;
  int idx = blockIdx.x * 4 + (threadIdx.x >> 6);
  if (idx >= 5 * G) return;
  int t = idx / G, g = idx % G;
  const float* zr = z + ((size_t)t * G + g) * 112;
  float p = 0.f;
  if (lane < 100) p += zr[lane] * w2[t * 100 + lane];
  if (lane < 36)  p += zr[lane + 64] * w2[t * 100 + 64 + lane];
  for (int o = 32; o >= 1; o >>= 1) p += __shfl_down(p, o);
  if (lane == 0) {
    float zv = p + b2[t];
    bool sig = (t == 0) | (t == 3) | (t == 4);   // SIG = {1,0,0,1,1}
    out[idx] = sig ? 1.f / (1.f + expf(-zv)) : zv;
  }
}

// a_src[n,h] = sum_c xs[n,h*25+c]*att_src[h,c]; same for a_dst
__global__ __launch_bounds__(256) void k_asrcdst(const float* __restrict__ xs, const float* __restrict__ as_l,
                                                 const float* __restrict__ ad_l, float* __restrict__ a_src,
                                                 float* __restrict__ a_dst, int N) {
  int tid = blockIdx.x * 256 + threadIdx.x;
  if (tid >= N * 8) return;
  int n = tid >> 3, hh = tid & 7;
  const float* xr = xs + (size_t)n * HD + hh * CD;
  const float* sa = as_l + hh * CD;
  const float* da = ad_l + hh * CD;
  float s = 0.f, d = 0.f;
#pragma unroll
  for (int c = 0; c < CD; ++c) { float v = xr[c]; s += v * sa[c]; d += v * da[c]; }
  a_src[tid] = s; a_dst[tid] = d;
}

// ---------------- per-dst-node softmax aggregation; one wave per node ----------------
__global__ __launch_bounds__(256) void k_aggr(const float* __restrict__ xs, const float* __restrict__ a_src,
                                              const float* __restrict__ a_dst, const float* __restrict__ ae_e,
                                              const float* __restrict__ ae_s, const float* __restrict__ gb,
                                              const int* __restrict__ off, const int* __restrict__ eid,
                                              const int* __restrict__ esrc, float* __restrict__ h_out, int N) {
  int lane = threadIdx.x & 63;
  int node = blockIdx.x * 4 + (threadIdx.x >> 6);
  if (node >= N) return;
  int o0 = off[node], o1 = off[node + 1];
  // column->head mapping for this lane's 4 owned columns (lane, +64, +128, +192)
  int hh0 = lane / 25, hh1 = (lane + 64) / 25, hh2 = (lane + 128) / 25, hh3 = (lane + 192) / 25;
  float adsth = 0.f, aself = 0.f, aes = 0.f, mx = -1e30f;
  if (lane < 8) {
    adsth = a_dst[(size_t)node * 8 + lane];
    aself = a_src[(size_t)node * 8 + lane];
    aes   = ae_s[(size_t)node * 8 + lane];
    float l0 = aself + adsth + aes;
    mx = (l0 >= 0.f) ? l0 : 0.2f * l0;
  }
  // pass 1: max logit per head (lanes 0..7)
  for (int p = o0; p < o1; ++p) {
    int e = eid[p], s = esrc[e];
    if (lane < 8) {
      float l0 = a_src[(size_t)s * 8 + lane] + adsth + ae_e[(size_t)e * 8 + lane];
      l0 = (l0 >= 0.f) ? l0 : 0.2f * l0;
      mx = fmaxf(mx, l0);
    }
  }
  // pass 2: exp-weights (lanes 0..7), broadcast via shuffle, accumulate columns
  float acc0 = 0.f, acc1 = 0.f, acc2 = 0.f, acc3 = 0.f, ssum = 0.f;
  {
    float w = 0.f;
    if (lane < 8) {
      float l0 = aself + adsth + aes;
      l0 = (l0 >= 0.f) ? l0 : 0.2f * l0;
      w = expf(l0 - mx); ssum += w;
    }
    float wa = __shfl(w, hh0), wb = __shfl(w, hh1), wc = __shfl(w, hh2), wd = __shfl(w, hh3);
    const float* xr = xs + (size_t)node * HD;
    acc0 += wa * xr[lane]; acc1 += wb * xr[lane + 64]; acc2 += wc * xr[lane + 128];
    if (lane < 8) acc3 += wd * xr[lane + 192];
  }
  for (int p = o0; p < o1; ++p) {
    int e = eid[p], s = esrc[e];
    float w = 0.f;
    if (lane < 8) {
      float l0 = a_src[(size_t)s * 8 + lane] + adsth + ae_e[(size_t)e * 8 + lane];
      l0 = (l0 >= 0.f) ? l0 : 0.2f * l0;
      w = expf(l0 - mx); ssum += w;
    }
    float wa = __shfl(w, hh0), wb = __shfl(w, hh1), wc = __shfl(w, hh2), wd = __shfl(w, hh3);
    const float* xr = xs + (size_t)s * HD;
    acc0 += wa * xr[lane]; acc1 += wb * xr[lane + 64]; acc2 += wc * xr[lane + 128];
    if (lane < 8) acc3 += wd * xr[lane + 192];
  }
  float sa = __shfl(ssum, hh0) + 1e-16f, sb = __shfl(ssum, hh1) + 1e-16f;
  float sc = __shfl(ssum, hh2) + 1e-16f, sd = __shfl(ssum, hh3) + 1e-16f;
  float* ho = h_out + (size_t)node * HD;
  ho[lane]       = acc0 / sa + gb[lane];
  ho[lane + 64]  = acc1 / sb + gb[lane + 64];
  ho[lane + 128] = acc2 / sc + gb[lane + 128];
  if (lane < 8) ho[lane + 192] = acc3 / sd + gb[lane + 192];
}

// graph start offsets from sorted batch
__global__ __launch_bounds__(256) void k_gstart(const int* __restrict__ batch, int* __restrict__ gstart,
                                                int N, int G) {
  int i = blockIdx.x * 256 + threadIdx.x;
  if (i >= N) return;
  int b = batch[i];
  int pb = (i == 0) ? -1 : batch[i - 1];
  for (int g = pb + 1; g <= b; ++g) gstart[g] = i;
  if (i == N - 1) for (int g = b + 1; g <= G; ++g) gstart[g] = N;
}

__global__ __launch_bounds__(256) void k_pool(const float* __restrict__ h, const int* __restrict__ gstart,
                                              float* __restrict__ pooled, int G) {
  int g = blockIdx.x, c = threadIdx.x;
  if (c >= HD) return;
  int s0 = gstart[g], s1 = gstart[g + 1];
  float acc = 0.f;
  for (int i = s0; i < s1; ++i) acc += h[(size_t)i * HD + c];
  pooled[(size_t)g * HD + c] = acc;
}

extern "C" void kernel_launch(void* const* d_in, const int* in_sizes, int n_in,
                              void* d_out, int out_size, void* d_ws, size_t ws_size,
                              hipStream_t stream) {
  const float* x         = (const float*)d_in[0];
  const float* edge_attr = (const float*)d_in[1];
  const float* node_w    = (const float*)d_in[2];
  const float* node_b    = (const float*)d_in[3];
  const float* edge_w    = (const float*)d_in[4];
  const float* edge_b    = (const float*)d_in[5];
  const float* lin_w     = (const float*)d_in[6];
  const float* lin_edge_w= (const float*)d_in[7];
  const float* att_src   = (const float*)d_in[8];
  const float* att_dst   = (const float*)d_in[9];
  const float* att_edge  = (const float*)d_in[10];
  const float* gat_bias  = (const float*)d_in[11];
  const float* readout_w = (const float*)d_in[12];
  const float* readout_b = (const float*)d_in[13];
  const float* head_w1   = (const float*)d_in[14];
  const float* head_b1   = (const float*)d_in[15];
  const float* head_w2   = (const float*)d_in[16];
  const float* head_b2   = (const float*)d_in[17];
  const int*   edge_index= (const int*)d_in[18];
  const int*   batch     = (const int*)d_in[19];

  const int N = in_sizes[0] / 64;
  const int E = in_sizes[1] / 6;
  const int G = out_size / 5;
  const int* srcI = edge_index;
  const int* dstI = edge_index + E;

  char* wsb = (char*)d_ws;
  size_t o = 0;
  auto alloc = [&](size_t bytes) -> void* {
    void* p = wsb + o;
    o = (o + bytes + 255) & ~(size_t)255;
    return p;
  };
  float* h       = (float*)alloc((size_t)N * HD * 4);
  float* xs      = (float*)alloc((size_t)N * HD * 4);
  float* a_src   = (float*)alloc((size_t)N * 8 * 4);
  float* a_dst   = (float*)alloc((size_t)N * 8 * 4);
  float* ae_e    = (float*)alloc((size_t)NL * E * 8 * 4);
  float* ae_s    = (float*)alloc((size_t)NL * N * 8 * 4);
  float* mean_ea = (float*)alloc((size_t)N * 6 * 4);
  float* we      = (float*)alloc((size_t)NL * HD * 8 * 4);
  float* Mm      = (float*)alloc((size_t)NL * 6 * 8 * 4);
  float* cv      = (float*)alloc((size_t)NL * 8 * 4);
  int* cnt       = (int*)alloc((size_t)N * 4);
  int* cur       = (int*)alloc((size_t)N * 4);
  int* off       = (int*)alloc((size_t)(N + 1) * 4);
  int* partial   = (int*)alloc(512 * 4);
  int* eid       = (int*)alloc((size_t)E * 4);
  int* gstart    = (int*)alloc((size_t)(G + 1) * 4);
  float* pooled  = (float*)alloc((size_t)G * HD * 4);
  float* readouts= (float*)alloc((size_t)G * HD * 4);
  // split-weight planes (u32 = 2 bf16)
  u32* nodeW_hi  = (u32*)alloc(208 * 32 * 4);            // [208][64] bf16
  u32* nodeW_lo  = (u32*)alloc(208 * 32 * 4);
  u32* linW_hi   = (u32*)alloc((size_t)NL * 208 * 112 * 4);   // [l][208][224] bf16
  u32* linW_lo   = (u32*)alloc((size_t)NL * 208 * 112 * 4);
  u32* roW_hi    = (u32*)alloc((size_t)NL * 208 * 112 * 4);
  u32* roW_lo    = (u32*)alloc((size_t)NL * 208 * 112 * 4);
  u32* hw_hi     = (u32*)alloc((size_t)5 * 112 * 112 * 4);    // [t][112][224] bf16
  u32* hw_lo     = (u32*)alloc((size_t)5 * 112 * 112 * 4);
  float* zbuf    = (float*)alloc((size_t)5 * G * 112 * 4);
  (void)ws_size; (void)n_in;

  hipMemsetAsync(cnt, 0, (size_t)N * 4, stream);
  hipMemsetAsync(cur, 0, (size_t)N * 4, stream);
  hipMemsetAsync(readouts, 0, (size_t)G * HD * 4, stream);

  int nb = (N + 255) / 256;
  k_hist<<<(E + 255) / 256, 256, 0, stream>>>(dstI, cnt, E);
  k_scan1<<<nb, 256, 0, stream>>>(cnt, off, partial, N);
  k_scan2<<<1, 512, 0, stream>>>(partial, nb, off, N);
  k_scan3<<<nb, 256, 0, stream>>>(off, partial, N);
  k_scatter<<<(E + 255) / 256, 256, 0, stream>>>(dstI, off, cur, eid, E);
  k_sort<<<nb, 256, 0, stream>>>(off, eid, N);
  k_meanea<<<(N + 127) / 128, 128, 0, stream>>>(edge_attr, off, eid, mean_ea, N);
  k_we<<<(NL * HD * 8 + 255) / 256, 256, 0, stream>>>(lin_edge_w, att_edge, we);
  k_M<<<1, 256, 0, stream>>>(edge_w, edge_b, we, Mm, cv);
  k_ae_edge<<<(E + 255) / 256, 256, 0, stream>>>(edge_attr, Mm, cv, ae_e, E);
  k_ae_self<<<(N + 255) / 256, 256, 0, stream>>>(mean_ea, cnt, Mm, cv, ae_s, N);

  // weight splits
  {
    dim3 g1((208 * 32 + 255) / 256, 1);
    k_split_w<<<g1, 256, 0, stream>>>(node_w, nodeW_hi, nodeW_lo, 64, 64, 0);
    dim3 g2((208 * 112 + 255) / 256, NL);
    k_split_w<<<g2, 256, 0, stream>>>(lin_w, linW_hi, linW_lo, HD, 224, HD * HD);
    k_split_w<<<g2, 256, 0, stream>>>(readout_w, roW_hi, roW_lo, HD, 224, HD * HD);
    dim3 g3((112 * 112 + 255) / 256, 5);
    k_split_hw<<<g3, 256, 0, stream>>>(head_w1, hw_hi, hw_lo);
  }

  const int gemmBlocksN = (N + 63) / 64;
  k_gemm_mf<<<gemmBlocksN, 128, 0, stream>>>(x, nodeW_hi, nodeW_lo, node_b, h, N, 64, 0);
  k_gstart<<<nb, 256, 0, stream>>>(batch, gstart, N, G);

  for (int l = 0; l < NL; ++l) {
    k_gemm_mf<<<gemmBlocksN, 128, 0, stream>>>(h, linW_hi + (size_t)l * 208 * 112,
                                               linW_lo + (size_t)l * 208 * 112, nullptr, xs, N, HD, 0);
    k_asrcdst<<<(N * 8 + 255) / 256, 256, 0, stream>>>(xs, att_src + l * NH * CD, att_dst + l * NH * CD,
                                                       a_src, a_dst, N);
    k_aggr<<<(N + 3) / 4, 256, 0, stream>>>(xs, a_src, a_dst, ae_e + (size_t)l * E * 8,
                                            ae_s + (size_t)l * N * 8, gat_bias + l * HD,
                                            off, eid, srcI, h, N);
    k_pool<<<G, 256, 0, stream>>>(h, gstart, pooled, G);
    k_gemm_mf<<<(G + 63) / 64, 128, 0, stream>>>(pooled, roW_hi + (size_t)l * 208 * 112,
                                                 roW_lo + (size_t)l * 208 * 112, readout_b + l * HD,
                                                 readouts, G, HD, 1);
  }
  {
    dim3 hg((G + 63) / 64, 5);
    k_headgemm<<<hg, 128, 0, stream>>>(readouts, hw_hi, hw_lo, head_b1, zbuf, G);
  }
  k_heads2<<<(5 * G + 3) / 4, 256, 0, stream>>>(zbuf, head_w2, head_b2, (float*)d_out, G);
}

// Round 7
// 1291.241 us; speedup vs baseline: 4.1465x; 1.2012x over previous
//
#include <hip/hip_runtime.h>
#include <cstdint>
#include <cstddef>

static constexpr int HD = 200;   // hidden
static constexpr int NH = 8;     // heads
static constexpr int CD = 25;    // per-head dim
static constexpr int NL = 4;     // layers

typedef unsigned int u32;
typedef unsigned int u32x4 __attribute__((ext_vector_type(4)));
typedef float f32x4 __attribute__((ext_vector_type(4)));
typedef __bf16 bf16x8 __attribute__((ext_vector_type(8)));

union U8cast { u32x4 u; bf16x8 b; };
__device__ inline bf16x8 as_bf16x8(u32x4 v) { U8cast x; x.u = v; return x.b; }

// truncation split: a = hi + lo + eps, |eps| <= 2^-16 |a|; packs 2 elems per u32.
__device__ inline void split2(float a0, float a1, u32& hi, u32& lo) {
  u32 u0 = __builtin_bit_cast(u32, a0), u1 = __builtin_bit_cast(u32, a1);
  u32 h0 = u0 & 0xffff0000u, h1 = u1 & 0xffff0000u;
  hi = (u0 >> 16) | h1;
  float r0 = a0 - __builtin_bit_cast(float, h0);
  float r1 = a1 - __builtin_bit_cast(float, h1);
  lo = (__builtin_bit_cast(u32, r0) >> 16) | (__builtin_bit_cast(u32, r1) & 0xffff0000u);
}

__device__ inline void mk_frags(const float* __restrict__ ap, bf16x8& hi8, bf16x8& lo8) {
  f32x4 x0 = *(const f32x4*)ap;
  f32x4 x1 = *(const f32x4*)(ap + 4);
  u32x4 h, l;
  u32 th, tl;
  split2(x0[0], x0[1], th, tl); h[0] = th; l[0] = tl;
  split2(x0[2], x0[3], th, tl); h[1] = th; l[1] = tl;
  split2(x1[0], x1[1], th, tl); h[2] = th; l[2] = tl;
  split2(x1[2], x1[3], th, tl); h[3] = th; l[3] = tl;
  hi8 = as_bf16x8(h); lo8 = as_bf16x8(l);
}

// ---------------- CSR build ----------------
__global__ __launch_bounds__(256) void k_hist(const int* __restrict__ dst, int* __restrict__ cnt, int E) {
  int e = blockIdx.x * 256 + threadIdx.x;
  if (e < E) atomicAdd(&cnt[dst[e]], 1);
}

__global__ __launch_bounds__(256) void k_scan1(const int* __restrict__ cnt, int* __restrict__ off,
                                               int* __restrict__ partial, int N) {
  __shared__ int sm[256];
  int t = threadIdx.x, i = blockIdx.x * 256 + t;
  int v = (i < N) ? cnt[i] : 0;
  sm[t] = v; __syncthreads();
  for (int o = 1; o < 256; o <<= 1) {
    int add = (t >= o) ? sm[t - o] : 0;
    __syncthreads();
    sm[t] += add;
    __syncthreads();
  }
  if (i < N) off[i] = sm[t] - v;
  if (t == 255) partial[blockIdx.x] = sm[255];
}

__global__ __launch_bounds__(512) void k_scan2(int* __restrict__ partial, int nb, int* __restrict__ off, int N) {
  __shared__ int sm[512];
  int t = threadIdx.x;
  int v = (t < nb) ? partial[t] : 0;
  sm[t] = v; __syncthreads();
  for (int o = 1; o < 512; o <<= 1) {
    int add = (t >= o) ? sm[t - o] : 0;
    __syncthreads();
    sm[t] += add;
    __syncthreads();
  }
  if (t < nb) partial[t] = sm[t] - v;
  if (t == 511) off[N] = sm[511];
}

__global__ __launch_bounds__(256) void k_scan3(int* __restrict__ off, const int* __restrict__ partial, int N) {
  int i = blockIdx.x * 256 + threadIdx.x;
  if (i < N) off[i] += partial[i >> 8];
}

__global__ __launch_bounds__(256) void k_scatter(const int* __restrict__ dst, const int* __restrict__ off,
                                                 int* __restrict__ cur, int* __restrict__ eid, int E) {
  int e = blockIdx.x * 256 + threadIdx.x;
  if (e < E) {
    int d = dst[e];
    int p = atomicAdd(&cur[d], 1);
    eid[off[d] + p] = e;
  }
}

__global__ __launch_bounds__(256) void k_sort(const int* __restrict__ off, int* __restrict__ eid, int N) {
  int n = blockIdx.x * 256 + threadIdx.x;
  if (n >= N) return;
  int o0 = off[n], o1 = off[n + 1];
  for (int i = o0 + 1; i < o1; ++i) {
    int v = eid[i]; int j = i - 1;
    while (j >= o0 && eid[j] > v) { eid[j + 1] = eid[j]; --j; }
    eid[j + 1] = v;
  }
}

// ---------------- edge-attention precompute (algebraic reductions) ----------------
__global__ __launch_bounds__(128) void k_meanea(const float* __restrict__ ea, const int* __restrict__ off,
                                                const int* __restrict__ eid, float* __restrict__ mea, int N) {
  int n = blockIdx.x * 128 + threadIdx.x;
  if (n >= N) return;
  int o0 = off[n], o1 = off[n + 1];
  float s0 = 0, s1 = 0, s2 = 0, s3 = 0, s4 = 0, s5 = 0;
  for (int p = o0; p < o1; ++p) {
    const float* r = ea + (size_t)eid[p] * 6;
    s0 += r[0]; s1 += r[1]; s2 += r[2]; s3 += r[3]; s4 += r[4]; s5 += r[5];
  }
  float inv = (o1 > o0) ? 1.f / (float)(o1 - o0) : 0.f;
  float* m = mea + (size_t)n * 6;
  m[0] = s0 * inv; m[1] = s1 * inv; m[2] = s2 * inv; m[3] = s3 * inv; m[4] = s4 * inv; m[5] = s5 * inv;
}

// we[l][k][h]   = sum_c lin_edge_w[l][k][h*25+c] * att_edge[l][h][c]
// wsrc[l][k][h] = sum_c lin_w[l][k][h*25+c]      * att_src[l][h][c]
// wdst[l][k][h] = sum_c lin_w[l][k][h*25+c]      * att_dst[l][h][c]
__global__ __launch_bounds__(256) void k_we2(const float* __restrict__ lew, const float* __restrict__ linw,
                                             const float* __restrict__ aeg, const float* __restrict__ asg,
                                             const float* __restrict__ adg, float* __restrict__ we,
                                             float* __restrict__ wsrc, float* __restrict__ wdst) {
  int tid = blockIdx.x * 256 + threadIdx.x;
  if (tid >= NL * HD * 8) return;
  int l = tid / (HD * 8); int r = tid % (HD * 8); int k = r >> 3; int hh = r & 7;
  const float* We = lew + (size_t)l * HD * HD + (size_t)k * HD + hh * CD;
  const float* Wl = linw + (size_t)l * HD * HD + (size_t)k * HD + hh * CD;
  const float* ae = aeg + l * NH * CD + hh * CD;
  const float* as = asg + l * NH * CD + hh * CD;
  const float* ad = adg + l * NH * CD + hh * CD;
  float s0 = 0.f, s1 = 0.f, s2 = 0.f;
#pragma unroll
  for (int c = 0; c < CD; ++c) {
    float we_ = We[c], wl_ = Wl[c];
    s0 += we_ * ae[c]; s1 += wl_ * as[c]; s2 += wl_ * ad[c];
  }
  we[tid] = s0; wsrc[tid] = s1; wdst[tid] = s2;   // layout l*1600 + k*8 + h
}

// M[l][f][h] = sum_k edge_emb_w[f][k] * we[l][k][h];  cv[l][h] = sum_k edge_emb_b[k]*we[l][k][h]
__global__ __launch_bounds__(256) void k_M(const float* __restrict__ ew, const float* __restrict__ eb,
                                           const float* __restrict__ we, float* __restrict__ Mm,
                                           float* __restrict__ cv) {
  int tid = threadIdx.x;
  if (tid < NL * 6 * 8) {
    int l = tid / 48, r = tid % 48, f = r / 8, hh = r % 8;
    float s = 0.f;
    for (int k = 0; k < HD; ++k) s += ew[f * HD + k] * we[l * 1600 + k * 8 + hh];
    Mm[tid] = s;   // l*48 + f*8 + hh
  } else if (tid < NL * 6 * 8 + NL * 8) {
    int u = tid - NL * 6 * 8, l = u / 8, hh = u % 8;
    float s = 0.f;
    for (int k = 0; k < HD; ++k) s += eb[k] * we[l * 1600 + k * 8 + hh];
    cv[u] = s;
  }
}

// self-loop attention logit contribution ae_s for all layers
__global__ __launch_bounds__(256) void k_ae_self(const float* __restrict__ mea, const int* __restrict__ cnt,
                                                 const float* __restrict__ Mm, const float* __restrict__ cv,
                                                 float* __restrict__ aes, int N) {
  int n = blockIdx.x * 256 + threadIdx.x;
  if (n >= N) return;
  bool has = cnt[n] > 0;
  float v[6];
#pragma unroll
  for (int f = 0; f < 6; ++f) v[f] = mea[(size_t)n * 6 + f];
  for (int l = 0; l < NL; ++l)
#pragma unroll
    for (int hh = 0; hh < 8; ++hh) {
      float s = 0.f;
      if (has) {
        s = cv[l * 8 + hh];
#pragma unroll
        for (int f = 0; f < 6; ++f) s += v[f] * Mm[l * 48 + f * 8 + hh];
      }
      aes[(size_t)l * N * 8 + (size_t)n * 8 + hh] = s;
    }
}

// per-layer CSR-ordered leaky-relu'd logits: lg[p][h], edge ae computed inline
__global__ __launch_bounds__(256) void k_lg(const float* __restrict__ ea, const float* __restrict__ a_src,
                                            const float* __restrict__ a_dst, const float* __restrict__ Mm,
                                            const float* __restrict__ cv, const int* __restrict__ eid,
                                            const int* __restrict__ esrc, const int* __restrict__ edst,
                                            float* __restrict__ lg, int E, int l) {
  int tid = blockIdx.x * 256 + threadIdx.x;
  if (tid >= E * 8) return;
  int p = tid >> 3, h = tid & 7;
  int e = eid[p];
  int s = esrc[e], d = edst[e];
  const float* er = ea + (size_t)e * 6;
  float aev = cv[l * 8 + h];
#pragma unroll
  for (int f = 0; f < 6; ++f) aev += er[f] * Mm[l * 48 + f * 8 + h];
  float v = a_src[(size_t)s * 8 + h] + a_dst[(size_t)d * 8 + h] + aev;
  lg[tid] = (v >= 0.f) ? v : 0.2f * v;
}

// ---------------- weight split: -> [l][ncols][Kpad] bf16 hi/lo planes ----------------
// cols 0..199 from W[k][c]; cols 200-207/208-215 (if wsrc) from wsrc/wdst[k][h]; else 0.
__global__ __launch_bounds__(256) void k_split_w(const float* __restrict__ W, u32* __restrict__ hiT,
                                                 u32* __restrict__ loT, int K, int Kpad, int inStride,
                                                 int ncols, const float* __restrict__ wsrc,
                                                 const float* __restrict__ wdst) {
  int l = blockIdx.y;
  int cpr = Kpad >> 1;
  int tot = ncols * cpr;
  int idx = blockIdx.x * 256 + threadIdx.x;
  if (idx >= tot) return;
  int c = idx / cpr, kp = (idx % cpr) * 2;
  float a0 = 0.f, a1 = 0.f;
  if (c < HD) {
    const float* Wl = W + (size_t)l * inStride;
    a0 = (kp < K) ? Wl[(size_t)kp * HD + c] : 0.f;
    a1 = (kp + 1 < K) ? Wl[(size_t)(kp + 1) * HD + c] : 0.f;
  } else if (wsrc && c < 216) {
    const float* src = ((c < 208) ? wsrc : wdst) + (size_t)l * 1600;
    int hh = (c - 200) & 7;
    a0 = (kp < K) ? src[kp * 8 + hh] : 0.f;
    a1 = (kp + 1 < K) ? src[(kp + 1) * 8 + hh] : 0.f;
  }
  u32 hi, lo; split2(a0, a1, hi, lo);
  size_t ob = (size_t)l * tot + idx;
  hiT[ob] = hi; loT[ob] = lo;
}

// head W1 split: head_w1 [5][200][100] -> planes [t][112 cols][224 k] bf16
__global__ __launch_bounds__(256) void k_split_hw(const float* __restrict__ W, u32* __restrict__ hiT,
                                                  u32* __restrict__ loT) {
  int t = blockIdx.y;
  int idx = blockIdx.x * 256 + threadIdx.x;
  if (idx >= 112 * 112) return;
  int c = idx / 112, kp = (idx % 112) * 2;
  const float* Wt = W + (size_t)t * HD * 100;
  float a0 = (c < 100 && kp < HD) ? Wt[(size_t)kp * 100 + c] : 0.f;
  float a1 = (c < 100 && kp + 1 < HD) ? Wt[(size_t)(kp + 1) * 100 + c] : 0.f;
  u32 hi, lo; split2(a0, a1, hi, lo);
  size_t ob = (size_t)t * 112 * 112 + idx;
  hiT[ob] = hi; loT[ob] = lo;
}

// ---------------- MFMA GEMM (split-bf16, no LDS) ----------------
// NT tiles of 16 cols. If ATTN: cols 200-207 -> aS[n][8], 208-215 -> aD[n][8].
template<int NT, bool ATTN>
__global__ __launch_bounds__(128) void k_gemm_t(const float* __restrict__ A, const u32* __restrict__ BhiT,
                                                const u32* __restrict__ BloT, const float* __restrict__ bias,
                                                float* __restrict__ C, float* __restrict__ aS,
                                                float* __restrict__ aD, int M, int K, int accumulate) {
  const int lane = threadIdx.x & 63;
  const int w = threadIdx.x >> 6;
  const int lr = lane & 15, kg = lane >> 4;
  const int Kpad = (K + 31) & ~31;
  const int nStep = Kpad >> 5;
  const int bstride = Kpad >> 1;

  const int rowA0 = blockIdx.x * 64 + w * 32 + lr;
  const int rowA1 = rowA0 + 16;
  const float* Ap0 = A + (size_t)((rowA0 < M) ? rowA0 : (M - 1)) * K;
  const float* Ap1 = A + (size_t)((rowA1 < M) ? rowA1 : (M - 1)) * K;

  f32x4 acc[2][NT];
#pragma unroll
  for (int mt = 0; mt < 2; ++mt)
#pragma unroll
    for (int t = 0; t < NT; ++t) acc[mt][t] = (f32x4)0.f;

  u32x4 zz; zz[0] = 0; zz[1] = 0; zz[2] = 0; zz[3] = 0;
  const bf16x8 zfrag = as_bf16x8(zz);

  for (int ks = 0; ks < nStep; ++ks) {
    const int kb = ks * 32;
    const int k0 = kb + kg * 8;
    bf16x8 ah0, al0, ah1, al1;
    if (k0 < K) {
      mk_frags(Ap0 + k0, ah0, al0);
      mk_frags(Ap1 + k0, ah1, al1);
    } else {
      ah0 = zfrag; al0 = zfrag; ah1 = zfrag; al1 = zfrag;
    }
    const u32* Bh = BhiT + (kb >> 1) + kg * 4;
    const u32* Bl = BloT + (kb >> 1) + kg * 4;
#pragma unroll
    for (int t = 0; t < NT; ++t) {
      const size_t cb = (size_t)(t * 16 + lr) * bstride;
      bf16x8 bh = as_bf16x8(*(const u32x4*)(Bh + cb));
      bf16x8 bl = as_bf16x8(*(const u32x4*)(Bl + cb));
      acc[0][t] = __builtin_amdgcn_mfma_f32_16x16x32_bf16(ah0, bh, acc[0][t], 0, 0, 0);
      acc[0][t] = __builtin_amdgcn_mfma_f32_16x16x32_bf16(ah0, bl, acc[0][t], 0, 0, 0);
      acc[0][t] = __builtin_amdgcn_mfma_f32_16x16x32_bf16(al0, bh, acc[0][t], 0, 0, 0);
      acc[1][t] = __builtin_amdgcn_mfma_f32_16x16x32_bf16(ah1, bh, acc[1][t], 0, 0, 0);
      acc[1][t] = __builtin_amdgcn_mfma_f32_16x16x32_bf16(ah1, bl, acc[1][t], 0, 0, 0);
      acc[1][t] = __builtin_amdgcn_mfma_f32_16x16x32_bf16(al1, bh, acc[1][t], 0, 0, 0);
    }
  }

#pragma unroll
  for (int mt = 0; mt < 2; ++mt) {
    const int rbase = blockIdx.x * 64 + w * 32 + mt * 16 + kg * 4;
#pragma unroll
    for (int t = 0; t < NT; ++t) {
      const int c = t * 16 + lr;
      if (c < HD) {
        const float badd = bias ? bias[c] : 0.f;
#pragma unroll
        for (int j = 0; j < 4; ++j) {
          const int r = rbase + j;
          if (r < M) {
            float v = acc[mt][t][j] + badd;
            if (accumulate) v += C[(size_t)r * HD + c];
            C[(size_t)r * HD + c] = v;
          }
        }
      } else if (ATTN && c < 216) {
        float* dstp = (c < 208) ? aS : aD;
        const int hh = (c - 200) & 7;
#pragma unroll
        for (int j = 0; j < 4; ++j) {
          const int r = rbase + j;
          if (r < M) dstp[(size_t)r * 8 + hh] = acc[mt][t][j];
        }
      }
    }
  }
}

// ---------------- head GEMM: z[t] = relu(readouts @ W1[t] + b1[t]), z [5][G][112] ----------------
__global__ __launch_bounds__(128) void k_headgemm(const float* __restrict__ A, const u32* __restrict__ hwHi,
                                                  const u32* __restrict__ hwLo, const float* __restrict__ b1,
                                                  float* __restrict__ z, int M) {
  const int task = blockIdx.y;
  const int lane = threadIdx.x & 63;
  const int w = threadIdx.x >> 6;
  const int lr = lane & 15, kg = lane >> 4;
  const int K = HD;
  const int nStep = 7;
  const int bstride = 112;

  const int rowA0 = blockIdx.x * 64 + w * 32 + lr;
  const int rowA1 = rowA0 + 16;
  const float* Ap0 = A + (size_t)((rowA0 < M) ? rowA0 : (M - 1)) * K;
  const float* Ap1 = A + (size_t)((rowA1 < M) ? rowA1 : (M - 1)) * K;
  const u32* BhT = hwHi + (size_t)task * 112 * 112;
  const u32* BlT = hwLo + (size_t)task * 112 * 112;

  f32x4 acc[2][7];
#pragma unroll
  for (int mt = 0; mt < 2; ++mt)
#pragma unroll
    for (int t = 0; t < 7; ++t) acc[mt][t] = (f32x4)0.f;

  u32x4 zz; zz[0] = 0; zz[1] = 0; zz[2] = 0; zz[3] = 0;
  const bf16x8 zfrag = as_bf16x8(zz);

  for (int ks = 0; ks < nStep; ++ks) {
    const int kb = ks * 32;
    const int k0 = kb + kg * 8;
    bf16x8 ah0, al0, ah1, al1;
    if (k0 < K) {
      mk_frags(Ap0 + k0, ah0, al0);
      mk_frags(Ap1 + k0, ah1, al1);
    } else {
      ah0 = zfrag; al0 = zfrag; ah1 = zfrag; al1 = zfrag;
    }
    const u32* Bh = BhT + (kb >> 1) + kg * 4;
    const u32* Bl = BlT + (kb >> 1) + kg * 4;
#pragma unroll
    for (int t = 0; t < 7; ++t) {
      const size_t cb = (size_t)(t * 16 + lr) * bstride;
      bf16x8 bh = as_bf16x8(*(const u32x4*)(Bh + cb));
      bf16x8 bl = as_bf16x8(*(const u32x4*)(Bl + cb));
      acc[0][t] = __builtin_amdgcn_mfma_f32_16x16x32_bf16(ah0, bh, acc[0][t], 0, 0, 0);
      acc[0][t] = __builtin_amdgcn_mfma_f32_16x16x32_bf16(ah0, bl, acc[0][t], 0, 0, 0);
      acc[0][t] = __builtin_amdgcn_mfma_f32_16x16x32_bf16(al0, bh, acc[0][t], 0, 0, 0);
      acc[1][t] = __builtin_amdgcn_mfma_f32_16x16x32_bf16(ah1, bh, acc[1][t], 0, 0, 0);
      acc[1][t] = __builtin_amdgcn_mfma_f32_16x16x32_bf16(ah1, bl, acc[1][t], 0, 0, 0);
      acc[1][t] = __builtin_amdgcn_mfma_f32_16x16x32_bf16(al1, bh, acc[1][t], 0, 0, 0);
    }
  }

#pragma unroll
  for (int mt = 0; mt < 2; ++mt) {
    const int rbase = blockIdx.x * 64 + w * 32 + mt * 16 + kg * 4;
#pragma unroll
    for (int t = 0; t < 7; ++t) {
      const int c = t * 16 + lr;
      if (c < 100) {
        const float badd = b1[task * 100 + c];
#pragma unroll
        for (int j = 0; j < 4; ++j) {
          const int r = rbase + j;
          if (r < M) {
            float v = acc[mt][t][j] + badd;
            z[((size_t)task * M + r) * 112 + c] = v > 0.f ? v : 0.f;
          }
        }
      }
    }
  }
}

__global__ __launch_bounds__(256) void k_heads2(const float* __restrict__ z, const float* __restrict__ w2,
                                                const float* __restrict__ b2, float* __restrict__ out, int G) {
  int lane = threadIdx.x & 63;
  int idx = blockIdx.x * 4 + (threadIdx.x >> 6);
  if (idx >= 5 * G) return;
  int t = idx / G, g = idx % G;
  const float* zr = z + ((size_t)t * G + g) * 112;
  float p = 0.f;
  if (lane < 100) p += zr[lane] * w2[t * 100 + lane];
  if (lane < 36)  p += zr[lane + 64] * w2[t * 100 + 64 + lane];
  for (int o = 32; o >= 1; o >>= 1) p += __shfl_down(p, o);
  if (lane == 0) {
    float zv = p + b2[t];
    bool sig = (t == 0) | (t == 3) | (t == 4);
    out[idx] = sig ? 1.f / (1.f + expf(-zv)) : zv;
  }
}

// ---------------- aggregation v2: wave per node, 8 edges x 8 heads per iteration ----------------
__global__ __launch_bounds__(256) void k_aggr2(const float* __restrict__ xs, const float* __restrict__ a_src,
                                               const float* __restrict__ a_dst, const float* __restrict__ lg,
                                               const float* __restrict__ aes, const float* __restrict__ gb,
                                               const int* __restrict__ off, const int* __restrict__ eid,
                                               const int* __restrict__ esrc, float* __restrict__ h_out, int N) {
  int lane = threadIdx.x & 63;
  int node = blockIdx.x * 4 + (threadIdx.x >> 6);
  if (node >= N) return;
  const int h = lane & 7, q = lane >> 3;
  const int o0 = off[node], o1 = off[node + 1];
  const int hh0 = lane / 25, hh1 = (lane + 64) / 25, hh2 = (lane + 128) / 25, hh3 = (lane + 192) / 25;

  // self logit (lanes 0..7, lane == its head)
  float lself = 0.f;
  if (lane < 8) {
    float v = a_src[(size_t)node * 8 + lane] + a_dst[(size_t)node * 8 + lane] + aes[(size_t)node * 8 + lane];
    lself = (v >= 0.f) ? v : 0.2f * v;
  }
  // pass 1: per-head max over edges (contiguous lg), then fold self
  float mx = -1e30f;
  for (int p0 = o0; p0 < o1; p0 += 8) {
    int p = p0 + q;
    if (p < o1) mx = fmaxf(mx, lg[(size_t)p * 8 + h]);
  }
  mx = fmaxf(mx, __shfl_xor(mx, 8));
  mx = fmaxf(mx, __shfl_xor(mx, 16));
  mx = fmaxf(mx, __shfl_xor(mx, 32));
  mx = fmaxf(mx, __shfl(lself, h));

  // pass 2: weights + column accumulation
  float acc0 = 0.f, acc1 = 0.f, acc2 = 0.f, acc3 = 0.f, wsum = 0.f;
  for (int p0 = o0; p0 < o1; p0 += 8) {
    int p = p0 + q;
    bool valid = p < o1;
    float w = 0.f; int s = 0;
    if (valid) {
      w = expf(lg[(size_t)p * 8 + h] - mx);
      s = esrc[eid[p]];
    }
    wsum += w;
    int cnt = o1 - p0; if (cnt > 8) cnt = 8;
    for (int j = 0; j < cnt; ++j) {
      float wa = __shfl(w, j * 8 + hh0);
      float wb = __shfl(w, j * 8 + hh1);
      float wc = __shfl(w, j * 8 + hh2);
      float wd = __shfl(w, j * 8 + hh3);
      int sj = __shfl(s, j * 8);
      const float* xr = xs + (size_t)sj * HD;
      acc0 += wa * xr[lane];
      acc1 += wb * xr[lane + 64];
      acc2 += wc * xr[lane + 128];
      if (lane < 8) acc3 += wd * xr[lane + 192];
    }
  }
  wsum += __shfl_xor(wsum, 8);
  wsum += __shfl_xor(wsum, 16);
  wsum += __shfl_xor(wsum, 32);

  // self contribution (last, matching reference concat order)
  float wself = (lane < 8) ? expf(lself - mx) : 0.f;
  {
    float wa = __shfl(wself, hh0), wb = __shfl(wself, hh1);
    float wc = __shfl(wself, hh2), wd = __shfl(wself, hh3);
    const float* xr = xs + (size_t)node * HD;
    acc0 += wa * xr[lane];
    acc1 += wb * xr[lane + 64];
    acc2 += wc * xr[lane + 128];
    if (lane < 8) acc3 += wd * xr[lane + 192];
    wsum += __shfl(wself, h);
  }

  float sa = __shfl(wsum, hh0) + 1e-16f, sb = __shfl(wsum, hh1) + 1e-16f;
  float sc = __shfl(wsum, hh2) + 1e-16f, sd = __shfl(wsum, hh3) + 1e-16f;
  float* ho = h_out + (size_t)node * HD;
  ho[lane]       = acc0 / sa + gb[lane];
  ho[lane + 64]  = acc1 / sb + gb[lane + 64];
  ho[lane + 128] = acc2 / sc + gb[lane + 128];
  if (lane < 8) ho[lane + 192] = acc3 / sd + gb[lane + 192];
}

__global__ __launch_bounds__(256) void k_gstart(const int* __restrict__ batch, int* __restrict__ gstart,
                                                int N, int G) {
  int i = blockIdx.x * 256 + threadIdx.x;
  if (i >= N) return;
  int b = batch[i];
  int pb = (i == 0) ? -1 : batch[i - 1];
  for (int g = pb + 1; g <= b; ++g) gstart[g] = i;
  if (i == N - 1) for (int g = b + 1; g <= G; ++g) gstart[g] = N;
}

__global__ __launch_bounds__(256) void k_pool(const float* __restrict__ h, const int* __restrict__ gstart,
                                              float* __restrict__ pooled, int G) {
  int g = blockIdx.x, c = threadIdx.x;
  if (c >= HD) return;
  int s0 = gstart[g], s1 = gstart[g + 1];
  float acc = 0.f;
  for (int i = s0; i < s1; ++i) acc += h[(size_t)i * HD + c];
  pooled[(size_t)g * HD + c] = acc;
}

extern "C" void kernel_launch(void* const* d_in, const int* in_sizes, int n_in,
                              void* d_out, int out_size, void* d_ws, size_t ws_size,
                              hipStream_t stream) {
  const float* x         = (const float*)d_in[0];
  const float* edge_attr = (const float*)d_in[1];
  const float* node_w    = (const float*)d_in[2];
  const float* node_b    = (const float*)d_in[3];
  const float* edge_w    = (const float*)d_in[4];
  const float* edge_b    = (const float*)d_in[5];
  const float* lin_w     = (const float*)d_in[6];
  const float* lin_edge_w= (const float*)d_in[7];
  const float* att_src   = (const float*)d_in[8];
  const float* att_dst   = (const float*)d_in[9];
  const float* att_edge  = (const float*)d_in[10];
  const float* gat_bias  = (const float*)d_in[11];
  const float* readout_w = (const float*)d_in[12];
  const float* readout_b = (const float*)d_in[13];
  const float* head_w1   = (const float*)d_in[14];
  const float* head_b1   = (const float*)d_in[15];
  const float* head_w2   = (const float*)d_in[16];
  const float* head_b2   = (const float*)d_in[17];
  const int*   edge_index= (const int*)d_in[18];
  const int*   batch     = (const int*)d_in[19];

  const int N = in_sizes[0] / 64;
  const int E = in_sizes[1] / 6;
  const int G = out_size / 5;
  const int* srcI = edge_index;
  const int* dstI = edge_index + E;

  char* wsb = (char*)d_ws;
  size_t o = 0;
  auto alloc = [&](size_t bytes) -> void* {
    void* p = wsb + o;
    o = (o + bytes + 255) & ~(size_t)255;
    return p;
  };
  float* h       = (float*)alloc((size_t)N * HD * 4);
  float* xs      = (float*)alloc((size_t)N * HD * 4);
  float* a_src   = (float*)alloc((size_t)N * 8 * 4);
  float* a_dst   = (float*)alloc((size_t)N * 8 * 4);
  float* lg      = (float*)alloc((size_t)E * 8 * 4);
  float* ae_s    = (float*)alloc((size_t)NL * N * 8 * 4);
  float* mean_ea = (float*)alloc((size_t)N * 6 * 4);
  float* we      = (float*)alloc((size_t)NL * HD * 8 * 4);
  float* wsrc    = (float*)alloc((size_t)NL * HD * 8 * 4);
  float* wdst    = (float*)alloc((size_t)NL * HD * 8 * 4);
  float* Mm      = (float*)alloc((size_t)NL * 6 * 8 * 4);
  float* cv      = (float*)alloc((size_t)NL * 8 * 4);
  int* cnt       = (int*)alloc((size_t)N * 4);
  int* cur       = (int*)alloc((size_t)N * 4);
  int* off       = (int*)alloc((size_t)(N + 1) * 4);
  int* partial   = (int*)alloc(512 * 4);
  int* eid       = (int*)alloc((size_t)E * 4);
  int* gstart    = (int*)alloc((size_t)(G + 1) * 4);
  float* pooled  = (float*)alloc((size_t)G * HD * 4);
  float* readouts= (float*)alloc((size_t)G * HD * 4);
  // split-weight planes (u32 = 2 bf16)
  u32* nodeW_hi  = (u32*)alloc(208 * 32 * 4);                  // [208][64] bf16
  u32* nodeW_lo  = (u32*)alloc(208 * 32 * 4);
  u32* linW_hi   = (u32*)alloc((size_t)NL * 224 * 112 * 4);    // [l][224][224] bf16 (incl attn cols)
  u32* linW_lo   = (u32*)alloc((size_t)NL * 224 * 112 * 4);
  u32* roW_hi    = (u32*)alloc((size_t)NL * 208 * 112 * 4);
  u32* roW_lo    = (u32*)alloc((size_t)NL * 208 * 112 * 4);
  u32* hw_hi     = (u32*)alloc((size_t)5 * 112 * 112 * 4);
  u32* hw_lo     = (u32*)alloc((size_t)5 * 112 * 112 * 4);
  float* zbuf    = (float*)alloc((size_t)5 * G * 112 * 4);
  (void)ws_size; (void)n_in;

  hipMemsetAsync(cnt, 0, (size_t)N * 4, stream);
  hipMemsetAsync(cur, 0, (size_t)N * 4, stream);
  hipMemsetAsync(readouts, 0, (size_t)G * HD * 4, stream);

  int nb = (N + 255) / 256;
  k_hist<<<(E + 255) / 256, 256, 0, stream>>>(dstI, cnt, E);
  k_scan1<<<nb, 256, 0, stream>>>(cnt, off, partial, N);
  k_scan2<<<1, 512, 0, stream>>>(partial, nb, off, N);
  k_scan3<<<nb, 256, 0, stream>>>(off, partial, N);
  k_scatter<<<(E + 255) / 256, 256, 0, stream>>>(dstI, off, cur, eid, E);
  k_sort<<<nb, 256, 0, stream>>>(off, eid, N);
  k_meanea<<<(N + 127) / 128, 128, 0, stream>>>(edge_attr, off, eid, mean_ea, N);
  k_we2<<<(NL * HD * 8 + 255) / 256, 256, 0, stream>>>(lin_edge_w, lin_w, att_edge, att_src, att_dst,
                                                       we, wsrc, wdst);
  k_M<<<1, 256, 0, stream>>>(edge_w, edge_b, we, Mm, cv);
  k_ae_self<<<(N + 255) / 256, 256, 0, stream>>>(mean_ea, cnt, Mm, cv, ae_s, N);

  // weight splits
  {
    dim3 g1((208 * 32 + 255) / 256, 1);
    k_split_w<<<g1, 256, 0, stream>>>(node_w, nodeW_hi, nodeW_lo, 64, 64, 0, 208, nullptr, nullptr);
    dim3 g2((224 * 112 + 255) / 256, NL);
    k_split_w<<<g2, 256, 0, stream>>>(lin_w, linW_hi, linW_lo, HD, 224, HD * HD, 224, wsrc, wdst);
    dim3 g2b((208 * 112 + 255) / 256, NL);
    k_split_w<<<g2b, 256, 0, stream>>>(readout_w, roW_hi, roW_lo, HD, 224, HD * HD, 208, nullptr, nullptr);
    dim3 g3((112 * 112 + 255) / 256, 5);
    k_split_hw<<<g3, 256, 0, stream>>>(head_w1, hw_hi, hw_lo);
  }

  const int gemmBlocksN = (N + 63) / 64;
  k_gemm_t<13, false><<<gemmBlocksN, 128, 0, stream>>>(x, nodeW_hi, nodeW_lo, node_b, h,
                                                       nullptr, nullptr, N, 64, 0);
  k_gstart<<<nb, 256, 0, stream>>>(batch, gstart, N, G);

  for (int l = 0; l < NL; ++l) {
    k_gemm_t<14, true><<<gemmBlocksN, 128, 0, stream>>>(h, linW_hi + (size_t)l * 224 * 112,
                                                        linW_lo + (size_t)l * 224 * 112, nullptr, xs,
                                                        a_src, a_dst, N, HD, 0);
    k_lg<<<((size_t)E * 8 + 255) / 256, 256, 0, stream>>>(edge_attr, a_src, a_dst, Mm, cv,
                                                          eid, srcI, dstI, lg, E, l);
    k_aggr2<<<(N + 3) / 4, 256, 0, stream>>>(xs, a_src, a_dst, lg, ae_s + (size_t)l * N * 8,
                                             gat_bias + l * HD, off, eid, srcI, h, N);
    k_pool<<<G, 256, 0, stream>>>(h, gstart, pooled, G);
    k_gemm_t<13, false><<<(G + 63) / 64, 128, 0, stream>>>(pooled, roW_hi + (size_t)l * 208 * 112,
                                                           roW_lo + (size_t)l * 208 * 112,
                                                           readout_b + l * HD, readouts,
                                                           nullptr, nullptr, G, HD, 1);
  }
  {
    dim3 hg((G + 63) / 64, 5);
    k_headgemm<<<hg, 128, 0, stream>>>(readouts, hw_hi, hw_lo, head_b1, zbuf, G);
  }
  k_heads2<<<(5 * G + 3) / 4, 256, 0, stream>>>(zbuf, head_w2, head_b2, (float*)d_out, G);
}

// Round 8
// 1076.289 us; speedup vs baseline: 4.9746x; 1.1997x over previous
//
#include <hip/hip_runtime.h>
#include <cstdint>
#include <cstddef>

static constexpr int HD = 200;   // hidden
static constexpr int NH = 8;     // heads
static constexpr int CD = 25;    // per-head dim
static constexpr int NL = 4;     // layers

typedef unsigned int u32;
typedef unsigned int u32x4 __attribute__((ext_vector_type(4)));
typedef float f32x4 __attribute__((ext_vector_type(4)));
typedef __bf16 bf16x8 __attribute__((ext_vector_type(8)));

union U8cast { u32x4 u; bf16x8 b; };
__device__ inline bf16x8 as_bf16x8(u32x4 v) { U8cast x; x.u = v; return x.b; }

// truncation split: a = hi + lo + eps, |eps| <= 2^-16 |a|; packs 2 elems per u32.
__device__ inline void split2(float a0, float a1, u32& hi, u32& lo) {
  u32 u0 = __builtin_bit_cast(u32, a0), u1 = __builtin_bit_cast(u32, a1);
  u32 h0 = u0 & 0xffff0000u, h1 = u1 & 0xffff0000u;
  hi = (u0 >> 16) | h1;
  float r0 = a0 - __builtin_bit_cast(float, h0);
  float r1 = a1 - __builtin_bit_cast(float, h1);
  lo = (__builtin_bit_cast(u32, r0) >> 16) | (__builtin_bit_cast(u32, r1) & 0xffff0000u);
}

__device__ inline void mk_frags_r(f32x4 x0, f32x4 x1, bf16x8& hi8, bf16x8& lo8) {
  u32x4 h, l;
  u32 th, tl;
  split2(x0[0], x0[1], th, tl); h[0] = th; l[0] = tl;
  split2(x0[2], x0[3], th, tl); h[1] = th; l[1] = tl;
  split2(x1[0], x1[1], th, tl); h[2] = th; l[2] = tl;
  split2(x1[2], x1[3], th, tl); h[3] = th; l[3] = tl;
  hi8 = as_bf16x8(h); lo8 = as_bf16x8(l);
}

__device__ inline void mk_frags(const float* __restrict__ ap, bf16x8& hi8, bf16x8& lo8) {
  mk_frags_r(*(const f32x4*)ap, *(const f32x4*)(ap + 4), hi8, lo8);
}

// ---------------- CSR build ----------------
__global__ __launch_bounds__(256) void k_hist(const int* __restrict__ dst, int* __restrict__ cnt, int E) {
  int e = blockIdx.x * 256 + threadIdx.x;
  if (e < E) atomicAdd(&cnt[dst[e]], 1);
}

__global__ __launch_bounds__(256) void k_scan1(const int* __restrict__ cnt, int* __restrict__ off,
                                               int* __restrict__ partial, int N) {
  __shared__ int sm[256];
  int t = threadIdx.x, i = blockIdx.x * 256 + t;
  int v = (i < N) ? cnt[i] : 0;
  sm[t] = v; __syncthreads();
  for (int o = 1; o < 256; o <<= 1) {
    int add = (t >= o) ? sm[t - o] : 0;
    __syncthreads();
    sm[t] += add;
    __syncthreads();
  }
  if (i < N) off[i] = sm[t] - v;
  if (t == 255) partial[blockIdx.x] = sm[255];
}

__global__ __launch_bounds__(512) void k_scan2(int* __restrict__ partial, int nb, int* __restrict__ off, int N) {
  __shared__ int sm[512];
  int t = threadIdx.x;
  int v = (t < nb) ? partial[t] : 0;
  sm[t] = v; __syncthreads();
  for (int o = 1; o < 512; o <<= 1) {
    int add = (t >= o) ? sm[t - o] : 0;
    __syncthreads();
    sm[t] += add;
    __syncthreads();
  }
  if (t < nb) partial[t] = sm[t] - v;
  if (t == 511) off[N] = sm[511];
}

__global__ __launch_bounds__(256) void k_scan3(int* __restrict__ off, const int* __restrict__ partial, int N) {
  int i = blockIdx.x * 256 + threadIdx.x;
  if (i < N) off[i] += partial[i >> 8];
}

__global__ __launch_bounds__(256) void k_scatter(const int* __restrict__ dst, const int* __restrict__ off,
                                                 int* __restrict__ cur, int* __restrict__ eid, int E) {
  int e = blockIdx.x * 256 + threadIdx.x;
  if (e < E) {
    int d = dst[e];
    int p = atomicAdd(&cur[d], 1);
    eid[off[d] + p] = e;
  }
}

__global__ __launch_bounds__(256) void k_sort(const int* __restrict__ off, int* __restrict__ eid, int N) {
  int n = blockIdx.x * 256 + threadIdx.x;
  if (n >= N) return;
  int o0 = off[n], o1 = off[n + 1];
  for (int i = o0 + 1; i < o1; ++i) {
    int v = eid[i]; int j = i - 1;
    while (j >= o0 && eid[j] > v) { eid[j + 1] = eid[j]; --j; }
    eid[j + 1] = v;
  }
}

// ---------------- edge-attention precompute (algebraic reductions) ----------------
__global__ __launch_bounds__(128) void k_meanea(const float* __restrict__ ea, const int* __restrict__ off,
                                                const int* __restrict__ eid, float* __restrict__ mea, int N) {
  int n = blockIdx.x * 128 + threadIdx.x;
  if (n >= N) return;
  int o0 = off[n], o1 = off[n + 1];
  float s0 = 0, s1 = 0, s2 = 0, s3 = 0, s4 = 0, s5 = 0;
  for (int p = o0; p < o1; ++p) {
    const float* r = ea + (size_t)eid[p] * 6;
    s0 += r[0]; s1 += r[1]; s2 += r[2]; s3 += r[3]; s4 += r[4]; s5 += r[5];
  }
  float inv = (o1 > o0) ? 1.f / (float)(o1 - o0) : 0.f;
  float* m = mea + (size_t)n * 6;
  m[0] = s0 * inv; m[1] = s1 * inv; m[2] = s2 * inv; m[3] = s3 * inv; m[4] = s4 * inv; m[5] = s5 * inv;
}

// we[l][k][h]   = sum_c lin_edge_w[l][k][h*25+c] * att_edge[l][h][c]
// wsrc[l][k][h] = sum_c lin_w[l][k][h*25+c]      * att_src[l][h][c]
// wdst[l][k][h] = sum_c lin_w[l][k][h*25+c]      * att_dst[l][h][c]
__global__ __launch_bounds__(256) void k_we2(const float* __restrict__ lew, const float* __restrict__ linw,
                                             const float* __restrict__ aeg, const float* __restrict__ asg,
                                             const float* __restrict__ adg, float* __restrict__ we,
                                             float* __restrict__ wsrc, float* __restrict__ wdst) {
  int tid = blockIdx.x * 256 + threadIdx.x;
  if (tid >= NL * HD * 8) return;
  int l = tid / (HD * 8); int r = tid % (HD * 8); int k = r >> 3; int hh = r & 7;
  const float* We = lew + (size_t)l * HD * HD + (size_t)k * HD + hh * CD;
  const float* Wl = linw + (size_t)l * HD * HD + (size_t)k * HD + hh * CD;
  const float* ae = aeg + l * NH * CD + hh * CD;
  const float* as = asg + l * NH * CD + hh * CD;
  const float* ad = adg + l * NH * CD + hh * CD;
  float s0 = 0.f, s1 = 0.f, s2 = 0.f;
#pragma unroll
  for (int c = 0; c < CD; ++c) {
    float we_ = We[c], wl_ = Wl[c];
    s0 += we_ * ae[c]; s1 += wl_ * as[c]; s2 += wl_ * ad[c];
  }
  we[tid] = s0; wsrc[tid] = s1; wdst[tid] = s2;   // layout l*1600 + k*8 + h
}

// M[l][f][h] = sum_k edge_emb_w[f][k] * we[l][k][h];  cv[l][h] = sum_k edge_emb_b[k]*we[l][k][h]
__global__ __launch_bounds__(256) void k_M(const float* __restrict__ ew, const float* __restrict__ eb,
                                           const float* __restrict__ we, float* __restrict__ Mm,
                                           float* __restrict__ cv) {
  int tid = threadIdx.x;
  if (tid < NL * 6 * 8) {
    int l = tid / 48, r = tid % 48, f = r / 8, hh = r % 8;
    float s = 0.f;
    for (int k = 0; k < HD; ++k) s += ew[f * HD + k] * we[l * 1600 + k * 8 + hh];
    Mm[tid] = s;   // l*48 + f*8 + hh
  } else if (tid < NL * 6 * 8 + NL * 8) {
    int u = tid - NL * 6 * 8, l = u / 8, hh = u % 8;
    float s = 0.f;
    for (int k = 0; k < HD; ++k) s += eb[k] * we[l * 1600 + k * 8 + hh];
    cv[u] = s;
  }
}

// self-loop attention logit contribution ae_s for all layers
__global__ __launch_bounds__(256) void k_ae_self(const float* __restrict__ mea, const int* __restrict__ cnt,
                                                 const float* __restrict__ Mm, const float* __restrict__ cv,
                                                 float* __restrict__ aes, int N) {
  int n = blockIdx.x * 256 + threadIdx.x;
  if (n >= N) return;
  bool has = cnt[n] > 0;
  float v[6];
#pragma unroll
  for (int f = 0; f < 6; ++f) v[f] = mea[(size_t)n * 6 + f];
  for (int l = 0; l < NL; ++l)
#pragma unroll
    for (int hh = 0; hh < 8; ++hh) {
      float s = 0.f;
      if (has) {
        s = cv[l * 8 + hh];
#pragma unroll
        for (int f = 0; f < 6; ++f) s += v[f] * Mm[l * 48 + f * 8 + hh];
      }
      aes[(size_t)l * N * 8 + (size_t)n * 8 + hh] = s;
    }
}

// per-layer CSR-ordered leaky-relu'd logits: lg[p][h], edge ae computed inline
__global__ __launch_bounds__(256) void k_lg(const float* __restrict__ ea, const float* __restrict__ a_src,
                                            const float* __restrict__ a_dst, const float* __restrict__ Mm,
                                            const float* __restrict__ cv, const int* __restrict__ eid,
                                            const int* __restrict__ esrc, const int* __restrict__ edst,
                                            float* __restrict__ lg, int E, int l) {
  int tid = blockIdx.x * 256 + threadIdx.x;
  if (tid >= E * 8) return;
  int p = tid >> 3, h = tid & 7;
  int e = eid[p];
  int s = esrc[e], d = edst[e];
  const float* er = ea + (size_t)e * 6;
  float aev = cv[l * 8 + h];
#pragma unroll
  for (int f = 0; f < 6; ++f) aev += er[f] * Mm[l * 48 + f * 8 + h];
  float v = a_src[(size_t)s * 8 + h] + a_dst[(size_t)d * 8 + h] + aev;
  lg[tid] = (v >= 0.f) ? v : 0.2f * v;
}

// ---------------- weight split: -> [l][224 cols][Kpad] bf16 hi/lo planes ----------------
// cols 0..199 from W[k][c]; cols 200-207/208-215 (if wsrc) from wsrc/wdst[k][h]; else 0.
__global__ __launch_bounds__(256) void k_split_w(const float* __restrict__ W, u32* __restrict__ hiT,
                                                 u32* __restrict__ loT, int K, int Kpad, int inStride,
                                                 const float* __restrict__ wsrc,
                                                 const float* __restrict__ wdst) {
  int l = blockIdx.y;
  int cpr = Kpad >> 1;
  int tot = 224 * cpr;
  int idx = blockIdx.x * 256 + threadIdx.x;
  if (idx >= tot) return;
  int c = idx / cpr, kp = (idx % cpr) * 2;
  float a0 = 0.f, a1 = 0.f;
  if (c < HD) {
    const float* Wl = W + (size_t)l * inStride;
    a0 = (kp < K) ? Wl[(size_t)kp * HD + c] : 0.f;
    a1 = (kp + 1 < K) ? Wl[(size_t)(kp + 1) * HD + c] : 0.f;
  } else if (wsrc && c < 216) {
    const float* src = ((c < 208) ? wsrc : wdst) + (size_t)l * 1600;
    int hh = (c - 200) & 7;
    a0 = (kp < K) ? src[kp * 8 + hh] : 0.f;
    a1 = (kp + 1 < K) ? src[(kp + 1) * 8 + hh] : 0.f;
  }
  u32 hi, lo; split2(a0, a1, hi, lo);
  size_t ob = (size_t)l * tot + idx;
  hiT[ob] = hi; loT[ob] = lo;
}

// merged readout weight split: readout_w [4][200][200] -> [224 cols][800 k] bf16 planes
__global__ __launch_bounds__(256) void k_split_ro(const float* __restrict__ W, u32* __restrict__ hiT,
                                                  u32* __restrict__ loT) {
  int idx = blockIdx.x * 256 + threadIdx.x;
  if (idx >= 224 * 400) return;
  int c = idx / 400, kpu = idx % 400;
  int kp = kpu * 2;                       // global k, 0..798; pairs never cross layer (200 even)
  int l = kp / HD, kl = kp % HD;
  float a0 = 0.f, a1 = 0.f;
  if (c < HD) {
    const float* Wl = W + (size_t)l * HD * HD;
    a0 = Wl[(size_t)kl * HD + c];
    a1 = Wl[(size_t)(kl + 1) * HD + c];
  }
  u32 hi, lo; split2(a0, a1, hi, lo);
  hiT[idx] = hi; loT[idx] = lo;
}

// summed readout bias
__global__ __launch_bounds__(256) void k_bsum(const float* __restrict__ rb, float* __restrict__ out) {
  int t = threadIdx.x;
  if (t < HD) out[t] = rb[t] + rb[HD + t] + rb[2 * HD + t] + rb[3 * HD + t];
}

// head W1 split: head_w1 [5][200][100] -> planes [t][112 cols][224 k] bf16
__global__ __launch_bounds__(256) void k_split_hw(const float* __restrict__ W, u32* __restrict__ hiT,
                                                  u32* __restrict__ loT) {
  int t = blockIdx.y;
  int idx = blockIdx.x * 256 + threadIdx.x;
  if (idx >= 112 * 112) return;
  int c = idx / 112, kp = (idx % 112) * 2;
  const float* Wt = W + (size_t)t * HD * 100;
  float a0 = (c < 100 && kp < HD) ? Wt[(size_t)kp * 100 + c] : 0.f;
  float a1 = (c < 100 && kp + 1 < HD) ? Wt[(size_t)(kp + 1) * 100 + c] : 0.f;
  u32 hi, lo; split2(a0, a1, hi, lo);
  size_t ob = (size_t)t * 112 * 112 + idx;
  hiT[ob] = hi; loT[ob] = lo;
}

// ---------------- MFMA GEMM v4 (split-bf16, no LDS, deep register pipeline) ----------------
// 256 threads = 4 waves: wave (wm,wn) owns rows [wm*32,+32) x cols [wn*112,+112) of a 64x224 tile.
// acc = 2 M-tiles x 7 N-tiles x 4 = 56 VGPR. Full next-K-step double-buffer prefetch of
// B frags (28x u32x4) and A rows in registers; __launch_bounds__(256,2) caps VGPR at 256.
template<int NSTEPS, bool ATTN>
__global__ __launch_bounds__(256, 2) void k_gemm_v4(const float* __restrict__ A, const u32* __restrict__ BhiT,
                                                    const u32* __restrict__ BloT, const float* __restrict__ bias,
                                                    float* __restrict__ C, float* __restrict__ aS,
                                                    float* __restrict__ aD, int M, int K, int accumulate) {
  constexpr int NT = 7;
  constexpr int bstride = NSTEPS * 16;      // u32 per column (Kpad = NSTEPS*32 bf16)
  const int lane = threadIdx.x & 63;
  const int w = threadIdx.x >> 6;
  const int wm = w >> 1, wn = w & 1;
  const int lr = lane & 15, kg = lane >> 4;
  const int kg8 = kg * 8;

  const int rowA0 = blockIdx.x * 64 + wm * 32 + lr;
  const int rowA1 = rowA0 + 16;
  const float* Ap0 = A + (size_t)((rowA0 < M) ? rowA0 : (M - 1)) * K;
  const float* Ap1 = A + (size_t)((rowA1 < M) ? rowA1 : (M - 1)) * K;
  const int colbase = wn * (NT * 16);

  int boff[NT];
#pragma unroll
  for (int t = 0; t < NT; ++t) boff[t] = (colbase + t * 16 + lr) * bstride + kg * 4;

  f32x4 acc[2][NT];
#pragma unroll
  for (int mt = 0; mt < 2; ++mt)
#pragma unroll
    for (int t = 0; t < NT; ++t) acc[mt][t] = (f32x4)0.f;

  u32x4 bhc[NT], blc[NT];
  f32x4 a0c, a0d, a1c, a1d;

  // prologue: K-step 0 (kg8+8 <= 32 <= K always)
#pragma unroll
  for (int t = 0; t < NT; ++t) {
    bhc[t] = *(const u32x4*)(BhiT + boff[t]);
    blc[t] = *(const u32x4*)(BloT + boff[t]);
  }
  a0c = *(const f32x4*)(Ap0 + kg8); a0d = *(const f32x4*)(Ap0 + kg8 + 4);
  a1c = *(const f32x4*)(Ap1 + kg8); a1d = *(const f32x4*)(Ap1 + kg8 + 4);

#pragma unroll
  for (int ks = 0; ks < NSTEPS; ++ks) {
    u32x4 bhn[NT], bln[NT];
    f32x4 a0cn = (f32x4)0.f, a0dn = (f32x4)0.f, a1cn = (f32x4)0.f, a1dn = (f32x4)0.f;
    const bool more = (ks + 1) < NSTEPS;
    if (more) {
      const int ko = (ks + 1) * 16;
#pragma unroll
      for (int t = 0; t < NT; ++t) {
        bhn[t] = *(const u32x4*)(BhiT + boff[t] + ko);
        bln[t] = *(const u32x4*)(BloT + boff[t] + ko);
      }
      const int k0n = (ks + 1) * 32 + kg8;
      if (k0n < K) {
        a0cn = *(const f32x4*)(Ap0 + k0n); a0dn = *(const f32x4*)(Ap0 + k0n + 4);
        a1cn = *(const f32x4*)(Ap1 + k0n); a1dn = *(const f32x4*)(Ap1 + k0n + 4);
      }
    }
    // build A frags for current step
    const int k0 = ks * 32 + kg8;
    bf16x8 ah0, al0, ah1, al1;
    if (k0 < K) {
      mk_frags_r(a0c, a0d, ah0, al0);
      mk_frags_r(a1c, a1d, ah1, al1);
    } else {
      u32x4 zz; zz[0] = 0; zz[1] = 0; zz[2] = 0; zz[3] = 0;
      ah0 = as_bf16x8(zz); al0 = ah0; ah1 = ah0; al1 = ah0;
    }
#pragma unroll
    for (int t = 0; t < NT; ++t) {
      bf16x8 bh = as_bf16x8(bhc[t]);
      bf16x8 bl = as_bf16x8(blc[t]);
      acc[0][t] = __builtin_amdgcn_mfma_f32_16x16x32_bf16(ah0, bh, acc[0][t], 0, 0, 0);
      acc[0][t] = __builtin_amdgcn_mfma_f32_16x16x32_bf16(ah0, bl, acc[0][t], 0, 0, 0);
      acc[0][t] = __builtin_amdgcn_mfma_f32_16x16x32_bf16(al0, bh, acc[0][t], 0, 0, 0);
      acc[1][t] = __builtin_amdgcn_mfma_f32_16x16x32_bf16(ah1, bh, acc[1][t], 0, 0, 0);
      acc[1][t] = __builtin_amdgcn_mfma_f32_16x16x32_bf16(ah1, bl, acc[1][t], 0, 0, 0);
      acc[1][t] = __builtin_amdgcn_mfma_f32_16x16x32_bf16(al1, bh, acc[1][t], 0, 0, 0);
    }
    if (more) {
#pragma unroll
      for (int t = 0; t < NT; ++t) { bhc[t] = bhn[t]; blc[t] = bln[t]; }
      a0c = a0cn; a0d = a0dn; a1c = a1cn; a1d = a1dn;
    }
  }

  // epilogue: D col = lane&15, row = 4*(lane>>4)+reg (within 16-row tile)
#pragma unroll
  for (int mt = 0; mt < 2; ++mt) {
    const int rbase = blockIdx.x * 64 + wm * 32 + mt * 16 + kg * 4;
#pragma unroll
    for (int t = 0; t < NT; ++t) {
      const int c = colbase + t * 16 + lr;
      if (c < HD) {
        const float badd = bias ? bias[c] : 0.f;
#pragma unroll
        for (int j = 0; j < 4; ++j) {
          const int r = rbase + j;
          if (r < M) {
            float v = acc[mt][t][j] + badd;
            if (accumulate) v += C[(size_t)r * HD + c];
            C[(size_t)r * HD + c] = v;
          }
        }
      } else if (ATTN && c < 216) {
        float* dstp = (c < 208) ? aS : aD;
        const int hh = (c - 200) & 7;
#pragma unroll
        for (int j = 0; j < 4; ++j) {
          const int r = rbase + j;
          if (r < M) dstp[(size_t)r * 8 + hh] = acc[mt][t][j];
        }
      }
    }
  }
}

// ---------------- head GEMM: z[t] = relu(readouts @ W1[t] + b1[t]), z [5][G][112] ----------------
__global__ __launch_bounds__(128) void k_headgemm(const float* __restrict__ A, const u32* __restrict__ hwHi,
                                                  const u32* __restrict__ hwLo, const float* __restrict__ b1,
                                                  float* __restrict__ z, int M) {
  const int task = blockIdx.y;
  const int lane = threadIdx.x & 63;
  const int w = threadIdx.x >> 6;
  const int lr = lane & 15, kg = lane >> 4;
  const int K = HD;
  const int nStep = 7;
  const int bstride = 112;

  const int rowA0 = blockIdx.x * 64 + w * 32 + lr;
  const int rowA1 = rowA0 + 16;
  const float* Ap0 = A + (size_t)((rowA0 < M) ? rowA0 : (M - 1)) * K;
  const float* Ap1 = A + (size_t)((rowA1 < M) ? rowA1 : (M - 1)) * K;
  const u32* BhT = hwHi + (size_t)task * 112 * 112;
  const u32* BlT = hwLo + (size_t)task * 112 * 112;

  f32x4 acc[2][7];
#pragma unroll
  for (int mt = 0; mt < 2; ++mt)
#pragma unroll
    for (int t = 0; t < 7; ++t) acc[mt][t] = (f32x4)0.f;

  u32x4 zz; zz[0] = 0; zz[1] = 0; zz[2] = 0; zz[3] = 0;
  const bf16x8 zfrag = as_bf16x8(zz);

  for (int ks = 0; ks < nStep; ++ks) {
    const int kb = ks * 32;
    const int k0 = kb + kg * 8;
    bf16x8 ah0, al0, ah1, al1;
    if (k0 < K) {
      mk_frags(Ap0 + k0, ah0, al0);
      mk_frags(Ap1 + k0, ah1, al1);
    } else {
      ah0 = zfrag; al0 = zfrag; ah1 = zfrag; al1 = zfrag;
    }
    const u32* Bh = BhT + (kb >> 1) + kg * 4;
    const u32* Bl = BlT + (kb >> 1) + kg * 4;
#pragma unroll
    for (int t = 0; t < 7; ++t) {
      const size_t cb = (size_t)(t * 16 + lr) * bstride;
      bf16x8 bh = as_bf16x8(*(const u32x4*)(Bh + cb));
      bf16x8 bl = as_bf16x8(*(const u32x4*)(Bl + cb));
      acc[0][t] = __builtin_amdgcn_mfma_f32_16x16x32_bf16(ah0, bh, acc[0][t], 0, 0, 0);
      acc[0][t] = __builtin_amdgcn_mfma_f32_16x16x32_bf16(ah0, bl, acc[0][t], 0, 0, 0);
      acc[0][t] = __builtin_amdgcn_mfma_f32_16x16x32_bf16(al0, bh, acc[0][t], 0, 0, 0);
      acc[1][t] = __builtin_amdgcn_mfma_f32_16x16x32_bf16(ah1, bh, acc[1][t], 0, 0, 0);
      acc[1][t] = __builtin_amdgcn_mfma_f32_16x16x32_bf16(ah1, bl, acc[1][t], 0, 0, 0);
      acc[1][t] = __builtin_amdgcn_mfma_f32_16x16x32_bf16(al1, bh, acc[1][t], 0, 0, 0);
    }
  }

#pragma unroll
  for (int mt = 0; mt < 2; ++mt) {
    const int rbase = blockIdx.x * 64 + w * 32 + mt * 16 + kg * 4;
#pragma unroll
    for (int t = 0; t < 7; ++t) {
      const int c = t * 16 + lr;
      if (c < 100) {
        const float badd = b1[task * 100 + c];
#pragma unroll
        for (int j = 0; j < 4; ++j) {
          const int r = rbase + j;
          if (r < M) {
            float v = acc[mt][t][j] + badd;
            z[((size_t)task * M + r) * 112 + c] = v > 0.f ? v : 0.f;
          }
        }
      }
    }
  }
}

__global__ __launch_bounds__(256) void k_heads2(const float* __restrict__ z, const float* __restrict__ w2,
                                                const float* __restrict__ b2, float* __restrict__ out, int G) {
  int lane = threadIdx.x & 63;
  int idx = blockIdx.x * 4 + (threadIdx.x >> 6);
  if (idx >= 5 * G) return;
  int t = idx / G, g = idx % G;
  const float* zr = z + ((size_t)t * G + g) * 112;
  float p = 0.f;
  if (lane < 100) p += zr[lane] * w2[t * 100 + lane];
  if (lane < 36)  p += zr[lane + 64] * w2[t * 100 + 64 + lane];
  for (int o = 32; o >= 1; o >>= 1) p += __shfl_down(p, o);
  if (lane == 0) {
    float zv = p + b2[t];
    bool sig = (t == 0) | (t == 3) | (t == 4);
    out[idx] = sig ? 1.f / (1.f + expf(-zv)) : zv;
  }
}

// ---------------- aggregation v2: wave per node, 8 edges x 8 heads per iteration ----------------
__global__ __launch_bounds__(256) void k_aggr2(const float* __restrict__ xs, const float* __restrict__ a_src,
                                               const float* __restrict__ a_dst, const float* __restrict__ lg,
                                               const float* __restrict__ aes, const float* __restrict__ gb,
                                               const int* __restrict__ off, const int* __restrict__ eid,
                                               const int* __restrict__ esrc, float* __restrict__ h_out, int N) {
  int lane = threadIdx.x & 63;
  int node = blockIdx.x * 4 + (threadIdx.x >> 6);
  if (node >= N) return;
  const int h = lane & 7, q = lane >> 3;
  const int o0 = off[node], o1 = off[node + 1];
  const int hh0 = lane / 25, hh1 = (lane + 64) / 25, hh2 = (lane + 128) / 25, hh3 = (lane + 192) / 25;

  float lself = 0.f;
  if (lane < 8) {
    float v = a_src[(size_t)node * 8 + lane] + a_dst[(size_t)node * 8 + lane] + aes[(size_t)node * 8 + lane];
    lself = (v >= 0.f) ? v : 0.2f * v;
  }
  float mx = -1e30f;
  for (int p0 = o0; p0 < o1; p0 += 8) {
    int p = p0 + q;
    if (p < o1) mx = fmaxf(mx, lg[(size_t)p * 8 + h]);
  }
  mx = fmaxf(mx, __shfl_xor(mx, 8));
  mx = fmaxf(mx, __shfl_xor(mx, 16));
  mx = fmaxf(mx, __shfl_xor(mx, 32));
  mx = fmaxf(mx, __shfl(lself, h));

  float acc0 = 0.f, acc1 = 0.f, acc2 = 0.f, acc3 = 0.f, wsum = 0.f;
  for (int p0 = o0; p0 < o1; p0 += 8) {
    int p = p0 + q;
    bool valid = p < o1;
    float w = 0.f; int s = 0;
    if (valid) {
      w = expf(lg[(size_t)p * 8 + h] - mx);
      s = esrc[eid[p]];
    }
    wsum += w;
    int cnt = o1 - p0; if (cnt > 8) cnt = 8;
    for (int j = 0; j < cnt; ++j) {
      float wa = __shfl(w, j * 8 + hh0);
      float wb = __shfl(w, j * 8 + hh1);
      float wc = __shfl(w, j * 8 + hh2);
      float wd = __shfl(w, j * 8 + hh3);
      int sj = __shfl(s, j * 8);
      const float* xr = xs + (size_t)sj * HD;
      acc0 += wa * xr[lane];
      acc1 += wb * xr[lane + 64];
      acc2 += wc * xr[lane + 128];
      if (lane < 8) acc3 += wd * xr[lane + 192];
    }
  }
  wsum += __shfl_xor(wsum, 8);
  wsum += __shfl_xor(wsum, 16);
  wsum += __shfl_xor(wsum, 32);

  float wself = (lane < 8) ? expf(lself - mx) : 0.f;
  {
    float wa = __shfl(wself, hh0), wb = __shfl(wself, hh1);
    float wc = __shfl(wself, hh2), wd = __shfl(wself, hh3);
    const float* xr = xs + (size_t)node * HD;
    acc0 += wa * xr[lane];
    acc1 += wb * xr[lane + 64];
    acc2 += wc * xr[lane + 128];
    if (lane < 8) acc3 += wd * xr[lane + 192];
    wsum += __shfl(wself, h);
  }

  float sa = __shfl(wsum, hh0) + 1e-16f, sb = __shfl(wsum, hh1) + 1e-16f;
  float sc = __shfl(wsum, hh2) + 1e-16f, sd = __shfl(wsum, hh3) + 1e-16f;
  float* ho = h_out + (size_t)node * HD;
  ho[lane]       = acc0 / sa + gb[lane];
  ho[lane + 64]  = acc1 / sb + gb[lane + 64];
  ho[lane + 128] = acc2 / sc + gb[lane + 128];
  if (lane < 8) ho[lane + 192] = acc3 / sd + gb[lane + 192];
}

__global__ __launch_bounds__(256) void k_gstart(const int* __restrict__ batch, int* __restrict__ gstart,
                                                int N, int G) {
  int i = blockIdx.x * 256 + threadIdx.x;
  if (i >= N) return;
  int b = batch[i];
  int pb = (i == 0) ? -1 : batch[i - 1];
  for (int g = pb + 1; g <= b; ++g) gstart[g] = i;
  if (i == N - 1) for (int g = b + 1; g <= G; ++g) gstart[g] = N;
}

// pool into pooled4[g][coff + c] with leading dim ld
__global__ __launch_bounds__(256) void k_pool(const float* __restrict__ h, const int* __restrict__ gstart,
                                              float* __restrict__ pooled, int G, int ld, int coff) {
  int g = blockIdx.x, c = threadIdx.x;
  if (c >= HD) return;
  int s0 = gstart[g], s1 = gstart[g + 1];
  float acc = 0.f;
  for (int i = s0; i < s1; ++i) acc += h[(size_t)i * HD + c];
  pooled[(size_t)g * ld + coff + c] = acc;
}

extern "C" void kernel_launch(void* const* d_in, const int* in_sizes, int n_in,
                              void* d_out, int out_size, void* d_ws, size_t ws_size,
                              hipStream_t stream) {
  const float* x         = (const float*)d_in[0];
  const float* edge_attr = (const float*)d_in[1];
  const float* node_w    = (const float*)d_in[2];
  const float* node_b    = (const float*)d_in[3];
  const float* edge_w    = (const float*)d_in[4];
  const float* edge_b    = (const float*)d_in[5];
  const float* lin_w     = (const float*)d_in[6];
  const float* lin_edge_w= (const float*)d_in[7];
  const float* att_src   = (const float*)d_in[8];
  const float* att_dst   = (const float*)d_in[9];
  const float* att_edge  = (const float*)d_in[10];
  const float* gat_bias  = (const float*)d_in[11];
  const float* readout_w = (const float*)d_in[12];
  const float* readout_b = (const float*)d_in[13];
  const float* head_w1   = (const float*)d_in[14];
  const float* head_b1   = (const float*)d_in[15];
  const float* head_w2   = (const float*)d_in[16];
  const float* head_b2   = (const float*)d_in[17];
  const int*   edge_index= (const int*)d_in[18];
  const int*   batch     = (const int*)d_in[19];

  const int N = in_sizes[0] / 64;
  const int E = in_sizes[1] / 6;
  const int G = out_size / 5;
  const int* srcI = edge_index;
  const int* dstI = edge_index + E;

  char* wsb = (char*)d_ws;
  size_t o = 0;
  auto alloc = [&](size_t bytes) -> void* {
    void* p = wsb + o;
    o = (o + bytes + 255) & ~(size_t)255;
    return p;
  };
  float* h       = (float*)alloc((size_t)N * HD * 4);
  float* xs      = (float*)alloc((size_t)N * HD * 4);
  float* a_src   = (float*)alloc((size_t)N * 8 * 4);
  float* a_dst   = (float*)alloc((size_t)N * 8 * 4);
  float* lg      = (float*)alloc((size_t)E * 8 * 4);
  float* ae_s    = (float*)alloc((size_t)NL * N * 8 * 4);
  float* mean_ea = (float*)alloc((size_t)N * 6 * 4);
  float* we      = (float*)alloc((size_t)NL * HD * 8 * 4);
  float* wsrc    = (float*)alloc((size_t)NL * HD * 8 * 4);
  float* wdst    = (float*)alloc((size_t)NL * HD * 8 * 4);
  float* Mm      = (float*)alloc((size_t)NL * 6 * 8 * 4);
  float* cv      = (float*)alloc((size_t)NL * 8 * 4);
  int* cnt       = (int*)alloc((size_t)N * 4);
  int* cur       = (int*)alloc((size_t)N * 4);
  int* off       = (int*)alloc((size_t)(N + 1) * 4);
  int* partial   = (int*)alloc(512 * 4);
  int* eid       = (int*)alloc((size_t)E * 4);
  int* gstart    = (int*)alloc((size_t)(G + 1) * 4);
  float* pooled4 = (float*)alloc((size_t)G * 800 * 4);
  float* readouts= (float*)alloc((size_t)G * HD * 4);
  float* bsum    = (float*)alloc(HD * 4);
  // split-weight planes (u32 = 2 bf16), all 224 columns wide
  u32* nodeW_hi  = (u32*)alloc(224 * 32 * 4);                  // [224][64] bf16
  u32* nodeW_lo  = (u32*)alloc(224 * 32 * 4);
  u32* linW_hi   = (u32*)alloc((size_t)NL * 224 * 112 * 4);    // [l][224][224] bf16
  u32* linW_lo   = (u32*)alloc((size_t)NL * 224 * 112 * 4);
  u32* ro4_hi    = (u32*)alloc((size_t)224 * 400 * 4);         // [224][800] bf16
  u32* ro4_lo    = (u32*)alloc((size_t)224 * 400 * 4);
  u32* hw_hi     = (u32*)alloc((size_t)5 * 112 * 112 * 4);
  u32* hw_lo     = (u32*)alloc((size_t)5 * 112 * 112 * 4);
  float* zbuf    = (float*)alloc((size_t)5 * G * 112 * 4);
  (void)ws_size; (void)n_in;

  hipMemsetAsync(cnt, 0, (size_t)N * 4, stream);
  hipMemsetAsync(cur, 0, (size_t)N * 4, stream);

  int nb = (N + 255) / 256;
  k_hist<<<(E + 255) / 256, 256, 0, stream>>>(dstI, cnt, E);
  k_scan1<<<nb, 256, 0, stream>>>(cnt, off, partial, N);
  k_scan2<<<1, 512, 0, stream>>>(partial, nb, off, N);
  k_scan3<<<nb, 256, 0, stream>>>(off, partial, N);
  k_scatter<<<(E + 255) / 256, 256, 0, stream>>>(dstI, off, cur, eid, E);
  k_sort<<<nb, 256, 0, stream>>>(off, eid, N);
  k_meanea<<<(N + 127) / 128, 128, 0, stream>>>(edge_attr, off, eid, mean_ea, N);
  k_we2<<<(NL * HD * 8 + 255) / 256, 256, 0, stream>>>(lin_edge_w, lin_w, att_edge, att_src, att_dst,
                                                       we, wsrc, wdst);
  k_M<<<1, 256, 0, stream>>>(edge_w, edge_b, we, Mm, cv);
  k_ae_self<<<(N + 255) / 256, 256, 0, stream>>>(mean_ea, cnt, Mm, cv, ae_s, N);

  // weight splits
  {
    dim3 g1((224 * 32 + 255) / 256, 1);
    k_split_w<<<g1, 256, 0, stream>>>(node_w, nodeW_hi, nodeW_lo, 64, 64, 0, nullptr, nullptr);
    dim3 g2((224 * 112 + 255) / 256, NL);
    k_split_w<<<g2, 256, 0, stream>>>(lin_w, linW_hi, linW_lo, HD, 224, HD * HD, wsrc, wdst);
    k_split_ro<<<(224 * 400 + 255) / 256, 256, 0, stream>>>(readout_w, ro4_hi, ro4_lo);
    k_bsum<<<1, 256, 0, stream>>>(readout_b, bsum);
    dim3 g3((112 * 112 + 255) / 256, 5);
    k_split_hw<<<g3, 256, 0, stream>>>(head_w1, hw_hi, hw_lo);
  }

  const int gemmBlocks = (N + 63) / 64;
  k_gemm_v4<2, false><<<gemmBlocks, 256, 0, stream>>>(x, nodeW_hi, nodeW_lo, node_b, h,
                                                      nullptr, nullptr, N, 64, 0);
  k_gstart<<<nb, 256, 0, stream>>>(batch, gstart, N, G);

  for (int l = 0; l < NL; ++l) {
    k_gemm_v4<7, true><<<gemmBlocks, 256, 0, stream>>>(h, linW_hi + (size_t)l * 224 * 112,
                                                       linW_lo + (size_t)l * 224 * 112, nullptr, xs,
                                                       a_src, a_dst, N, HD, 0);
    k_lg<<<((size_t)E * 8 + 255) / 256, 256, 0, stream>>>(edge_attr, a_src, a_dst, Mm, cv,
                                                          eid, srcI, dstI, lg, E, l);
    k_aggr2<<<(N + 3) / 4, 256, 0, stream>>>(xs, a_src, a_dst, lg, ae_s + (size_t)l * N * 8,
                                             gat_bias + l * HD, off, eid, srcI, h, N);
    k_pool<<<G, 256, 0, stream>>>(h, gstart, pooled4, G, 800, l * HD);
  }
  // merged readout: readouts = pooled4 @ roW4 + sum_l b_l   (K = 800)
  k_gemm_v4<25, false><<<(G + 63) / 64, 256, 0, stream>>>(pooled4, ro4_hi, ro4_lo, bsum, readouts,
                                                          nullptr, nullptr, G, 800, 0);
  {
    dim3 hg((G + 63) / 64, 5);
    k_headgemm<<<hg, 128, 0, stream>>>(readouts, hw_hi, hw_lo, head_b1, zbuf, G);
  }
  k_heads2<<<(5 * G + 3) / 4, 256, 0, stream>>>(zbuf, head_w2, head_b2, (float*)d_out, G);
}

// Round 9
// 927.738 us; speedup vs baseline: 5.7712x; 1.1601x over previous
//
#include <hip/hip_runtime.h>
#include <cstdint>
#include <cstddef>

static constexpr int HD = 200;   // hidden
static constexpr int NH = 8;     // heads
static constexpr int CD = 25;    // per-head dim
static constexpr int NL = 4;     // layers

typedef unsigned int u32;
typedef unsigned int u32x4 __attribute__((ext_vector_type(4)));
typedef float f32x4 __attribute__((ext_vector_type(4)));
typedef __bf16 bf16x8 __attribute__((ext_vector_type(8)));

union U8cast { u32x4 u; bf16x8 b; };
__device__ inline bf16x8 as_bf16x8(u32x4 v) { U8cast x; x.u = v; return x.b; }

// truncation split: a = hi + lo + eps, |eps| <= 2^-16 |a|; packs 2 elems per u32.
__device__ inline void split2(float a0, float a1, u32& hi, u32& lo) {
  u32 u0 = __builtin_bit_cast(u32, a0), u1 = __builtin_bit_cast(u32, a1);
  u32 h0 = u0 & 0xffff0000u, h1 = u1 & 0xffff0000u;
  hi = (u0 >> 16) | h1;
  float r0 = a0 - __builtin_bit_cast(float, h0);
  float r1 = a1 - __builtin_bit_cast(float, h1);
  lo = (__builtin_bit_cast(u32, r0) >> 16) | (__builtin_bit_cast(u32, r1) & 0xffff0000u);
}

__device__ inline void mk_frags_r(f32x4 x0, f32x4 x1, bf16x8& hi8, bf16x8& lo8) {
  u32x4 h, l;
  u32 th, tl;
  split2(x0[0], x0[1], th, tl); h[0] = th; l[0] = tl;
  split2(x0[2], x0[3], th, tl); h[1] = th; l[1] = tl;
  split2(x1[0], x1[1], th, tl); h[2] = th; l[2] = tl;
  split2(x1[2], x1[3], th, tl); h[3] = th; l[3] = tl;
  hi8 = as_bf16x8(h); lo8 = as_bf16x8(l);
}

__device__ inline void mk_frags(const float* __restrict__ ap, bf16x8& hi8, bf16x8& lo8) {
  mk_frags_r(*(const f32x4*)ap, *(const f32x4*)(ap + 4), hi8, lo8);
}

// ---------------- CSR build ----------------
__global__ __launch_bounds__(256) void k_hist(const int* __restrict__ dst, int* __restrict__ cnt, int E) {
  int e = blockIdx.x * 256 + threadIdx.x;
  if (e < E) atomicAdd(&cnt[dst[e]], 1);
}

__global__ __launch_bounds__(256) void k_scan1(const int* __restrict__ cnt, int* __restrict__ off,
                                               int* __restrict__ partial, int N) {
  __shared__ int sm[256];
  int t = threadIdx.x, i = blockIdx.x * 256 + t;
  int v = (i < N) ? cnt[i] : 0;
  sm[t] = v; __syncthreads();
  for (int o = 1; o < 256; o <<= 1) {
    int add = (t >= o) ? sm[t - o] : 0;
    __syncthreads();
    sm[t] += add;
    __syncthreads();
  }
  if (i < N) off[i] = sm[t] - v;
  if (t == 255) partial[blockIdx.x] = sm[255];
}

__global__ __launch_bounds__(512) void k_scan2(int* __restrict__ partial, int nb, int* __restrict__ off, int N) {
  __shared__ int sm[512];
  int t = threadIdx.x;
  int v = (t < nb) ? partial[t] : 0;
  sm[t] = v; __syncthreads();
  for (int o = 1; o < 512; o <<= 1) {
    int add = (t >= o) ? sm[t - o] : 0;
    __syncthreads();
    sm[t] += add;
    __syncthreads();
  }
  if (t < nb) partial[t] = sm[t] - v;
  if (t == 511) off[N] = sm[511];
}

__global__ __launch_bounds__(256) void k_scan3(int* __restrict__ off, const int* __restrict__ partial, int N) {
  int i = blockIdx.x * 256 + threadIdx.x;
  if (i < N) off[i] += partial[i >> 8];
}

__global__ __launch_bounds__(256) void k_scatter(const int* __restrict__ dst, const int* __restrict__ off,
                                                 int* __restrict__ cur, int* __restrict__ eid, int E) {
  int e = blockIdx.x * 256 + threadIdx.x;
  if (e < E) {
    int d = dst[e];
    int p = atomicAdd(&cur[d], 1);
    eid[off[d] + p] = e;
  }
}

__global__ __launch_bounds__(256) void k_sort(const int* __restrict__ off, int* __restrict__ eid, int N) {
  int n = blockIdx.x * 256 + threadIdx.x;
  if (n >= N) return;
  int o0 = off[n], o1 = off[n + 1];
  for (int i = o0 + 1; i < o1; ++i) {
    int v = eid[i]; int j = i - 1;
    while (j >= o0 && eid[j] > v) { eid[j + 1] = eid[j]; --j; }
    eid[j + 1] = v;
  }
}

// ---------------- edge-attention precompute (algebraic reductions) ----------------
__global__ __launch_bounds__(128) void k_meanea(const float* __restrict__ ea, const int* __restrict__ off,
                                                const int* __restrict__ eid, float* __restrict__ mea, int N) {
  int n = blockIdx.x * 128 + threadIdx.x;
  if (n >= N) return;
  int o0 = off[n], o1 = off[n + 1];
  float s0 = 0, s1 = 0, s2 = 0, s3 = 0, s4 = 0, s5 = 0;
  for (int p = o0; p < o1; ++p) {
    const float* r = ea + (size_t)eid[p] * 6;
    s0 += r[0]; s1 += r[1]; s2 += r[2]; s3 += r[3]; s4 += r[4]; s5 += r[5];
  }
  float inv = (o1 > o0) ? 1.f / (float)(o1 - o0) : 0.f;
  float* m = mea + (size_t)n * 6;
  m[0] = s0 * inv; m[1] = s1 * inv; m[2] = s2 * inv; m[3] = s3 * inv; m[4] = s4 * inv; m[5] = s5 * inv;
}

// we[l][k][h]   = sum_c lin_edge_w[l][k][h*25+c] * att_edge[l][h][c]
// wsrc[l][k][h] = sum_c lin_w[l][k][h*25+c]      * att_src[l][h][c]
// wdst[l][k][h] = sum_c lin_w[l][k][h*25+c]      * att_dst[l][h][c]
__global__ __launch_bounds__(256) void k_we2(const float* __restrict__ lew, const float* __restrict__ linw,
                                             const float* __restrict__ aeg, const float* __restrict__ asg,
                                             const float* __restrict__ adg, float* __restrict__ we,
                                             float* __restrict__ wsrc, float* __restrict__ wdst) {
  int tid = blockIdx.x * 256 + threadIdx.x;
  if (tid >= NL * HD * 8) return;
  int l = tid / (HD * 8); int r = tid % (HD * 8); int k = r >> 3; int hh = r & 7;
  const float* We = lew + (size_t)l * HD * HD + (size_t)k * HD + hh * CD;
  const float* Wl = linw + (size_t)l * HD * HD + (size_t)k * HD + hh * CD;
  const float* ae = aeg + l * NH * CD + hh * CD;
  const float* as = asg + l * NH * CD + hh * CD;
  const float* ad = adg + l * NH * CD + hh * CD;
  float s0 = 0.f, s1 = 0.f, s2 = 0.f;
#pragma unroll
  for (int c = 0; c < CD; ++c) {
    float we_ = We[c], wl_ = Wl[c];
    s0 += we_ * ae[c]; s1 += wl_ * as[c]; s2 += wl_ * ad[c];
  }
  we[tid] = s0; wsrc[tid] = s1; wdst[tid] = s2;   // layout l*1600 + k*8 + h
}

// M[l][f][h] = sum_k edge_emb_w[f][k] * we[l][k][h];  cv[l][h] = sum_k edge_emb_b[k]*we[l][k][h]
__global__ __launch_bounds__(256) void k_M(const float* __restrict__ ew, const float* __restrict__ eb,
                                           const float* __restrict__ we, float* __restrict__ Mm,
                                           float* __restrict__ cv) {
  int tid = threadIdx.x;
  if (tid < NL * 6 * 8) {
    int l = tid / 48, r = tid % 48, f = r / 8, hh = r % 8;
    float s = 0.f;
    for (int k = 0; k < HD; ++k) s += ew[f * HD + k] * we[l * 1600 + k * 8 + hh];
    Mm[tid] = s;   // l*48 + f*8 + hh
  } else if (tid < NL * 6 * 8 + NL * 8) {
    int u = tid - NL * 6 * 8, l = u / 8, hh = u % 8;
    float s = 0.f;
    for (int k = 0; k < HD; ++k) s += eb[k] * we[l * 1600 + k * 8 + hh];
    cv[u] = s;
  }
}

// self-loop attention logit contribution ae_s for all layers
__global__ __launch_bounds__(256) void k_ae_self(const float* __restrict__ mea, const int* __restrict__ cnt,
                                                 const float* __restrict__ Mm, const float* __restrict__ cv,
                                                 float* __restrict__ aes, int N) {
  int n = blockIdx.x * 256 + threadIdx.x;
  if (n >= N) return;
  bool has = cnt[n] > 0;
  float v[6];
#pragma unroll
  for (int f = 0; f < 6; ++f) v[f] = mea[(size_t)n * 6 + f];
  for (int l = 0; l < NL; ++l)
#pragma unroll
    for (int hh = 0; hh < 8; ++hh) {
      float s = 0.f;
      if (has) {
        s = cv[l * 8 + hh];
#pragma unroll
        for (int f = 0; f < 6; ++f) s += v[f] * Mm[l * 48 + f * 8 + hh];
      }
      aes[(size_t)l * N * 8 + (size_t)n * 8 + hh] = s;
    }
}

// per-layer CSR-ordered leaky-relu'd logits: lg[p][h], edge ae computed inline
__global__ __launch_bounds__(256) void k_lg(const float* __restrict__ ea, const float* __restrict__ a_src,
                                            const float* __restrict__ a_dst, const float* __restrict__ Mm,
                                            const float* __restrict__ cv, const int* __restrict__ eid,
                                            const int* __restrict__ esrc, const int* __restrict__ edst,
                                            float* __restrict__ lg, int E, int l) {
  int tid = blockIdx.x * 256 + threadIdx.x;
  if (tid >= E * 8) return;
  int p = tid >> 3, h = tid & 7;
  int e = eid[p];
  int s = esrc[e], d = edst[e];
  const float* er = ea + (size_t)e * 6;
  float aev = cv[l * 8 + h];
#pragma unroll
  for (int f = 0; f < 6; ++f) aev += er[f] * Mm[l * 48 + f * 8 + h];
  float v = a_src[(size_t)s * 8 + h] + a_dst[(size_t)d * 8 + h] + aev;
  lg[tid] = (v >= 0.f) ? v : 0.2f * v;
}

// ---------------- weight split v5: LDS-image layout ----------------
// out[l][ks][plane][col c][granule kg][4 u32]; per K-step block = 7168 u32 = 28 KB
// (hi plane 3584 u32, lo plane 3584 u32; granule = 8 bf16 of column c, k = ks*32+kg*8..+8).
// cols 0..199 from W[k][c]; cols 200-207/208-215 (if wsrc) from wsrc/wdst[k][h]; else 0.
__global__ __launch_bounds__(256) void k_split5(const float* __restrict__ W, u32* __restrict__ out,
                                                int K, int nsteps, int inStride,
                                                const float* __restrict__ wsrc,
                                                const float* __restrict__ wdst) {
  int l = blockIdx.y;
  int tot = nsteps * 7168;
  int idx = blockIdx.x * 256 + threadIdx.x;
  if (idx >= tot) return;
  int ks = idx / 7168, r = idx % 7168;
  int plane = r / 3584, r2 = r % 3584;
  int g = r2 >> 2, j = r2 & 3;
  int c = g >> 2, kg = g & 3;
  int k = ks * 32 + kg * 8 + j * 2;
  float a0 = 0.f, a1 = 0.f;
  if (c < HD) {
    if (k < K) {
      const float* Wl = W + (size_t)l * inStride;
      a0 = Wl[(size_t)k * HD + c];
      a1 = Wl[(size_t)(k + 1) * HD + c];
    }
  } else if (wsrc && c < 216 && k < K) {
    const float* src = ((c < 208) ? wsrc : wdst) + (size_t)l * 1600;
    int hh = (c - 200) & 7;
    a0 = src[k * 8 + hh];
    a1 = src[(k + 1) * 8 + hh];
  }
  u32 hi, lo; split2(a0, a1, hi, lo);
  out[(size_t)l * tot + idx] = (plane == 0) ? hi : lo;
}

// merged readout split: readout_w [4][200][200] -> LDS-image [25 ks][7168 u32], K global 0..799
__global__ __launch_bounds__(256) void k_split_ro5(const float* __restrict__ W, u32* __restrict__ out) {
  int idx = blockIdx.x * 256 + threadIdx.x;
  if (idx >= 25 * 7168) return;
  int ks = idx / 7168, r = idx % 7168;
  int plane = r / 3584, r2 = r % 3584;
  int g = r2 >> 2, j = r2 & 3;
  int c = g >> 2, kg = g & 3;
  int k = ks * 32 + kg * 8 + j * 2;       // 0..798, even -> pair stays in one layer
  float a0 = 0.f, a1 = 0.f;
  if (c < HD) {
    int lsrc = k / HD, kl = k % HD;
    const float* Wl = W + (size_t)lsrc * HD * HD;
    a0 = Wl[(size_t)kl * HD + c];
    a1 = Wl[(size_t)(kl + 1) * HD + c];
  }
  u32 hi, lo; split2(a0, a1, hi, lo);
  out[idx] = (plane == 0) ? hi : lo;
}

// summed readout bias
__global__ __launch_bounds__(256) void k_bsum(const float* __restrict__ rb, float* __restrict__ out) {
  int t = threadIdx.x;
  if (t < HD) out[t] = rb[t] + rb[HD + t] + rb[2 * HD + t] + rb[3 * HD + t];
}

// head W1 split: head_w1 [5][200][100] -> planes [t][112 cols][224 k] bf16 (old layout, k_headgemm)
__global__ __launch_bounds__(256) void k_split_hw(const float* __restrict__ W, u32* __restrict__ hiT,
                                                  u32* __restrict__ loT) {
  int t = blockIdx.y;
  int idx = blockIdx.x * 256 + threadIdx.x;
  if (idx >= 112 * 112) return;
  int c = idx / 112, kp = (idx % 112) * 2;
  const float* Wt = W + (size_t)t * HD * 100;
  float a0 = (c < 100 && kp < HD) ? Wt[(size_t)kp * 100 + c] : 0.f;
  float a1 = (c < 100 && kp + 1 < HD) ? Wt[(size_t)(kp + 1) * 100 + c] : 0.f;
  u32 hi, lo; split2(a0, a1, hi, lo);
  size_t ob = (size_t)t * 112 * 112 + idx;
  hiT[ob] = hi; loT[ob] = lo;
}

// ---------------- MFMA GEMM v5 (split-bf16, B double-buffered in LDS via global_load_lds) ----
// 256 threads = 4 waves: wave (wm,wn) owns rows [wm*32,+32) x cols [wn*112,+112) of a 64x224 tile.
// B pre-split in per-K-step LDS-image layout -> staging is a straight async 28 KB copy.
// One barrier per K-step; ds_read_b128 fragments; A fp32->split in registers with 1-step prefetch.
template<int NSTEPS, bool ATTN>
__global__ __launch_bounds__(256) void k_gemm_v5(const float* __restrict__ A, const u32* __restrict__ Bpk,
                                                 const float* __restrict__ bias, float* __restrict__ C,
                                                 float* __restrict__ aS, float* __restrict__ aD,
                                                 int M, int K) {
  constexpr int NT = 7;
  __shared__ u32 smem[2 * 7168];            // 2 bufs x (hi 3584 + lo 3584) u32 = 57344 B
  const int tid = threadIdx.x;
  const int lane = tid & 63;
  const int w = tid >> 6;
  const int wm = w >> 1, wn = w & 1;
  const int lr = lane & 15, kg = lane >> 4;
  const int kg8 = kg * 8;

  const int rowA0 = blockIdx.x * 64 + wm * 32 + lr;
  const int rowA1 = rowA0 + 16;
  const float* Ap0 = A + (size_t)((rowA0 < M) ? rowA0 : (M - 1)) * K;
  const float* Ap1 = A + (size_t)((rowA1 < M) ? rowA1 : (M - 1)) * K;
  const int colbase = wn * 112;
  const int dsbase = (colbase + lr) * 16 + kg * 4;   // u32 index of lane's granule within a plane

  f32x4 acc[2][NT];
#pragma unroll
  for (int mt = 0; mt < 2; ++mt)
#pragma unroll
    for (int t = 0; t < NT; ++t) acc[mt][t] = (f32x4)0.f;

  // prologue: stage K-step 0 into buffer 0 (28 chunks of 1 KB; chunk = i*4 + w)
#pragma unroll
  for (int i = 0; i < 7; ++i) {
    const int chunk = i * 4 + w;
    __builtin_amdgcn_global_load_lds((const void*)(Bpk + chunk * 256 + lane * 4),
                                     (void*)(smem + chunk * 256), 16, 0, 0);
  }
  f32x4 a0c, a0d, a1c, a1d;
  a0c = *(const f32x4*)(Ap0 + kg8); a0d = *(const f32x4*)(Ap0 + kg8 + 4);
  a1c = *(const f32x4*)(Ap1 + kg8); a1d = *(const f32x4*)(Ap1 + kg8 + 4);
  __syncthreads();

  int cur = 0;
  for (int ks = 0; ks < NSTEPS; ++ks) {
    const bool more = (ks + 1) < NSTEPS;
    // issue async staging of next K-step into the other buffer (before consuming current)
    if (more) {
      const u32* src = Bpk + (size_t)(ks + 1) * 7168;
      u32* dst = smem + (cur ^ 1) * 7168;
#pragma unroll
      for (int i = 0; i < 7; ++i) {
        const int chunk = i * 4 + w;
        __builtin_amdgcn_global_load_lds((const void*)(src + chunk * 256 + lane * 4),
                                         (void*)(dst + chunk * 256), 16, 0, 0);
      }
    }
    // current A frags
    bf16x8 ah0, al0, ah1, al1;
    {
      const int k0 = ks * 32 + kg8;
      if (k0 < K) {                          // k0, K both multiples of 8 -> full granule valid
        mk_frags_r(a0c, a0d, ah0, al0);
        mk_frags_r(a1c, a1d, ah1, al1);
      } else {
        u32x4 zz; zz[0] = 0; zz[1] = 0; zz[2] = 0; zz[3] = 0;
        ah0 = as_bf16x8(zz); al0 = ah0; ah1 = ah0; al1 = ah0;
      }
    }
    // prefetch next-step A rows
    if (more) {
      const int k0n = (ks + 1) * 32 + kg8;
      if (k0n < K) {
        a0c = *(const f32x4*)(Ap0 + k0n); a0d = *(const f32x4*)(Ap0 + k0n + 4);
        a1c = *(const f32x4*)(Ap1 + k0n); a1d = *(const f32x4*)(Ap1 + k0n + 4);
      }
    }
    // consume current buffer
    const u32* bb = smem + cur * 7168;
#pragma unroll
    for (int t = 0; t < NT; ++t) {
      bf16x8 bh = as_bf16x8(*(const u32x4*)(bb + dsbase + t * 256));
      bf16x8 bl = as_bf16x8(*(const u32x4*)(bb + 3584 + dsbase + t * 256));
      acc[0][t] = __builtin_amdgcn_mfma_f32_16x16x32_bf16(ah0, bh, acc[0][t], 0, 0, 0);
      acc[0][t] = __builtin_amdgcn_mfma_f32_16x16x32_bf16(ah0, bl, acc[0][t], 0, 0, 0);
      acc[0][t] = __builtin_amdgcn_mfma_f32_16x16x32_bf16(al0, bh, acc[0][t], 0, 0, 0);
      acc[1][t] = __builtin_amdgcn_mfma_f32_16x16x32_bf16(ah1, bh, acc[1][t], 0, 0, 0);
      acc[1][t] = __builtin_amdgcn_mfma_f32_16x16x32_bf16(ah1, bl, acc[1][t], 0, 0, 0);
      acc[1][t] = __builtin_amdgcn_mfma_f32_16x16x32_bf16(al1, bh, acc[1][t], 0, 0, 0);
    }
    __syncthreads();   // drains staged loads + all waves done with cur
    cur ^= 1;
  }

  // epilogue: D col = lane&15, row = 4*(lane>>4)+reg (within 16-row tile)
#pragma unroll
  for (int mt = 0; mt < 2; ++mt) {
    const int rbase = blockIdx.x * 64 + wm * 32 + mt * 16 + kg * 4;
#pragma unroll
    for (int t = 0; t < NT; ++t) {
      const int c = colbase + t * 16 + lr;
      if (c < HD) {
        const float badd = bias ? bias[c] : 0.f;
#pragma unroll
        for (int j = 0; j < 4; ++j) {
          const int r = rbase + j;
          if (r < M) C[(size_t)r * HD + c] = acc[mt][t][j] + badd;
        }
      } else if (ATTN && c < 216) {
        float* dstp = (c < 208) ? aS : aD;
        const int hh = (c - 200) & 7;
#pragma unroll
        for (int j = 0; j < 4; ++j) {
          const int r = rbase + j;
          if (r < M) dstp[(size_t)r * 8 + hh] = acc[mt][t][j];
        }
      }
    }
  }
}

// ---------------- head GEMM: z[t] = relu(readouts @ W1[t] + b1[t]), z [5][G][112] ----------------
__global__ __launch_bounds__(128) void k_headgemm(const float* __restrict__ A, const u32* __restrict__ hwHi,
                                                  const u32* __restrict__ hwLo, const float* __restrict__ b1,
                                                  float* __restrict__ z, int M) {
  const int task = blockIdx.y;
  const int lane = threadIdx.x & 63;
  const int w = threadIdx.x >> 6;
  const int lr = lane & 15, kg = lane >> 4;
  const int K = HD;
  const int nStep = 7;
  const int bstride = 112;

  const int rowA0 = blockIdx.x * 64 + w * 32 + lr;
  const int rowA1 = rowA0 + 16;
  const float* Ap0 = A + (size_t)((rowA0 < M) ? rowA0 : (M - 1)) * K;
  const float* Ap1 = A + (size_t)((rowA1 < M) ? rowA1 : (M - 1)) * K;
  const u32* BhT = hwHi + (size_t)task * 112 * 112;
  const u32* BlT = hwLo + (size_t)task * 112 * 112;

  f32x4 acc[2][7];
#pragma unroll
  for (int mt = 0; mt < 2; ++mt)
#pragma unroll
    for (int t = 0; t < 7; ++t) acc[mt][t] = (f32x4)0.f;

  u32x4 zz; zz[0] = 0; zz[1] = 0; zz[2] = 0; zz[3] = 0;
  const bf16x8 zfrag = as_bf16x8(zz);

  for (int ks = 0; ks < nStep; ++ks) {
    const int kb = ks * 32;
    const int k0 = kb + kg * 8;
    bf16x8 ah0, al0, ah1, al1;
    if (k0 < K) {
      mk_frags(Ap0 + k0, ah0, al0);
      mk_frags(Ap1 + k0, ah1, al1);
    } else {
      ah0 = zfrag; al0 = zfrag; ah1 = zfrag; al1 = zfrag;
    }
    const u32* Bh = BhT + (kb >> 1) + kg * 4;
    const u32* Bl = BlT + (kb >> 1) + kg * 4;
#pragma unroll
    for (int t = 0; t < 7; ++t) {
      const size_t cb = (size_t)(t * 16 + lr) * bstride;
      bf16x8 bh = as_bf16x8(*(const u32x4*)(Bh + cb));
      bf16x8 bl = as_bf16x8(*(const u32x4*)(Bl + cb));
      acc[0][t] = __builtin_amdgcn_mfma_f32_16x16x32_bf16(ah0, bh, acc[0][t], 0, 0, 0);
      acc[0][t] = __builtin_amdgcn_mfma_f32_16x16x32_bf16(ah0, bl, acc[0][t], 0, 0, 0);
      acc[0][t] = __builtin_amdgcn_mfma_f32_16x16x32_bf16(al0, bh, acc[0][t], 0, 0, 0);
      acc[1][t] = __builtin_amdgcn_mfma_f32_16x16x32_bf16(ah1, bh, acc[1][t], 0, 0, 0);
      acc[1][t] = __builtin_amdgcn_mfma_f32_16x16x32_bf16(ah1, bl, acc[1][t], 0, 0, 0);
      acc[1][t] = __builtin_amdgcn_mfma_f32_16x16x32_bf16(al1, bh, acc[1][t], 0, 0, 0);
    }
  }

#pragma unroll
  for (int mt = 0; mt < 2; ++mt) {
    const int rbase = blockIdx.x * 64 + w * 32 + mt * 16 + kg * 4;
#pragma unroll
    for (int t = 0; t < 7; ++t) {
      const int c = t * 16 + lr;
      if (c < 100) {
        const float badd = b1[task * 100 + c];
#pragma unroll
        for (int j = 0; j < 4; ++j) {
          const int r = rbase + j;
          if (r < M) {
            float v = acc[mt][t][j] + badd;
            z[((size_t)task * M + r) * 112 + c] = v > 0.f ? v : 0.f;
          }
        }
      }
    }
  }
}

__global__ __launch_bounds__(256) void k_heads2(const float* __restrict__ z, const float* __restrict__ w2,
                                                const float* __restrict__ b2, float* __restrict__ out, int G) {
  int lane = threadIdx.x & 63;
  int idx = blockIdx.x * 4 + (threadIdx.x >> 6);
  if (idx >= 5 * G) return;
  int t = idx / G, g = idx % G;
  const float* zr = z + ((size_t)t * G + g) * 112;
  float p = 0.f;
  if (lane < 100) p += zr[lane] * w2[t * 100 + lane];
  if (lane < 36)  p += zr[lane + 64] * w2[t * 100 + 64 + lane];
  for (int o = 32; o >= 1; o >>= 1) p += __shfl_down(p, o);
  if (lane == 0) {
    float zv = p + b2[t];
    bool sig = (t == 0) | (t == 3) | (t == 4);
    out[idx] = sig ? 1.f / (1.f + expf(-zv)) : zv;
  }
}

// ---------------- aggregation v2: wave per node, 8 edges x 8 heads per iteration ----------------
__global__ __launch_bounds__(256) void k_aggr2(const float* __restrict__ xs, const float* __restrict__ a_src,
                                               const float* __restrict__ a_dst, const float* __restrict__ lg,
                                               const float* __restrict__ aes, const float* __restrict__ gb,
                                               const int* __restrict__ off, const int* __restrict__ eid,
                                               const int* __restrict__ esrc, float* __restrict__ h_out, int N) {
  int lane = threadIdx.x & 63;
  int node = blockIdx.x * 4 + (threadIdx.x >> 6);
  if (node >= N) return;
  const int h = lane & 7, q = lane >> 3;
  const int o0 = off[node], o1 = off[node + 1];
  const int hh0 = lane / 25, hh1 = (lane + 64) / 25, hh2 = (lane + 128) / 25, hh3 = (lane + 192) / 25;

  float lself = 0.f;
  if (lane < 8) {
    float v = a_src[(size_t)node * 8 + lane] + a_dst[(size_t)node * 8 + lane] + aes[(size_t)node * 8 + lane];
    lself = (v >= 0.f) ? v : 0.2f * v;
  }
  float mx = -1e30f;
  for (int p0 = o0; p0 < o1; p0 += 8) {
    int p = p0 + q;
    if (p < o1) mx = fmaxf(mx, lg[(size_t)p * 8 + h]);
  }
  mx = fmaxf(mx, __shfl_xor(mx, 8));
  mx = fmaxf(mx, __shfl_xor(mx, 16));
  mx = fmaxf(mx, __shfl_xor(mx, 32));
  mx = fmaxf(mx, __shfl(lself, h));

  float acc0 = 0.f, acc1 = 0.f, acc2 = 0.f, acc3 = 0.f, wsum = 0.f;
  for (int p0 = o0; p0 < o1; p0 += 8) {
    int p = p0 + q;
    bool valid = p < o1;
    float w = 0.f; int s = 0;
    if (valid) {
      w = expf(lg[(size_t)p * 8 + h] - mx);
      s = esrc[eid[p]];
    }
    wsum += w;
    int cnt = o1 - p0; if (cnt > 8) cnt = 8;
    for (int j = 0; j < cnt; ++j) {
      float wa = __shfl(w, j * 8 + hh0);
      float wb = __shfl(w, j * 8 + hh1);
      float wc = __shfl(w, j * 8 + hh2);
      float wd = __shfl(w, j * 8 + hh3);
      int sj = __shfl(s, j * 8);
      const float* xr = xs + (size_t)sj * HD;
      acc0 += wa * xr[lane];
      acc1 += wb * xr[lane + 64];
      acc2 += wc * xr[lane + 128];
      if (lane < 8) acc3 += wd * xr[lane + 192];
    }
  }
  wsum += __shfl_xor(wsum, 8);
  wsum += __shfl_xor(wsum, 16);
  wsum += __shfl_xor(wsum, 32);

  float wself = (lane < 8) ? expf(lself - mx) : 0.f;
  {
    float wa = __shfl(wself, hh0), wb = __shfl(wself, hh1);
    float wc = __shfl(wself, hh2), wd = __shfl(wself, hh3);
    const float* xr = xs + (size_t)node * HD;
    acc0 += wa * xr[lane];
    acc1 += wb * xr[lane + 64];
    acc2 += wc * xr[lane + 128];
    if (lane < 8) acc3 += wd * xr[lane + 192];
    wsum += __shfl(wself, h);
  }

  float sa = __shfl(wsum, hh0) + 1e-16f, sb = __shfl(wsum, hh1) + 1e-16f;
  float sc = __shfl(wsum, hh2) + 1e-16f, sd = __shfl(wsum, hh3) + 1e-16f;
  float* ho = h_out + (size_t)node * HD;
  ho[lane]       = acc0 / sa + gb[lane];
  ho[lane + 64]  = acc1 / sb + gb[lane + 64];
  ho[lane + 128] = acc2 / sc + gb[lane + 128];
  if (lane < 8) ho[lane + 192] = acc3 / sd + gb[lane + 192];
}

__global__ __launch_bounds__(256) void k_gstart(const int* __restrict__ batch, int* __restrict__ gstart,
                                                int N, int G) {
  int i = blockIdx.x * 256 + threadIdx.x;
  if (i >= N) return;
  int b = batch[i];
  int pb = (i == 0) ? -1 : batch[i - 1];
  for (int g = pb + 1; g <= b; ++g) gstart[g] = i;
  if (i == N - 1) for (int g = b + 1; g <= G; ++g) gstart[g] = N;
}

// pool into pooled4[g][coff + c] with leading dim ld
__global__ __launch_bounds__(256) void k_pool(const float* __restrict__ h, const int* __restrict__ gstart,
                                              float* __restrict__ pooled, int G, int ld, int coff) {
  int g = blockIdx.x, c = threadIdx.x;
  if (c >= HD) return;
  int s0 = gstart[g], s1 = gstart[g + 1];
  float acc = 0.f;
  for (int i = s0; i < s1; ++i) acc += h[(size_t)i * HD + c];
  pooled[(size_t)g * ld + coff + c] = acc;
}

extern "C" void kernel_launch(void* const* d_in, const int* in_sizes, int n_in,
                              void* d_out, int out_size, void* d_ws, size_t ws_size,
                              hipStream_t stream) {
  const float* x         = (const float*)d_in[0];
  const float* edge_attr = (const float*)d_in[1];
  const float* node_w    = (const float*)d_in[2];
  const float* node_b    = (const float*)d_in[3];
  const float* edge_w    = (const float*)d_in[4];
  const float* edge_b    = (const float*)d_in[5];
  const float* lin_w     = (const float*)d_in[6];
  const float* lin_edge_w= (const float*)d_in[7];
  const float* att_src   = (const float*)d_in[8];
  const float* att_dst   = (const float*)d_in[9];
  const float* att_edge  = (const float*)d_in[10];
  const float* gat_bias  = (const float*)d_in[11];
  const float* readout_w = (const float*)d_in[12];
  const float* readout_b = (const float*)d_in[13];
  const float* head_w1   = (const float*)d_in[14];
  const float* head_b1   = (const float*)d_in[15];
  const float* head_w2   = (const float*)d_in[16];
  const float* head_b2   = (const float*)d_in[17];
  const int*   edge_index= (const int*)d_in[18];
  const int*   batch     = (const int*)d_in[19];

  const int N = in_sizes[0] / 64;
  const int E = in_sizes[1] / 6;
  const int G = out_size / 5;
  const int* srcI = edge_index;
  const int* dstI = edge_index + E;

  char* wsb = (char*)d_ws;
  size_t o = 0;
  auto alloc = [&](size_t bytes) -> void* {
    void* p = wsb + o;
    o = (o + bytes + 255) & ~(size_t)255;
    return p;
  };
  float* h       = (float*)alloc((size_t)N * HD * 4);
  float* xs      = (float*)alloc((size_t)N * HD * 4);
  float* a_src   = (float*)alloc((size_t)N * 8 * 4);
  float* a_dst   = (float*)alloc((size_t)N * 8 * 4);
  float* lg      = (float*)alloc((size_t)E * 8 * 4);
  float* ae_s    = (float*)alloc((size_t)NL * N * 8 * 4);
  float* mean_ea = (float*)alloc((size_t)N * 6 * 4);
  float* we      = (float*)alloc((size_t)NL * HD * 8 * 4);
  float* wsrc    = (float*)alloc((size_t)NL * HD * 8 * 4);
  float* wdst    = (float*)alloc((size_t)NL * HD * 8 * 4);
  float* Mm      = (float*)alloc((size_t)NL * 6 * 8 * 4);
  float* cv      = (float*)alloc((size_t)NL * 8 * 4);
  int* cnt       = (int*)alloc((size_t)N * 4);
  int* cur       = (int*)alloc((size_t)N * 4);
  int* off       = (int*)alloc((size_t)(N + 1) * 4);
  int* partial   = (int*)alloc(512 * 4);
  int* eid       = (int*)alloc((size_t)E * 4);
  int* gstart    = (int*)alloc((size_t)(G + 1) * 4);
  float* pooled4 = (float*)alloc((size_t)G * 800 * 4);
  float* readouts= (float*)alloc((size_t)G * HD * 4);
  float* bsum    = (float*)alloc(HD * 4);
  // pre-split LDS-image weight buffers (u32 = 2 bf16; 7168 u32 per K-step)
  u32* nodePk    = (u32*)alloc((size_t)2 * 7168 * 4);
  u32* linPk     = (u32*)alloc((size_t)NL * 7 * 7168 * 4);
  u32* roPk      = (u32*)alloc((size_t)25 * 7168 * 4);
  u32* hw_hi     = (u32*)alloc((size_t)5 * 112 * 112 * 4);
  u32* hw_lo     = (u32*)alloc((size_t)5 * 112 * 112 * 4);
  float* zbuf    = (float*)alloc((size_t)5 * G * 112 * 4);
  (void)ws_size; (void)n_in;

  hipMemsetAsync(cnt, 0, (size_t)N * 4, stream);
  hipMemsetAsync(cur, 0, (size_t)N * 4, stream);

  int nb = (N + 255) / 256;
  k_hist<<<(E + 255) / 256, 256, 0, stream>>>(dstI, cnt, E);
  k_scan1<<<nb, 256, 0, stream>>>(cnt, off, partial, N);
  k_scan2<<<1, 512, 0, stream>>>(partial, nb, off, N);
  k_scan3<<<nb, 256, 0, stream>>>(off, partial, N);
  k_scatter<<<(E + 255) / 256, 256, 0, stream>>>(dstI, off, cur, eid, E);
  k_sort<<<nb, 256, 0, stream>>>(off, eid, N);
  k_meanea<<<(N + 127) / 128, 128, 0, stream>>>(edge_attr, off, eid, mean_ea, N);
  k_we2<<<(NL * HD * 8 + 255) / 256, 256, 0, stream>>>(lin_edge_w, lin_w, att_edge, att_src, att_dst,
                                                       we, wsrc, wdst);
  k_M<<<1, 256, 0, stream>>>(edge_w, edge_b, we, Mm, cv);
  k_ae_self<<<(N + 255) / 256, 256, 0, stream>>>(mean_ea, cnt, Mm, cv, ae_s, N);

  // weight splits
  {
    k_split5<<<dim3((2 * 7168 + 255) / 256, 1), 256, 0, stream>>>(node_w, nodePk, 64, 2, 0,
                                                                  nullptr, nullptr);
    k_split5<<<dim3((7 * 7168 + 255) / 256, NL), 256, 0, stream>>>(lin_w, linPk, HD, 7, HD * HD,
                                                                   wsrc, wdst);
    k_split_ro5<<<(25 * 7168 + 255) / 256, 256, 0, stream>>>(readout_w, roPk);
    k_bsum<<<1, 256, 0, stream>>>(readout_b, bsum);
    dim3 g3((112 * 112 + 255) / 256, 5);
    k_split_hw<<<g3, 256, 0, stream>>>(head_w1, hw_hi, hw_lo);
  }

  const int gemmBlocks = (N + 63) / 64;
  k_gemm_v5<2, false><<<gemmBlocks, 256, 0, stream>>>(x, nodePk, node_b, h, nullptr, nullptr, N, 64);
  k_gstart<<<nb, 256, 0, stream>>>(batch, gstart, N, G);

  for (int l = 0; l < NL; ++l) {
    k_gemm_v5<7, true><<<gemmBlocks, 256, 0, stream>>>(h, linPk + (size_t)l * 7 * 7168,
                                                       nullptr, xs, a_src, a_dst, N, HD);
    k_lg<<<((size_t)E * 8 + 255) / 256, 256, 0, stream>>>(edge_attr, a_src, a_dst, Mm, cv,
                                                          eid, srcI, dstI, lg, E, l);
    k_aggr2<<<(N + 3) / 4, 256, 0, stream>>>(xs, a_src, a_dst, lg, ae_s + (size_t)l * N * 8,
                                             gat_bias + l * HD, off, eid, srcI, h, N);
    k_pool<<<G, 256, 0, stream>>>(h, gstart, pooled4, G, 800, l * HD);
  }
  // merged readout: readouts = pooled4 @ roW4 + sum_l b_l   (K = 800)
  k_gemm_v5<25, false><<<(G + 63) / 64, 256, 0, stream>>>(pooled4, roPk, bsum, readouts,
                                                          nullptr, nullptr, G, 800);
  {
    dim3 hg((G + 63) / 64, 5);
    k_headgemm<<<hg, 128, 0, stream>>>(readouts, hw_hi, hw_lo, head_b1, zbuf, G);
  }
  k_heads2<<<(5 * G + 3) / 4, 256, 0, stream>>>(zbuf, head_w2, head_b2, (float*)d_out, G);
}

// Round 10
// 877.788 us; speedup vs baseline: 6.0996x; 1.0569x over previous
//
#include <hip/hip_runtime.h>
#include <cstdint>
#include <cstddef>

static constexpr int HD = 200;   // hidden
static constexpr int NH = 8;     // heads
static constexpr int CD = 25;    // per-head dim
static constexpr int NL = 4;     // layers

typedef unsigned int u32;
typedef unsigned int u32x4 __attribute__((ext_vector_type(4)));
typedef float f32x4 __attribute__((ext_vector_type(4)));
typedef __bf16 bf16x8 __attribute__((ext_vector_type(8)));

union U8cast { u32x4 u; bf16x8 b; };
__device__ inline bf16x8 as_bf16x8(u32x4 v) { U8cast x; x.u = v; return x.b; }

// truncation split: a = hi + lo + eps, |eps| <= 2^-16 |a|; packs 2 elems per u32.
__device__ inline void split2(float a0, float a1, u32& hi, u32& lo) {
  u32 u0 = __builtin_bit_cast(u32, a0), u1 = __builtin_bit_cast(u32, a1);
  u32 h0 = u0 & 0xffff0000u, h1 = u1 & 0xffff0000u;
  hi = (u0 >> 16) | h1;
  float r0 = a0 - __builtin_bit_cast(float, h0);
  float r1 = a1 - __builtin_bit_cast(float, h1);
  lo = (__builtin_bit_cast(u32, r0) >> 16) | (__builtin_bit_cast(u32, r1) & 0xffff0000u);
}

__device__ inline void mk_frags_r(f32x4 x0, f32x4 x1, bf16x8& hi8, bf16x8& lo8) {
  u32x4 h, l;
  u32 th, tl;
  split2(x0[0], x0[1], th, tl); h[0] = th; l[0] = tl;
  split2(x0[2], x0[3], th, tl); h[1] = th; l[1] = tl;
  split2(x1[0], x1[1], th, tl); h[2] = th; l[2] = tl;
  split2(x1[2], x1[3], th, tl); h[3] = th; l[3] = tl;
  hi8 = as_bf16x8(h); lo8 = as_bf16x8(l);
}

__device__ inline void mk_frags(const float* __restrict__ ap, bf16x8& hi8, bf16x8& lo8) {
  mk_frags_r(*(const f32x4*)ap, *(const f32x4*)(ap + 4), hi8, lo8);
}

// ---------------- CSR build ----------------
__global__ __launch_bounds__(256) void k_hist(const int* __restrict__ dst, int* __restrict__ cnt, int E) {
  int e = blockIdx.x * 256 + threadIdx.x;
  if (e < E) atomicAdd(&cnt[dst[e]], 1);
}

__global__ __launch_bounds__(256) void k_scan1(const int* __restrict__ cnt, int* __restrict__ off,
                                               int* __restrict__ partial, int N) {
  __shared__ int sm[256];
  int t = threadIdx.x, i = blockIdx.x * 256 + t;
  int v = (i < N) ? cnt[i] : 0;
  sm[t] = v; __syncthreads();
  for (int o = 1; o < 256; o <<= 1) {
    int add = (t >= o) ? sm[t - o] : 0;
    __syncthreads();
    sm[t] += add;
    __syncthreads();
  }
  if (i < N) off[i] = sm[t] - v;
  if (t == 255) partial[blockIdx.x] = sm[255];
}

__global__ __launch_bounds__(512) void k_scan2(int* __restrict__ partial, int nb, int* __restrict__ off, int N) {
  __shared__ int sm[512];
  int t = threadIdx.x;
  int v = (t < nb) ? partial[t] : 0;
  sm[t] = v; __syncthreads();
  for (int o = 1; o < 512; o <<= 1) {
    int add = (t >= o) ? sm[t - o] : 0;
    __syncthreads();
    sm[t] += add;
    __syncthreads();
  }
  if (t < nb) partial[t] = sm[t] - v;
  if (t == 511) off[N] = sm[511];
}

__global__ __launch_bounds__(256) void k_scan3(int* __restrict__ off, const int* __restrict__ partial, int N) {
  int i = blockIdx.x * 256 + threadIdx.x;
  if (i < N) off[i] += partial[i >> 8];
}

__global__ __launch_bounds__(256) void k_scatter(const int* __restrict__ dst, const int* __restrict__ off,
                                                 int* __restrict__ cur, int* __restrict__ eid, int E) {
  int e = blockIdx.x * 256 + threadIdx.x;
  if (e < E) {
    int d = dst[e];
    int p = atomicAdd(&cur[d], 1);
    eid[off[d] + p] = e;
  }
}

__global__ __launch_bounds__(256) void k_sort(const int* __restrict__ off, int* __restrict__ eid, int N) {
  int n = blockIdx.x * 256 + threadIdx.x;
  if (n >= N) return;
  int o0 = off[n], o1 = off[n + 1];
  for (int i = o0 + 1; i < o1; ++i) {
    int v = eid[i]; int j = i - 1;
    while (j >= o0 && eid[j] > v) { eid[j + 1] = eid[j]; --j; }
    eid[j + 1] = v;
  }
}

// ---------------- edge-attention precompute (algebraic reductions) ----------------
__global__ __launch_bounds__(128) void k_meanea(const float* __restrict__ ea, const int* __restrict__ off,
                                                const int* __restrict__ eid, float* __restrict__ mea, int N) {
  int n = blockIdx.x * 128 + threadIdx.x;
  if (n >= N) return;
  int o0 = off[n], o1 = off[n + 1];
  float s0 = 0, s1 = 0, s2 = 0, s3 = 0, s4 = 0, s5 = 0;
  for (int p = o0; p < o1; ++p) {
    const float* r = ea + (size_t)eid[p] * 6;
    s0 += r[0]; s1 += r[1]; s2 += r[2]; s3 += r[3]; s4 += r[4]; s5 += r[5];
  }
  float inv = (o1 > o0) ? 1.f / (float)(o1 - o0) : 0.f;
  float* m = mea + (size_t)n * 6;
  m[0] = s0 * inv; m[1] = s1 * inv; m[2] = s2 * inv; m[3] = s3 * inv; m[4] = s4 * inv; m[5] = s5 * inv;
}

// we[l][k][h]   = sum_c lin_edge_w[l][k][h*25+c] * att_edge[l][h][c]
// wsrc[l][k][h] = sum_c lin_w[l][k][h*25+c]      * att_src[l][h][c]
// wdst[l][k][h] = sum_c lin_w[l][k][h*25+c]      * att_dst[l][h][c]
__global__ __launch_bounds__(256) void k_we2(const float* __restrict__ lew, const float* __restrict__ linw,
                                             const float* __restrict__ aeg, const float* __restrict__ asg,
                                             const float* __restrict__ adg, float* __restrict__ we,
                                             float* __restrict__ wsrc, float* __restrict__ wdst) {
  int tid = blockIdx.x * 256 + threadIdx.x;
  if (tid >= NL * HD * 8) return;
  int l = tid / (HD * 8); int r = tid % (HD * 8); int k = r >> 3; int hh = r & 7;
  const float* We = lew + (size_t)l * HD * HD + (size_t)k * HD + hh * CD;
  const float* Wl = linw + (size_t)l * HD * HD + (size_t)k * HD + hh * CD;
  const float* ae = aeg + l * NH * CD + hh * CD;
  const float* as = asg + l * NH * CD + hh * CD;
  const float* ad = adg + l * NH * CD + hh * CD;
  float s0 = 0.f, s1 = 0.f, s2 = 0.f;
#pragma unroll
  for (int c = 0; c < CD; ++c) {
    float we_ = We[c], wl_ = Wl[c];
    s0 += we_ * ae[c]; s1 += wl_ * as[c]; s2 += wl_ * ad[c];
  }
  we[tid] = s0; wsrc[tid] = s1; wdst[tid] = s2;   // layout l*1600 + k*8 + h
}

// M[l][f][h] = sum_k edge_emb_w[f][k] * we[l][k][h];  cv[l][h] = sum_k edge_emb_b[k]*we[l][k][h]
__global__ __launch_bounds__(256) void k_M(const float* __restrict__ ew, const float* __restrict__ eb,
                                           const float* __restrict__ we, float* __restrict__ Mm,
                                           float* __restrict__ cv) {
  int tid = threadIdx.x;
  if (tid < NL * 6 * 8) {
    int l = tid / 48, r = tid % 48, f = r / 8, hh = r % 8;
    float s = 0.f;
    for (int k = 0; k < HD; ++k) s += ew[f * HD + k] * we[l * 1600 + k * 8 + hh];
    Mm[tid] = s;   // l*48 + f*8 + hh
  } else if (tid < NL * 6 * 8 + NL * 8) {
    int u = tid - NL * 6 * 8, l = u / 8, hh = u % 8;
    float s = 0.f;
    for (int k = 0; k < HD; ++k) s += eb[k] * we[l * 1600 + k * 8 + hh];
    cv[u] = s;
  }
}

// self-loop attention logit contribution ae_s for all layers
__global__ __launch_bounds__(256) void k_ae_self(const float* __restrict__ mea, const int* __restrict__ cnt,
                                                 const float* __restrict__ Mm, const float* __restrict__ cv,
                                                 float* __restrict__ aes, int N) {
  int n = blockIdx.x * 256 + threadIdx.x;
  if (n >= N) return;
  bool has = cnt[n] > 0;
  float v[6];
#pragma unroll
  for (int f = 0; f < 6; ++f) v[f] = mea[(size_t)n * 6 + f];
  for (int l = 0; l < NL; ++l)
#pragma unroll
    for (int hh = 0; hh < 8; ++hh) {
      float s = 0.f;
      if (has) {
        s = cv[l * 8 + hh];
#pragma unroll
        for (int f = 0; f < 6; ++f) s += v[f] * Mm[l * 48 + f * 8 + hh];
      }
      aes[(size_t)l * N * 8 + (size_t)n * 8 + hh] = s;
    }
}

// one-time: CSR-ordered src index + all-layer layer-invariant edge logit part
// aep[l][p][h] = cv[l][h] + sum_f edge_attr[eid[p]][f] * Mm[l][f][h]
__global__ __launch_bounds__(256) void k_aep(const float* __restrict__ ea, const int* __restrict__ eid,
                                             const int* __restrict__ esrc, const float* __restrict__ Mm,
                                             const float* __restrict__ cv, int* __restrict__ src_csr,
                                             float* __restrict__ aep, int E) {
  int p = blockIdx.x * 256 + threadIdx.x;
  if (p >= E) return;
  int e = eid[p];
  src_csr[p] = esrc[e];
  float v[6];
  const float* er = ea + (size_t)e * 6;
#pragma unroll
  for (int f = 0; f < 6; ++f) v[f] = er[f];
#pragma unroll
  for (int l = 0; l < NL; ++l) {
#pragma unroll
    for (int hh = 0; hh < 8; ++hh) {
      float s = cv[l * 8 + hh];
#pragma unroll
      for (int f = 0; f < 6; ++f) s += v[f] * Mm[l * 48 + f * 8 + hh];
      aep[(size_t)l * E * 8 + (size_t)p * 8 + hh] = s;
    }
  }
}

// ---------------- weight split v5: LDS-image layout ----------------
__global__ __launch_bounds__(256) void k_split5(const float* __restrict__ W, u32* __restrict__ out,
                                                int K, int nsteps, int inStride,
                                                const float* __restrict__ wsrc,
                                                const float* __restrict__ wdst) {
  int l = blockIdx.y;
  int tot = nsteps * 7168;
  int idx = blockIdx.x * 256 + threadIdx.x;
  if (idx >= tot) return;
  int ks = idx / 7168, r = idx % 7168;
  int plane = r / 3584, r2 = r % 3584;
  int g = r2 >> 2, j = r2 & 3;
  int c = g >> 2, kg = g & 3;
  int k = ks * 32 + kg * 8 + j * 2;
  float a0 = 0.f, a1 = 0.f;
  if (c < HD) {
    if (k < K) {
      const float* Wl = W + (size_t)l * inStride;
      a0 = Wl[(size_t)k * HD + c];
      a1 = Wl[(size_t)(k + 1) * HD + c];
    }
  } else if (wsrc && c < 216 && k < K) {
    const float* src = ((c < 208) ? wsrc : wdst) + (size_t)l * 1600;
    int hh = (c - 200) & 7;
    a0 = src[k * 8 + hh];
    a1 = src[(k + 1) * 8 + hh];
  }
  u32 hi, lo; split2(a0, a1, hi, lo);
  out[(size_t)l * tot + idx] = (plane == 0) ? hi : lo;
}

// merged readout split: readout_w [4][200][200] -> LDS-image [25 ks][7168 u32], K global 0..799
__global__ __launch_bounds__(256) void k_split_ro5(const float* __restrict__ W, u32* __restrict__ out) {
  int idx = blockIdx.x * 256 + threadIdx.x;
  if (idx >= 25 * 7168) return;
  int ks = idx / 7168, r = idx % 7168;
  int plane = r / 3584, r2 = r % 3584;
  int g = r2 >> 2, j = r2 & 3;
  int c = g >> 2, kg = g & 3;
  int k = ks * 32 + kg * 8 + j * 2;
  float a0 = 0.f, a1 = 0.f;
  if (c < HD) {
    int lsrc = k / HD, kl = k % HD;
    const float* Wl = W + (size_t)lsrc * HD * HD;
    a0 = Wl[(size_t)kl * HD + c];
    a1 = Wl[(size_t)(kl + 1) * HD + c];
  }
  u32 hi, lo; split2(a0, a1, hi, lo);
  out[idx] = (plane == 0) ? hi : lo;
}

// summed readout bias
__global__ __launch_bounds__(256) void k_bsum(const float* __restrict__ rb, float* __restrict__ out) {
  int t = threadIdx.x;
  if (t < HD) out[t] = rb[t] + rb[HD + t] + rb[2 * HD + t] + rb[3 * HD + t];
}

// head W1 split: head_w1 [5][200][100] -> planes [t][112 cols][224 k] bf16
__global__ __launch_bounds__(256) void k_split_hw(const float* __restrict__ W, u32* __restrict__ hiT,
                                                  u32* __restrict__ loT) {
  int t = blockIdx.y;
  int idx = blockIdx.x * 256 + threadIdx.x;
  if (idx >= 112 * 112) return;
  int c = idx / 112, kp = (idx % 112) * 2;
  const float* Wt = W + (size_t)t * HD * 100;
  float a0 = (c < 100 && kp < HD) ? Wt[(size_t)kp * 100 + c] : 0.f;
  float a1 = (c < 100 && kp + 1 < HD) ? Wt[(size_t)(kp + 1) * 100 + c] : 0.f;
  u32 hi, lo; split2(a0, a1, hi, lo);
  size_t ob = (size_t)t * 112 * 112 + idx;
  hiT[ob] = hi; loT[ob] = lo;
}

// ---------------- MFMA GEMM v5 (split-bf16, B double-buffered in LDS via global_load_lds) ----
template<int NSTEPS, bool ATTN>
__global__ __launch_bounds__(256) void k_gemm_v5(const float* __restrict__ A, const u32* __restrict__ Bpk,
                                                 const float* __restrict__ bias, float* __restrict__ C,
                                                 float* __restrict__ aS, float* __restrict__ aD,
                                                 int M, int K) {
  constexpr int NT = 7;
  __shared__ u32 smem[2 * 7168];
  const int tid = threadIdx.x;
  const int lane = tid & 63;
  const int w = tid >> 6;
  const int wm = w >> 1, wn = w & 1;
  const int lr = lane & 15, kg = lane >> 4;
  const int kg8 = kg * 8;

  const int rowA0 = blockIdx.x * 64 + wm * 32 + lr;
  const int rowA1 = rowA0 + 16;
  const float* Ap0 = A + (size_t)((rowA0 < M) ? rowA0 : (M - 1)) * K;
  const float* Ap1 = A + (size_t)((rowA1 < M) ? rowA1 : (M - 1)) * K;
  const int colbase = wn * 112;
  const int dsbase = (colbase + lr) * 16 + kg * 4;

  f32x4 acc[2][NT];
#pragma unroll
  for (int mt = 0; mt < 2; ++mt)
#pragma unroll
    for (int t = 0; t < NT; ++t) acc[mt][t] = (f32x4)0.f;

#pragma unroll
  for (int i = 0; i < 7; ++i) {
    const int chunk = i * 4 + w;
    __builtin_amdgcn_global_load_lds((const void*)(Bpk + chunk * 256 + lane * 4),
                                     (void*)(smem + chunk * 256), 16, 0, 0);
  }
  f32x4 a0c, a0d, a1c, a1d;
  a0c = *(const f32x4*)(Ap0 + kg8); a0d = *(const f32x4*)(Ap0 + kg8 + 4);
  a1c = *(const f32x4*)(Ap1 + kg8); a1d = *(const f32x4*)(Ap1 + kg8 + 4);
  __syncthreads();

  int cur = 0;
  for (int ks = 0; ks < NSTEPS; ++ks) {
    const bool more = (ks + 1) < NSTEPS;
    if (more) {
      const u32* src = Bpk + (size_t)(ks + 1) * 7168;
      u32* dst = smem + (cur ^ 1) * 7168;
#pragma unroll
      for (int i = 0; i < 7; ++i) {
        const int chunk = i * 4 + w;
        __builtin_amdgcn_global_load_lds((const void*)(src + chunk * 256 + lane * 4),
                                         (void*)(dst + chunk * 256), 16, 0, 0);
      }
    }
    bf16x8 ah0, al0, ah1, al1;
    {
      const int k0 = ks * 32 + kg8;
      if (k0 < K) {
        mk_frags_r(a0c, a0d, ah0, al0);
        mk_frags_r(a1c, a1d, ah1, al1);
      } else {
        u32x4 zz; zz[0] = 0; zz[1] = 0; zz[2] = 0; zz[3] = 0;
        ah0 = as_bf16x8(zz); al0 = ah0; ah1 = ah0; al1 = ah0;
      }
    }
    if (more) {
      const int k0n = (ks + 1) * 32 + kg8;
      if (k0n < K) {
        a0c = *(const f32x4*)(Ap0 + k0n); a0d = *(const f32x4*)(Ap0 + k0n + 4);
        a1c = *(const f32x4*)(Ap1 + k0n); a1d = *(const f32x4*)(Ap1 + k0n + 4);
      }
    }
    const u32* bb = smem + cur * 7168;
#pragma unroll
    for (int t = 0; t < NT; ++t) {
      bf16x8 bh = as_bf16x8(*(const u32x4*)(bb + dsbase + t * 256));
      bf16x8 bl = as_bf16x8(*(const u32x4*)(bb + 3584 + dsbase + t * 256));
      acc[0][t] = __builtin_amdgcn_mfma_f32_16x16x32_bf16(ah0, bh, acc[0][t], 0, 0, 0);
      acc[0][t] = __builtin_amdgcn_mfma_f32_16x16x32_bf16(ah0, bl, acc[0][t], 0, 0, 0);
      acc[0][t] = __builtin_amdgcn_mfma_f32_16x16x32_bf16(al0, bh, acc[0][t], 0, 0, 0);
      acc[1][t] = __builtin_amdgcn_mfma_f32_16x16x32_bf16(ah1, bh, acc[1][t], 0, 0, 0);
      acc[1][t] = __builtin_amdgcn_mfma_f32_16x16x32_bf16(ah1, bl, acc[1][t], 0, 0, 0);
      acc[1][t] = __builtin_amdgcn_mfma_f32_16x16x32_bf16(al1, bh, acc[1][t], 0, 0, 0);
    }
    __syncthreads();
    cur ^= 1;
  }

#pragma unroll
  for (int mt = 0; mt < 2; ++mt) {
    const int rbase = blockIdx.x * 64 + wm * 32 + mt * 16 + kg * 4;
#pragma unroll
    for (int t = 0; t < NT; ++t) {
      const int c = colbase + t * 16 + lr;
      if (c < HD) {
        const float badd = bias ? bias[c] : 0.f;
#pragma unroll
        for (int j = 0; j < 4; ++j) {
          const int r = rbase + j;
          if (r < M) C[(size_t)r * HD + c] = acc[mt][t][j] + badd;
        }
      } else if (ATTN && c < 216) {
        float* dstp = (c < 208) ? aS : aD;
        const int hh = (c - 200) & 7;
#pragma unroll
        for (int j = 0; j < 4; ++j) {
          const int r = rbase + j;
          if (r < M) dstp[(size_t)r * 8 + hh] = acc[mt][t][j];
        }
      }
    }
  }
}

// ---------------- head GEMM: z[t] = relu(readouts @ W1[t] + b1[t]), z [5][G][112] ----------------
__global__ __launch_bounds__(128) void k_headgemm(const float* __restrict__ A, const u32* __restrict__ hwHi,
                                                  const u32* __restrict__ hwLo, const float* __restrict__ b1,
                                                  float* __restrict__ z, int M) {
  const int task = blockIdx.y;
  const int lane = threadIdx.x & 63;
  const int w = threadIdx.x >> 6;
  const int lr = lane & 15, kg = lane >> 4;
  const int K = HD;
  const int nStep = 7;
  const int bstride = 112;

  const int rowA0 = blockIdx.x * 64 + w * 32 + lr;
  const int rowA1 = rowA0 + 16;
  const float* Ap0 = A + (size_t)((rowA0 < M) ? rowA0 : (M - 1)) * K;
  const float* Ap1 = A + (size_t)((rowA1 < M) ? rowA1 : (M - 1)) * K;
  const u32* BhT = hwHi + (size_t)task * 112 * 112;
  const u32* BlT = hwLo + (size_t)task * 112 * 112;

  f32x4 acc[2][7];
#pragma unroll
  for (int mt = 0; mt < 2; ++mt)
#pragma unroll
    for (int t = 0; t < 7; ++t) acc[mt][t] = (f32x4)0.f;

  u32x4 zz; zz[0] = 0; zz[1] = 0; zz[2] = 0; zz[3] = 0;
  const bf16x8 zfrag = as_bf16x8(zz);

  for (int ks = 0; ks < nStep; ++ks) {
    const int kb = ks * 32;
    const int k0 = kb + kg * 8;
    bf16x8 ah0, al0, ah1, al1;
    if (k0 < K) {
      mk_frags(Ap0 + k0, ah0, al0);
      mk_frags(Ap1 + k0, ah1, al1);
    } else {
      ah0 = zfrag; al0 = zfrag; ah1 = zfrag; al1 = zfrag;
    }
    const u32* Bh = BhT + (kb >> 1) + kg * 4;
    const u32* Bl = BlT + (kb >> 1) + kg * 4;
#pragma unroll
    for (int t = 0; t < 7; ++t) {
      const size_t cb = (size_t)(t * 16 + lr) * bstride;
      bf16x8 bh = as_bf16x8(*(const u32x4*)(Bh + cb));
      bf16x8 bl = as_bf16x8(*(const u32x4*)(Bl + cb));
      acc[0][t] = __builtin_amdgcn_mfma_f32_16x16x32_bf16(ah0, bh, acc[0][t], 0, 0, 0);
      acc[0][t] = __builtin_amdgcn_mfma_f32_16x16x32_bf16(ah0, bl, acc[0][t], 0, 0, 0);
      acc[0][t] = __builtin_amdgcn_mfma_f32_16x16x32_bf16(al0, bh, acc[0][t], 0, 0, 0);
      acc[1][t] = __builtin_amdgcn_mfma_f32_16x16x32_bf16(ah1, bh, acc[1][t], 0, 0, 0);
      acc[1][t] = __builtin_amdgcn_mfma_f32_16x16x32_bf16(ah1, bl, acc[1][t], 0, 0, 0);
      acc[1][t] = __builtin_amdgcn_mfma_f32_16x16x32_bf16(al1, bh, acc[1][t], 0, 0, 0);
    }
  }

#pragma unroll
  for (int mt = 0; mt < 2; ++mt) {
    const int rbase = blockIdx.x * 64 + w * 32 + mt * 16 + kg * 4;
#pragma unroll
    for (int t = 0; t < 7; ++t) {
      const int c = t * 16 + lr;
      if (c < 100) {
        const float badd = b1[task * 100 + c];
#pragma unroll
        for (int j = 0; j < 4; ++j) {
          const int r = rbase + j;
          if (r < M) {
            float v = acc[mt][t][j] + badd;
            z[((size_t)task * M + r) * 112 + c] = v > 0.f ? v : 0.f;
          }
        }
      }
    }
  }
}

__global__ __launch_bounds__(256) void k_heads2(const float* __restrict__ z, const float* __restrict__ w2,
                                                const float* __restrict__ b2, float* __restrict__ out, int G) {
  int lane = threadIdx.x & 63;
  int idx = blockIdx.x * 4 + (threadIdx.x >> 6);
  if (idx >= 5 * G) return;
  int t = idx / G, g = idx % G;
  const float* zr = z + ((size_t)t * G + g) * 112;
  float p = 0.f;
  if (lane < 100) p += zr[lane] * w2[t * 100 + lane];
  if (lane < 36)  p += zr[lane + 64] * w2[t * 100 + 64 + lane];
  for (int o = 32; o >= 1; o >>= 1) p += __shfl_down(p, o);
  if (lane == 0) {
    float zv = p + b2[t];
    bool sig = (t == 0) | (t == 3) | (t == 4);
    out[idx] = sig ? 1.f / (1.f + expf(-zv)) : zv;
  }
}

// ---------------- aggregation v3: inline logits, register fast path for deg<=8 ----------------
__global__ __launch_bounds__(256) void k_aggr3(const float* __restrict__ xs, const float* __restrict__ a_src,
                                               const float* __restrict__ a_dst, const float* __restrict__ aep,
                                               const float* __restrict__ aes, const float* __restrict__ gb,
                                               const int* __restrict__ off, const int* __restrict__ src_csr,
                                               float* __restrict__ h_out, int N) {
  int lane = threadIdx.x & 63;
  int node = blockIdx.x * 4 + (threadIdx.x >> 6);
  if (node >= N) return;
  const int h = lane & 7, q = lane >> 3;
  const int o0 = off[node], o1 = off[node + 1];
  const int hh0 = lane / 25, hh1 = (lane + 64) / 25, hh2 = (lane + 128) / 25, hh3 = (lane + 192) / 25;

  const float adst_h = a_dst[(size_t)node * 8 + h];

  float lself = 0.f;
  if (lane < 8) {
    float v = a_src[(size_t)node * 8 + lane] + a_dst[(size_t)node * 8 + lane] + aes[(size_t)node * 8 + lane];
    lself = (v >= 0.f) ? v : 0.2f * v;
  }

  // chunk 0 logits in registers (covers deg <= 8, the common case)
  const int p0i = o0 + q;
  const bool v0 = p0i < o1;
  int s0 = 0; float lg0 = -1e30f;
  if (v0) {
    s0 = src_csr[p0i];
    float av = a_src[(size_t)s0 * 8 + h] + adst_h + aep[(size_t)p0i * 8 + h];
    lg0 = (av >= 0.f) ? av : 0.2f * av;
  }
  float mx = lg0;
  for (int pb = o0 + 8; pb < o1; pb += 8) {        // rare: deg > 8
    int p = pb + q;
    if (p < o1) {
      int s = src_csr[p];
      float av = a_src[(size_t)s * 8 + h] + adst_h + aep[(size_t)p * 8 + h];
      av = (av >= 0.f) ? av : 0.2f * av;
      mx = fmaxf(mx, av);
    }
  }
  mx = fmaxf(mx, __shfl_xor(mx, 8));
  mx = fmaxf(mx, __shfl_xor(mx, 16));
  mx = fmaxf(mx, __shfl_xor(mx, 32));
  mx = fmaxf(mx, __shfl(lself, h));

  float acc0 = 0.f, acc1 = 0.f, acc2 = 0.f, acc3 = 0.f, wsum = 0.f;
  // chunk 0 from registers
  {
    float w = v0 ? expf(lg0 - mx) : 0.f;
    wsum += w;
    int cnt = o1 - o0; if (cnt > 8) cnt = 8;
    for (int j = 0; j < cnt; ++j) {
      float wa = __shfl(w, j * 8 + hh0);
      float wb = __shfl(w, j * 8 + hh1);
      float wc = __shfl(w, j * 8 + hh2);
      float wd = __shfl(w, j * 8 + hh3);
      int sj = __shfl(s0, j * 8);
      const float* xr = xs + (size_t)sj * HD;
      acc0 += wa * xr[lane];
      acc1 += wb * xr[lane + 64];
      acc2 += wc * xr[lane + 128];
      if (lane < 8) acc3 += wd * xr[lane + 192];
    }
  }
  // remaining chunks (rare): recompute logits
  for (int pb = o0 + 8; pb < o1; pb += 8) {
    int p = pb + q;
    bool valid = p < o1;
    float w = 0.f; int s = 0;
    if (valid) {
      s = src_csr[p];
      float av = a_src[(size_t)s * 8 + h] + adst_h + aep[(size_t)p * 8 + h];
      av = (av >= 0.f) ? av : 0.2f * av;
      w = expf(av - mx);
    }
    wsum += w;
    int cnt = o1 - pb; if (cnt > 8) cnt = 8;
    for (int j = 0; j < cnt; ++j) {
      float wa = __shfl(w, j * 8 + hh0);
      float wb = __shfl(w, j * 8 + hh1);
      float wc = __shfl(w, j * 8 + hh2);
      float wd = __shfl(w, j * 8 + hh3);
      int sj = __shfl(s, j * 8);
      const float* xr = xs + (size_t)sj * HD;
      acc0 += wa * xr[lane];
      acc1 += wb * xr[lane + 64];
      acc2 += wc * xr[lane + 128];
      if (lane < 8) acc3 += wd * xr[lane + 192];
    }
  }
  wsum += __shfl_xor(wsum, 8);
  wsum += __shfl_xor(wsum, 16);
  wsum += __shfl_xor(wsum, 32);

  // self contribution last (reference concat order)
  float wself = (lane < 8) ? expf(lself - mx) : 0.f;
  {
    float wa = __shfl(wself, hh0), wb = __shfl(wself, hh1);
    float wc = __shfl(wself, hh2), wd = __shfl(wself, hh3);
    const float* xr = xs + (size_t)node * HD;
    acc0 += wa * xr[lane];
    acc1 += wb * xr[lane + 64];
    acc2 += wc * xr[lane + 128];
    if (lane < 8) acc3 += wd * xr[lane + 192];
    wsum += __shfl(wself, h);
  }

  float sa = __shfl(wsum, hh0) + 1e-16f, sb = __shfl(wsum, hh1) + 1e-16f;
  float sc = __shfl(wsum, hh2) + 1e-16f, sd = __shfl(wsum, hh3) + 1e-16f;
  float* ho = h_out + (size_t)node * HD;
  ho[lane]       = acc0 / sa + gb[lane];
  ho[lane + 64]  = acc1 / sb + gb[lane + 64];
  ho[lane + 128] = acc2 / sc + gb[lane + 128];
  if (lane < 8) ho[lane + 192] = acc3 / sd + gb[lane + 192];
}

__global__ __launch_bounds__(256) void k_gstart(const int* __restrict__ batch, int* __restrict__ gstart,
                                                int N, int G) {
  int i = blockIdx.x * 256 + threadIdx.x;
  if (i >= N) return;
  int b = batch[i];
  int pb = (i == 0) ? -1 : batch[i - 1];
  for (int g = pb + 1; g <= b; ++g) gstart[g] = i;
  if (i == N - 1) for (int g = b + 1; g <= G; ++g) gstart[g] = N;
}

// pool into pooled4[g][coff + c] with leading dim ld
__global__ __launch_bounds__(256) void k_pool(const float* __restrict__ h, const int* __restrict__ gstart,
                                              float* __restrict__ pooled, int G, int ld, int coff) {
  int g = blockIdx.x, c = threadIdx.x;
  if (c >= HD) return;
  int s0 = gstart[g], s1 = gstart[g + 1];
  float acc = 0.f;
  for (int i = s0; i < s1; ++i) acc += h[(size_t)i * HD + c];
  pooled[(size_t)g * ld + coff + c] = acc;
}

extern "C" void kernel_launch(void* const* d_in, const int* in_sizes, int n_in,
                              void* d_out, int out_size, void* d_ws, size_t ws_size,
                              hipStream_t stream) {
  const float* x         = (const float*)d_in[0];
  const float* edge_attr = (const float*)d_in[1];
  const float* node_w    = (const float*)d_in[2];
  const float* node_b    = (const float*)d_in[3];
  const float* edge_w    = (const float*)d_in[4];
  const float* edge_b    = (const float*)d_in[5];
  const float* lin_w     = (const float*)d_in[6];
  const float* lin_edge_w= (const float*)d_in[7];
  const float* att_src   = (const float*)d_in[8];
  const float* att_dst   = (const float*)d_in[9];
  const float* att_edge  = (const float*)d_in[10];
  const float* gat_bias  = (const float*)d_in[11];
  const float* readout_w = (const float*)d_in[12];
  const float* readout_b = (const float*)d_in[13];
  const float* head_w1   = (const float*)d_in[14];
  const float* head_b1   = (const float*)d_in[15];
  const float* head_w2   = (const float*)d_in[16];
  const float* head_b2   = (const float*)d_in[17];
  const int*   edge_index= (const int*)d_in[18];
  const int*   batch     = (const int*)d_in[19];

  const int N = in_sizes[0] / 64;
  const int E = in_sizes[1] / 6;
  const int G = out_size / 5;
  const int* srcI = edge_index;
  const int* dstI = edge_index + E;

  char* wsb = (char*)d_ws;
  size_t o = 0;
  auto alloc = [&](size_t bytes) -> void* {
    void* p = wsb + o;
    o = (o + bytes + 255) & ~(size_t)255;
    return p;
  };
  float* h       = (float*)alloc((size_t)N * HD * 4);
  float* xs      = (float*)alloc((size_t)N * HD * 4);
  float* a_src   = (float*)alloc((size_t)N * 8 * 4);
  float* a_dst   = (float*)alloc((size_t)N * 8 * 4);
  float* aep     = (float*)alloc((size_t)NL * E * 8 * 4);
  int*   src_csr = (int*)alloc((size_t)E * 4);
  float* ae_s    = (float*)alloc((size_t)NL * N * 8 * 4);
  float* mean_ea = (float*)alloc((size_t)N * 6 * 4);
  float* we      = (float*)alloc((size_t)NL * HD * 8 * 4);
  float* wsrc    = (float*)alloc((size_t)NL * HD * 8 * 4);
  float* wdst    = (float*)alloc((size_t)NL * HD * 8 * 4);
  float* Mm      = (float*)alloc((size_t)NL * 6 * 8 * 4);
  float* cv      = (float*)alloc((size_t)NL * 8 * 4);
  int* cnt       = (int*)alloc((size_t)N * 4);
  int* cur       = (int*)alloc((size_t)N * 4);
  int* off       = (int*)alloc((size_t)(N + 1) * 4);
  int* partial   = (int*)alloc(512 * 4);
  int* eid       = (int*)alloc((size_t)E * 4);
  int* gstart    = (int*)alloc((size_t)(G + 1) * 4);
  float* pooled4 = (float*)alloc((size_t)G * 800 * 4);
  float* readouts= (float*)alloc((size_t)G * HD * 4);
  float* bsum    = (float*)alloc(HD * 4);
  // pre-split LDS-image weight buffers (u32 = 2 bf16; 7168 u32 per K-step)
  u32* nodePk    = (u32*)alloc((size_t)2 * 7168 * 4);
  u32* linPk     = (u32*)alloc((size_t)NL * 7 * 7168 * 4);
  u32* roPk      = (u32*)alloc((size_t)25 * 7168 * 4);
  u32* hw_hi     = (u32*)alloc((size_t)5 * 112 * 112 * 4);
  u32* hw_lo     = (u32*)alloc((size_t)5 * 112 * 112 * 4);
  float* zbuf    = (float*)alloc((size_t)5 * G * 112 * 4);
  (void)ws_size; (void)n_in;

  hipMemsetAsync(cnt, 0, (size_t)N * 4, stream);
  hipMemsetAsync(cur, 0, (size_t)N * 4, stream);

  int nb = (N + 255) / 256;
  k_hist<<<(E + 255) / 256, 256, 0, stream>>>(dstI, cnt, E);
  k_scan1<<<nb, 256, 0, stream>>>(cnt, off, partial, N);
  k_scan2<<<1, 512, 0, stream>>>(partial, nb, off, N);
  k_scan3<<<nb, 256, 0, stream>>>(off, partial, N);
  k_scatter<<<(E + 255) / 256, 256, 0, stream>>>(dstI, off, cur, eid, E);
  k_sort<<<nb, 256, 0, stream>>>(off, eid, N);
  k_meanea<<<(N + 127) / 128, 128, 0, stream>>>(edge_attr, off, eid, mean_ea, N);
  k_we2<<<(NL * HD * 8 + 255) / 256, 256, 0, stream>>>(lin_edge_w, lin_w, att_edge, att_src, att_dst,
                                                       we, wsrc, wdst);
  k_M<<<1, 256, 0, stream>>>(edge_w, edge_b, we, Mm, cv);
  k_ae_self<<<(N + 255) / 256, 256, 0, stream>>>(mean_ea, cnt, Mm, cv, ae_s, N);
  k_aep<<<(E + 255) / 256, 256, 0, stream>>>(edge_attr, eid, srcI, Mm, cv, src_csr, aep, E);

  // weight splits
  {
    k_split5<<<dim3((2 * 7168 + 255) / 256, 1), 256, 0, stream>>>(node_w, nodePk, 64, 2, 0,
                                                                  nullptr, nullptr);
    k_split5<<<dim3((7 * 7168 + 255) / 256, NL), 256, 0, stream>>>(lin_w, linPk, HD, 7, HD * HD,
                                                                   wsrc, wdst);
    k_split_ro5<<<(25 * 7168 + 255) / 256, 256, 0, stream>>>(readout_w, roPk);
    k_bsum<<<1, 256, 0, stream>>>(readout_b, bsum);
    dim3 g3((112 * 112 + 255) / 256, 5);
    k_split_hw<<<g3, 256, 0, stream>>>(head_w1, hw_hi, hw_lo);
  }

  const int gemmBlocks = (N + 63) / 64;
  k_gemm_v5<2, false><<<gemmBlocks, 256, 0, stream>>>(x, nodePk, node_b, h, nullptr, nullptr, N, 64);
  k_gstart<<<nb, 256, 0, stream>>>(batch, gstart, N, G);

  for (int l = 0; l < NL; ++l) {
    k_gemm_v5<7, true><<<gemmBlocks, 256, 0, stream>>>(h, linPk + (size_t)l * 7 * 7168,
                                                       nullptr, xs, a_src, a_dst, N, HD);
    k_aggr3<<<(N + 3) / 4, 256, 0, stream>>>(xs, a_src, a_dst, aep + (size_t)l * E * 8,
                                             ae_s + (size_t)l * N * 8, gat_bias + l * HD,
                                             off, src_csr, h, N);
    k_pool<<<G, 256, 0, stream>>>(h, gstart, pooled4, G, 800, l * HD);
  }
  // merged readout: readouts = pooled4 @ roW4 + sum_l b_l   (K = 800)
  k_gemm_v5<25, false><<<(G + 63) / 64, 256, 0, stream>>>(pooled4, roPk, bsum, readouts,
                                                          nullptr, nullptr, G, 800);
  {
    dim3 hg((G + 63) / 64, 5);
    k_headgemm<<<hg, 128, 0, stream>>>(readouts, hw_hi, hw_lo, head_b1, zbuf, G);
  }
  k_heads2<<<(5 * G + 3) / 4, 256, 0, stream>>>(zbuf, head_w2, head_b2, (float*)d_out, G);
}

// Round 11
// 836.048 us; speedup vs baseline: 6.4041x; 1.0499x over previous
//
#include <hip/hip_runtime.h>
#include <cstdint>
#include <cstddef>

static constexpr int HD = 200;   // hidden
static constexpr int NH = 8;     // heads
static constexpr int CD = 25;    // per-head dim
static constexpr int NL = 4;     // layers

typedef unsigned int u32;
typedef unsigned int u32x4 __attribute__((ext_vector_type(4)));
typedef float f32x4 __attribute__((ext_vector_type(4)));
typedef __bf16 bf16x8 __attribute__((ext_vector_type(8)));

union U8cast { u32x4 u; bf16x8 b; };
__device__ inline bf16x8 as_bf16x8(u32x4 v) { U8cast x; x.u = v; return x.b; }

// truncation split: a = hi + lo + eps, |eps| <= 2^-16 |a|; packs 2 elems per u32.
__device__ inline void split2(float a0, float a1, u32& hi, u32& lo) {
  u32 u0 = __builtin_bit_cast(u32, a0), u1 = __builtin_bit_cast(u32, a1);
  u32 h0 = u0 & 0xffff0000u, h1 = u1 & 0xffff0000u;
  hi = (u0 >> 16) | h1;
  float r0 = a0 - __builtin_bit_cast(float, h0);
  float r1 = a1 - __builtin_bit_cast(float, h1);
  lo = (__builtin_bit_cast(u32, r0) >> 16) | (__builtin_bit_cast(u32, r1) & 0xffff0000u);
}

__device__ inline void mk_frags_r(f32x4 x0, f32x4 x1, bf16x8& hi8, bf16x8& lo8) {
  u32x4 h, l;
  u32 th, tl;
  split2(x0[0], x0[1], th, tl); h[0] = th; l[0] = tl;
  split2(x0[2], x0[3], th, tl); h[1] = th; l[1] = tl;
  split2(x1[0], x1[1], th, tl); h[2] = th; l[2] = tl;
  split2(x1[2], x1[3], th, tl); h[3] = th; l[3] = tl;
  hi8 = as_bf16x8(h); lo8 = as_bf16x8(l);
}

__device__ inline void mk_frags(const float* __restrict__ ap, bf16x8& hi8, bf16x8& lo8) {
  mk_frags_r(*(const f32x4*)ap, *(const f32x4*)(ap + 4), hi8, lo8);
}

// ---------------- CSR build ----------------
__global__ __launch_bounds__(256) void k_hist(const int* __restrict__ dst, int* __restrict__ cnt, int E) {
  int e = blockIdx.x * 256 + threadIdx.x;
  if (e < E) atomicAdd(&cnt[dst[e]], 1);
}

__global__ __launch_bounds__(256) void k_scan1(const int* __restrict__ cnt, int* __restrict__ off,
                                               int* __restrict__ partial, int N) {
  __shared__ int sm[256];
  int t = threadIdx.x, i = blockIdx.x * 256 + t;
  int v = (i < N) ? cnt[i] : 0;
  sm[t] = v; __syncthreads();
  for (int o = 1; o < 256; o <<= 1) {
    int add = (t >= o) ? sm[t - o] : 0;
    __syncthreads();
    sm[t] += add;
    __syncthreads();
  }
  if (i < N) off[i] = sm[t] - v;
  if (t == 255) partial[blockIdx.x] = sm[255];
}

__global__ __launch_bounds__(512) void k_scan2(int* __restrict__ partial, int nb, int* __restrict__ off, int N) {
  __shared__ int sm[512];
  int t = threadIdx.x;
  int v = (t < nb) ? partial[t] : 0;
  sm[t] = v; __syncthreads();
  for (int o = 1; o < 512; o <<= 1) {
    int add = (t >= o) ? sm[t - o] : 0;
    __syncthreads();
    sm[t] += add;
    __syncthreads();
  }
  if (t < nb) partial[t] = sm[t] - v;
  if (t == 511) off[N] = sm[511];
}

__global__ __launch_bounds__(256) void k_scan3(int* __restrict__ off, const int* __restrict__ partial, int N) {
  int i = blockIdx.x * 256 + threadIdx.x;
  if (i < N) off[i] += partial[i >> 8];
}

__global__ __launch_bounds__(256) void k_scatter(const int* __restrict__ dst, const int* __restrict__ off,
                                                 int* __restrict__ cur, int* __restrict__ eid, int E) {
  int e = blockIdx.x * 256 + threadIdx.x;
  if (e < E) {
    int d = dst[e];
    int p = atomicAdd(&cur[d], 1);
    eid[off[d] + p] = e;
  }
}

__global__ __launch_bounds__(256) void k_sort(const int* __restrict__ off, int* __restrict__ eid, int N) {
  int n = blockIdx.x * 256 + threadIdx.x;
  if (n >= N) return;
  int o0 = off[n], o1 = off[n + 1];
  for (int i = o0 + 1; i < o1; ++i) {
    int v = eid[i]; int j = i - 1;
    while (j >= o0 && eid[j] > v) { eid[j + 1] = eid[j]; --j; }
    eid[j + 1] = v;
  }
}

// ---------------- edge-attention precompute (algebraic reductions) ----------------
__global__ __launch_bounds__(128) void k_meanea(const float* __restrict__ ea, const int* __restrict__ off,
                                                const int* __restrict__ eid, float* __restrict__ mea, int N) {
  int n = blockIdx.x * 128 + threadIdx.x;
  if (n >= N) return;
  int o0 = off[n], o1 = off[n + 1];
  float s0 = 0, s1 = 0, s2 = 0, s3 = 0, s4 = 0, s5 = 0;
  for (int p = o0; p < o1; ++p) {
    const float* r = ea + (size_t)eid[p] * 6;
    s0 += r[0]; s1 += r[1]; s2 += r[2]; s3 += r[3]; s4 += r[4]; s5 += r[5];
  }
  float inv = (o1 > o0) ? 1.f / (float)(o1 - o0) : 0.f;
  float* m = mea + (size_t)n * 6;
  m[0] = s0 * inv; m[1] = s1 * inv; m[2] = s2 * inv; m[3] = s3 * inv; m[4] = s4 * inv; m[5] = s5 * inv;
}

// we[l][k][h]   = sum_c lin_edge_w[l][k][h*25+c] * att_edge[l][h][c]
// wsrc[l][k][h] = sum_c lin_w[l][k][h*25+c]      * att_src[l][h][c]
// wdst[l][k][h] = sum_c lin_w[l][k][h*25+c]      * att_dst[l][h][c]
__global__ __launch_bounds__(256) void k_we2(const float* __restrict__ lew, const float* __restrict__ linw,
                                             const float* __restrict__ aeg, const float* __restrict__ asg,
                                             const float* __restrict__ adg, float* __restrict__ we,
                                             float* __restrict__ wsrc, float* __restrict__ wdst) {
  int tid = blockIdx.x * 256 + threadIdx.x;
  if (tid >= NL * HD * 8) return;
  int l = tid / (HD * 8); int r = tid % (HD * 8); int k = r >> 3; int hh = r & 7;
  const float* We = lew + (size_t)l * HD * HD + (size_t)k * HD + hh * CD;
  const float* Wl = linw + (size_t)l * HD * HD + (size_t)k * HD + hh * CD;
  const float* ae = aeg + l * NH * CD + hh * CD;
  const float* as = asg + l * NH * CD + hh * CD;
  const float* ad = adg + l * NH * CD + hh * CD;
  float s0 = 0.f, s1 = 0.f, s2 = 0.f;
#pragma unroll
  for (int c = 0; c < CD; ++c) {
    float we_ = We[c], wl_ = Wl[c];
    s0 += we_ * ae[c]; s1 += wl_ * as[c]; s2 += wl_ * ad[c];
  }
  we[tid] = s0; wsrc[tid] = s1; wdst[tid] = s2;   // layout l*1600 + k*8 + h
}

// M[l][f][h] = sum_k edge_emb_w[f][k] * we[l][k][h];  cv[l][h] = sum_k edge_emb_b[k]*we[l][k][h]
__global__ __launch_bounds__(256) void k_M(const float* __restrict__ ew, const float* __restrict__ eb,
                                           const float* __restrict__ we, float* __restrict__ Mm,
                                           float* __restrict__ cv) {
  int tid = threadIdx.x;
  if (tid < NL * 6 * 8) {
    int l = tid / 48, r = tid % 48, f = r / 8, hh = r % 8;
    float s = 0.f;
    for (int k = 0; k < HD; ++k) s += ew[f * HD + k] * we[l * 1600 + k * 8 + hh];
    Mm[tid] = s;   // l*48 + f*8 + hh
  } else if (tid < NL * 6 * 8 + NL * 8) {
    int u = tid - NL * 6 * 8, l = u / 8, hh = u % 8;
    float s = 0.f;
    for (int k = 0; k < HD; ++k) s += eb[k] * we[l * 1600 + k * 8 + hh];
    cv[u] = s;
  }
}

// self-loop attention logit contribution ae_s for all layers
__global__ __launch_bounds__(256) void k_ae_self(const float* __restrict__ mea, const int* __restrict__ cnt,
                                                 const float* __restrict__ Mm, const float* __restrict__ cv,
                                                 float* __restrict__ aes, int N) {
  int n = blockIdx.x * 256 + threadIdx.x;
  if (n >= N) return;
  bool has = cnt[n] > 0;
  float v[6];
#pragma unroll
  for (int f = 0; f < 6; ++f) v[f] = mea[(size_t)n * 6 + f];
  for (int l = 0; l < NL; ++l)
#pragma unroll
    for (int hh = 0; hh < 8; ++hh) {
      float s = 0.f;
      if (has) {
        s = cv[l * 8 + hh];
#pragma unroll
        for (int f = 0; f < 6; ++f) s += v[f] * Mm[l * 48 + f * 8 + hh];
      }
      aes[(size_t)l * N * 8 + (size_t)n * 8 + hh] = s;
    }
}

// one-time: CSR-ordered src index + all-layer layer-invariant edge logit part
__global__ __launch_bounds__(256) void k_aep(const float* __restrict__ ea, const int* __restrict__ eid,
                                             const int* __restrict__ esrc, const float* __restrict__ Mm,
                                             const float* __restrict__ cv, int* __restrict__ src_csr,
                                             float* __restrict__ aep, int E) {
  int p = blockIdx.x * 256 + threadIdx.x;
  if (p >= E) return;
  int e = eid[p];
  src_csr[p] = esrc[e];
  float v[6];
  const float* er = ea + (size_t)e * 6;
#pragma unroll
  for (int f = 0; f < 6; ++f) v[f] = er[f];
#pragma unroll
  for (int l = 0; l < NL; ++l) {
#pragma unroll
    for (int hh = 0; hh < 8; ++hh) {
      float s = cv[l * 8 + hh];
#pragma unroll
      for (int f = 0; f < 6; ++f) s += v[f] * Mm[l * 48 + f * 8 + hh];
      aep[(size_t)l * E * 8 + (size_t)p * 8 + hh] = s;
    }
  }
}

// ---------------- weight split v5: LDS-image layout ----------------
__global__ __launch_bounds__(256) void k_split5(const float* __restrict__ W, u32* __restrict__ out,
                                                int K, int nsteps, int inStride,
                                                const float* __restrict__ wsrc,
                                                const float* __restrict__ wdst) {
  int l = blockIdx.y;
  int tot = nsteps * 7168;
  int idx = blockIdx.x * 256 + threadIdx.x;
  if (idx >= tot) return;
  int ks = idx / 7168, r = idx % 7168;
  int plane = r / 3584, r2 = r % 3584;
  int g = r2 >> 2, j = r2 & 3;
  int c = g >> 2, kg = g & 3;
  int k = ks * 32 + kg * 8 + j * 2;
  float a0 = 0.f, a1 = 0.f;
  if (c < HD) {
    if (k < K) {
      const float* Wl = W + (size_t)l * inStride;
      a0 = Wl[(size_t)k * HD + c];
      a1 = Wl[(size_t)(k + 1) * HD + c];
    }
  } else if (wsrc && c < 216 && k < K) {
    const float* src = ((c < 208) ? wsrc : wdst) + (size_t)l * 1600;
    int hh = (c - 200) & 7;
    a0 = src[k * 8 + hh];
    a1 = src[(k + 1) * 8 + hh];
  }
  u32 hi, lo; split2(a0, a1, hi, lo);
  out[(size_t)l * tot + idx] = (plane == 0) ? hi : lo;
}

// merged readout split: readout_w [4][200][200] -> LDS-image [25 ks][7168 u32], K global 0..799
__global__ __launch_bounds__(256) void k_split_ro5(const float* __restrict__ W, u32* __restrict__ out) {
  int idx = blockIdx.x * 256 + threadIdx.x;
  if (idx >= 25 * 7168) return;
  int ks = idx / 7168, r = idx % 7168;
  int plane = r / 3584, r2 = r % 3584;
  int g = r2 >> 2, j = r2 & 3;
  int c = g >> 2, kg = g & 3;
  int k = ks * 32 + kg * 8 + j * 2;
  float a0 = 0.f, a1 = 0.f;
  if (c < HD) {
    int lsrc = k / HD, kl = k % HD;
    const float* Wl = W + (size_t)lsrc * HD * HD;
    a0 = Wl[(size_t)kl * HD + c];
    a1 = Wl[(size_t)(kl + 1) * HD + c];
  }
  u32 hi, lo; split2(a0, a1, hi, lo);
  out[idx] = (plane == 0) ? hi : lo;
}

// summed readout bias
__global__ __launch_bounds__(256) void k_bsum(const float* __restrict__ rb, float* __restrict__ out) {
  int t = threadIdx.x;
  if (t < HD) out[t] = rb[t] + rb[HD + t] + rb[2 * HD + t] + rb[3 * HD + t];
}

// head W1 split: head_w1 [5][200][100] -> planes [t][112 cols][224 k] bf16
__global__ __launch_bounds__(256) void k_split_hw(const float* __restrict__ W, u32* __restrict__ hiT,
                                                  u32* __restrict__ loT) {
  int t = blockIdx.y;
  int idx = blockIdx.x * 256 + threadIdx.x;
  if (idx >= 112 * 112) return;
  int c = idx / 112, kp = (idx % 112) * 2;
  const float* Wt = W + (size_t)t * HD * 100;
  float a0 = (c < 100 && kp < HD) ? Wt[(size_t)kp * 100 + c] : 0.f;
  float a1 = (c < 100 && kp + 1 < HD) ? Wt[(size_t)(kp + 1) * 100 + c] : 0.f;
  u32 hi, lo; split2(a0, a1, hi, lo);
  size_t ob = (size_t)t * 112 * 112 + idx;
  hiT[ob] = hi; loT[ob] = lo;
}

// ---------------- MFMA GEMM v5 (split-bf16, B double-buffered in LDS via global_load_lds) ----
template<int NSTEPS, bool ATTN>
__global__ __launch_bounds__(256) void k_gemm_v5(const float* __restrict__ A, const u32* __restrict__ Bpk,
                                                 const float* __restrict__ bias, float* __restrict__ C,
                                                 float* __restrict__ aS, float* __restrict__ aD,
                                                 int M, int K) {
  constexpr int NT = 7;
  __shared__ u32 smem[2 * 7168];
  const int tid = threadIdx.x;
  const int lane = tid & 63;
  const int w = tid >> 6;
  const int wm = w >> 1, wn = w & 1;
  const int lr = lane & 15, kg = lane >> 4;
  const int kg8 = kg * 8;

  const int rowA0 = blockIdx.x * 64 + wm * 32 + lr;
  const int rowA1 = rowA0 + 16;
  const float* Ap0 = A + (size_t)((rowA0 < M) ? rowA0 : (M - 1)) * K;
  const float* Ap1 = A + (size_t)((rowA1 < M) ? rowA1 : (M - 1)) * K;
  const int colbase = wn * 112;
  const int dsbase = (colbase + lr) * 16 + kg * 4;

  f32x4 acc[2][NT];
#pragma unroll
  for (int mt = 0; mt < 2; ++mt)
#pragma unroll
    for (int t = 0; t < NT; ++t) acc[mt][t] = (f32x4)0.f;

#pragma unroll
  for (int i = 0; i < 7; ++i) {
    const int chunk = i * 4 + w;
    __builtin_amdgcn_global_load_lds((const void*)(Bpk + chunk * 256 + lane * 4),
                                     (void*)(smem + chunk * 256), 16, 0, 0);
  }
  f32x4 a0c, a0d, a1c, a1d;
  a0c = *(const f32x4*)(Ap0 + kg8); a0d = *(const f32x4*)(Ap0 + kg8 + 4);
  a1c = *(const f32x4*)(Ap1 + kg8); a1d = *(const f32x4*)(Ap1 + kg8 + 4);
  __syncthreads();

  int cur = 0;
  for (int ks = 0; ks < NSTEPS; ++ks) {
    const bool more = (ks + 1) < NSTEPS;
    if (more) {
      const u32* src = Bpk + (size_t)(ks + 1) * 7168;
      u32* dst = smem + (cur ^ 1) * 7168;
#pragma unroll
      for (int i = 0; i < 7; ++i) {
        const int chunk = i * 4 + w;
        __builtin_amdgcn_global_load_lds((const void*)(src + chunk * 256 + lane * 4),
                                         (void*)(dst + chunk * 256), 16, 0, 0);
      }
    }
    bf16x8 ah0, al0, ah1, al1;
    {
      const int k0 = ks * 32 + kg8;
      if (k0 < K) {
        mk_frags_r(a0c, a0d, ah0, al0);
        mk_frags_r(a1c, a1d, ah1, al1);
      } else {
        u32x4 zz; zz[0] = 0; zz[1] = 0; zz[2] = 0; zz[3] = 0;
        ah0 = as_bf16x8(zz); al0 = ah0; ah1 = ah0; al1 = ah0;
      }
    }
    if (more) {
      const int k0n = (ks + 1) * 32 + kg8;
      if (k0n < K) {
        a0c = *(const f32x4*)(Ap0 + k0n); a0d = *(const f32x4*)(Ap0 + k0n + 4);
        a1c = *(const f32x4*)(Ap1 + k0n); a1d = *(const f32x4*)(Ap1 + k0n + 4);
      }
    }
    const u32* bb = smem + cur * 7168;
#pragma unroll
    for (int t = 0; t < NT; ++t) {
      bf16x8 bh = as_bf16x8(*(const u32x4*)(bb + dsbase + t * 256));
      bf16x8 bl = as_bf16x8(*(const u32x4*)(bb + 3584 + dsbase + t * 256));
      acc[0][t] = __builtin_amdgcn_mfma_f32_16x16x32_bf16(ah0, bh, acc[0][t], 0, 0, 0);
      acc[0][t] = __builtin_amdgcn_mfma_f32_16x16x32_bf16(ah0, bl, acc[0][t], 0, 0, 0);
      acc[0][t] = __builtin_amdgcn_mfma_f32_16x16x32_bf16(al0, bh, acc[0][t], 0, 0, 0);
      acc[1][t] = __builtin_amdgcn_mfma_f32_16x16x32_bf16(ah1, bh, acc[1][t], 0, 0, 0);
      acc[1][t] = __builtin_amdgcn_mfma_f32_16x16x32_bf16(ah1, bl, acc[1][t], 0, 0, 0);
      acc[1][t] = __builtin_amdgcn_mfma_f32_16x16x32_bf16(al1, bh, acc[1][t], 0, 0, 0);
    }
    __syncthreads();
    cur ^= 1;
  }

#pragma unroll
  for (int mt = 0; mt < 2; ++mt) {
    const int rbase = blockIdx.x * 64 + wm * 32 + mt * 16 + kg * 4;
#pragma unroll
    for (int t = 0; t < NT; ++t) {
      const int c = colbase + t * 16 + lr;
      if (c < HD) {
        const float badd = bias ? bias[c] : 0.f;
#pragma unroll
        for (int j = 0; j < 4; ++j) {
          const int r = rbase + j;
          if (r < M) C[(size_t)r * HD + c] = acc[mt][t][j] + badd;
        }
      } else if (ATTN && c < 216) {
        float* dstp = (c < 208) ? aS : aD;
        const int hh = (c - 200) & 7;
#pragma unroll
        for (int j = 0; j < 4; ++j) {
          const int r = rbase + j;
          if (r < M) dstp[(size_t)r * 8 + hh] = acc[mt][t][j];
        }
      }
    }
  }
}

// ---------------- head GEMM fused with w2 dot + sigmoid: out[t][g] directly ----------------
__global__ __launch_bounds__(128) void k_headgemm(const float* __restrict__ A, const u32* __restrict__ hwHi,
                                                  const u32* __restrict__ hwLo, const float* __restrict__ b1,
                                                  const float* __restrict__ w2, const float* __restrict__ b2,
                                                  float* __restrict__ out, int M) {
  const int task = blockIdx.y;
  const int lane = threadIdx.x & 63;
  const int w = threadIdx.x >> 6;
  const int lr = lane & 15, kg = lane >> 4;
  const int K = HD;
  const int nStep = 7;
  const int bstride = 112;

  const int rowA0 = blockIdx.x * 64 + w * 32 + lr;
  const int rowA1 = rowA0 + 16;
  const float* Ap0 = A + (size_t)((rowA0 < M) ? rowA0 : (M - 1)) * K;
  const float* Ap1 = A + (size_t)((rowA1 < M) ? rowA1 : (M - 1)) * K;
  const u32* BhT = hwHi + (size_t)task * 112 * 112;
  const u32* BlT = hwLo + (size_t)task * 112 * 112;

  f32x4 acc[2][7];
#pragma unroll
  for (int mt = 0; mt < 2; ++mt)
#pragma unroll
    for (int t = 0; t < 7; ++t) acc[mt][t] = (f32x4)0.f;

  u32x4 zz; zz[0] = 0; zz[1] = 0; zz[2] = 0; zz[3] = 0;
  const bf16x8 zfrag = as_bf16x8(zz);

  for (int ks = 0; ks < nStep; ++ks) {
    const int kb = ks * 32;
    const int k0 = kb + kg * 8;
    bf16x8 ah0, al0, ah1, al1;
    if (k0 < K) {
      mk_frags(Ap0 + k0, ah0, al0);
      mk_frags(Ap1 + k0, ah1, al1);
    } else {
      ah0 = zfrag; al0 = zfrag; ah1 = zfrag; al1 = zfrag;
    }
    const u32* Bh = BhT + (kb >> 1) + kg * 4;
    const u32* Bl = BlT + (kb >> 1) + kg * 4;
#pragma unroll
    for (int t = 0; t < 7; ++t) {
      const size_t cb = (size_t)(t * 16 + lr) * bstride;
      bf16x8 bh = as_bf16x8(*(const u32x4*)(Bh + cb));
      bf16x8 bl = as_bf16x8(*(const u32x4*)(Bl + cb));
      acc[0][t] = __builtin_amdgcn_mfma_f32_16x16x32_bf16(ah0, bh, acc[0][t], 0, 0, 0);
      acc[0][t] = __builtin_amdgcn_mfma_f32_16x16x32_bf16(ah0, bl, acc[0][t], 0, 0, 0);
      acc[0][t] = __builtin_amdgcn_mfma_f32_16x16x32_bf16(al0, bh, acc[0][t], 0, 0, 0);
      acc[1][t] = __builtin_amdgcn_mfma_f32_16x16x32_bf16(ah1, bh, acc[1][t], 0, 0, 0);
      acc[1][t] = __builtin_amdgcn_mfma_f32_16x16x32_bf16(ah1, bl, acc[1][t], 0, 0, 0);
      acc[1][t] = __builtin_amdgcn_mfma_f32_16x16x32_bf16(al1, bh, acc[1][t], 0, 0, 0);
    }
  }

  // fused epilogue: z = relu(acc + b1); part = z . w2 over this lane's 7 cols;
  // 16-lane butterfly sums over lr -> full 100-col dot; lr==0 writes out.
  float w2v[7], b1v[7];
#pragma unroll
  for (int t = 0; t < 7; ++t) {
    const int c = t * 16 + lr;
    w2v[t] = (c < 100) ? w2[task * 100 + c] : 0.f;
    b1v[t] = (c < 100) ? b1[task * 100 + c] : 0.f;
  }
  const bool sig = (task == 0) | (task == 3) | (task == 4);
#pragma unroll
  for (int mt = 0; mt < 2; ++mt) {
    const int rbase = blockIdx.x * 64 + w * 32 + mt * 16 + kg * 4;
#pragma unroll
    for (int j = 0; j < 4; ++j) {
      float part = 0.f;
#pragma unroll
      for (int t = 0; t < 7; ++t) {
        const int c = t * 16 + lr;
        if (c < 100) {
          float v = acc[mt][t][j] + b1v[t];
          v = v > 0.f ? v : 0.f;
          part += v * w2v[t];
        }
      }
      part += __shfl_xor(part, 1);
      part += __shfl_xor(part, 2);
      part += __shfl_xor(part, 4);
      part += __shfl_xor(part, 8);
      const int r = rbase + j;
      if (lr == 0 && r < M) {
        float zv = part + b2[task];
        out[(size_t)task * M + r] = sig ? 1.f / (1.f + expf(-zv)) : zv;
      }
    }
  }
}

// ---------------- aggregation v4: block per graph, fused global_add_pool ----------------
// Wave handles one node at a time (stride 4 within the graph). Lanes 0..49 own 4
// contiguous columns each (f32x4 gather = 1 load per row vs 4). Pool partials in
// registers, 4-wave LDS reduce, one pooled write per graph. writeH=0 skips h store.
__global__ __launch_bounds__(256) void k_aggr4(const float* __restrict__ xs, const float* __restrict__ a_src,
                                               const float* __restrict__ a_dst, const float* __restrict__ aep,
                                               const float* __restrict__ aes, const float* __restrict__ gb,
                                               const int* __restrict__ off, const int* __restrict__ src_csr,
                                               const int* __restrict__ gstart, float* __restrict__ h_out,
                                               float* __restrict__ pooled, int coff, int writeH) {
  __shared__ float red[4][HD];
  const int g = blockIdx.x;
  const int lane = threadIdx.x & 63;
  const int wv = threadIdx.x >> 6;
  const int s0g = gstart[g], s1g = gstart[g + 1];
  const int h = lane & 7, q = lane >> 3;
  const int c0 = lane * 4;                 // cols c0..c0+3 (lanes 0..49)
  const bool val4 = lane < 50;
  const int h0 = val4 ? (c0 / 25) : 0;
  const int h3 = val4 ? ((c0 + 3) / 25) : 0;
  const int bcut = 25 * (h0 + 1) - c0;     // #elems in head h0

  f32x4 pacc = (f32x4)0.f;

  for (int node = s0g + wv; node < s1g; node += 4) {
    const int o0 = off[node], o1 = off[node + 1];
    const float adst_h = a_dst[(size_t)node * 8 + h];
    float lself = 0.f;
    if (lane < 8) {
      float v = a_src[(size_t)node * 8 + lane] + a_dst[(size_t)node * 8 + lane]
              + aes[(size_t)node * 8 + lane];
      lself = (v >= 0.f) ? v : 0.2f * v;
    }
    // chunk 0 logits in registers (deg <= 8 fast path)
    const int p0i = o0 + q;
    const bool v0 = p0i < o1;
    int s0 = 0; float lg0 = -1e30f;
    if (v0) {
      s0 = src_csr[p0i];
      float av = a_src[(size_t)s0 * 8 + h] + adst_h + aep[(size_t)p0i * 8 + h];
      lg0 = (av >= 0.f) ? av : 0.2f * av;
    }
    float mx = lg0;
    for (int pb = o0 + 8; pb < o1; pb += 8) {
      int p = pb + q;
      if (p < o1) {
        int s = src_csr[p];
        float av = a_src[(size_t)s * 8 + h] + adst_h + aep[(size_t)p * 8 + h];
        av = (av >= 0.f) ? av : 0.2f * av;
        mx = fmaxf(mx, av);
      }
    }
    mx = fmaxf(mx, __shfl_xor(mx, 8));
    mx = fmaxf(mx, __shfl_xor(mx, 16));
    mx = fmaxf(mx, __shfl_xor(mx, 32));
    mx = fmaxf(mx, __shfl(lself, h));

    f32x4 acc = (f32x4)0.f;
    float wsum = 0.f;
    // chunk 0
    {
      float wgt = v0 ? expf(lg0 - mx) : 0.f;
      wsum += wgt;
      int cnt = o1 - o0; if (cnt > 8) cnt = 8;
      for (int j = 0; j < cnt; ++j) {
        float wA = __shfl(wgt, j * 8 + h0);
        float wB = __shfl(wgt, j * 8 + h3);
        int sj = __shfl(s0, j * 8);
        if (val4) {
          f32x4 xv = *(const f32x4*)(xs + (size_t)sj * HD + c0);
#pragma unroll
          for (int i = 0; i < 4; ++i)
            acc[i] += ((i < bcut) ? wA : wB) * xv[i];
        }
      }
    }
    // remaining chunks (deg > 8, rare)
    for (int pb = o0 + 8; pb < o1; pb += 8) {
      int p = pb + q;
      bool valid = p < o1;
      float wgt = 0.f; int s = 0;
      if (valid) {
        s = src_csr[p];
        float av = a_src[(size_t)s * 8 + h] + adst_h + aep[(size_t)p * 8 + h];
        av = (av >= 0.f) ? av : 0.2f * av;
        wgt = expf(av - mx);
      }
      wsum += wgt;
      int cnt = o1 - pb; if (cnt > 8) cnt = 8;
      for (int j = 0; j < cnt; ++j) {
        float wA = __shfl(wgt, j * 8 + h0);
        float wB = __shfl(wgt, j * 8 + h3);
        int sj = __shfl(s, j * 8);
        if (val4) {
          f32x4 xv = *(const f32x4*)(xs + (size_t)sj * HD + c0);
#pragma unroll
          for (int i = 0; i < 4; ++i)
            acc[i] += ((i < bcut) ? wA : wB) * xv[i];
        }
      }
    }
    wsum += __shfl_xor(wsum, 8);
    wsum += __shfl_xor(wsum, 16);
    wsum += __shfl_xor(wsum, 32);
    // self contribution last (reference concat order)
    float wself = (lane < 8) ? expf(lself - mx) : 0.f;
    {
      float wA = __shfl(wself, h0);
      float wB = __shfl(wself, h3);
      if (val4) {
        f32x4 xv = *(const f32x4*)(xs + (size_t)node * HD + c0);
#pragma unroll
        for (int i = 0; i < 4; ++i)
          acc[i] += ((i < bcut) ? wA : wB) * xv[i];
      }
      wsum += __shfl(wself, h);
    }
    float denA = __shfl(wsum, h0) + 1e-16f;
    float denB = __shfl(wsum, h3) + 1e-16f;
    if (val4) {
      f32x4 gv = *(const f32x4*)(gb + c0);
      f32x4 hv;
#pragma unroll
      for (int i = 0; i < 4; ++i)
        hv[i] = acc[i] / ((i < bcut) ? denA : denB) + gv[i];
      if (writeH) *(f32x4*)(h_out + (size_t)node * HD + c0) = hv;
      pacc += hv;
    }
  }
  // cross-wave pooled reduction -> pooled[g][coff + c]
  if (val4) *(f32x4*)(&red[wv][c0]) = pacc;
  __syncthreads();
  if (wv == 0 && val4) {
    f32x4 r0 = *(const f32x4*)(&red[0][c0]);
    f32x4 r1 = *(const f32x4*)(&red[1][c0]);
    f32x4 r2 = *(const f32x4*)(&red[2][c0]);
    f32x4 r3 = *(const f32x4*)(&red[3][c0]);
    f32x4 s = (r0 + r1) + (r2 + r3);
    *(f32x4*)(pooled + (size_t)g * 800 + coff + c0) = s;
  }
}

__global__ __launch_bounds__(256) void k_gstart(const int* __restrict__ batch, int* __restrict__ gstart,
                                                int N, int G) {
  int i = blockIdx.x * 256 + threadIdx.x;
  if (i >= N) return;
  int b = batch[i];
  int pb = (i == 0) ? -1 : batch[i - 1];
  for (int g = pb + 1; g <= b; ++g) gstart[g] = i;
  if (i == N - 1) for (int g = b + 1; g <= G; ++g) gstart[g] = N;
}

extern "C" void kernel_launch(void* const* d_in, const int* in_sizes, int n_in,
                              void* d_out, int out_size, void* d_ws, size_t ws_size,
                              hipStream_t stream) {
  const float* x         = (const float*)d_in[0];
  const float* edge_attr = (const float*)d_in[1];
  const float* node_w    = (const float*)d_in[2];
  const float* node_b    = (const float*)d_in[3];
  const float* edge_w    = (const float*)d_in[4];
  const float* edge_b    = (const float*)d_in[5];
  const float* lin_w     = (const float*)d_in[6];
  const float* lin_edge_w= (const float*)d_in[7];
  const float* att_src   = (const float*)d_in[8];
  const float* att_dst   = (const float*)d_in[9];
  const float* att_edge  = (const float*)d_in[10];
  const float* gat_bias  = (const float*)d_in[11];
  const float* readout_w = (const float*)d_in[12];
  const float* readout_b = (const float*)d_in[13];
  const float* head_w1   = (const float*)d_in[14];
  const float* head_b1   = (const float*)d_in[15];
  const float* head_w2   = (const float*)d_in[16];
  const float* head_b2   = (const float*)d_in[17];
  const int*   edge_index= (const int*)d_in[18];
  const int*   batch     = (const int*)d_in[19];

  const int N = in_sizes[0] / 64;
  const int E = in_sizes[1] / 6;
  const int G = out_size / 5;
  const int* srcI = edge_index;
  const int* dstI = edge_index + E;

  char* wsb = (char*)d_ws;
  size_t o = 0;
  auto alloc = [&](size_t bytes) -> void* {
    void* p = wsb + o;
    o = (o + bytes + 255) & ~(size_t)255;
    return p;
  };
  float* h       = (float*)alloc((size_t)N * HD * 4);
  float* xs      = (float*)alloc((size_t)N * HD * 4);
  float* a_src   = (float*)alloc((size_t)N * 8 * 4);
  float* a_dst   = (float*)alloc((size_t)N * 8 * 4);
  float* aep     = (float*)alloc((size_t)NL * E * 8 * 4);
  int*   src_csr = (int*)alloc((size_t)E * 4);
  float* ae_s    = (float*)alloc((size_t)NL * N * 8 * 4);
  float* mean_ea = (float*)alloc((size_t)N * 6 * 4);
  float* we      = (float*)alloc((size_t)NL * HD * 8 * 4);
  float* wsrc    = (float*)alloc((size_t)NL * HD * 8 * 4);
  float* wdst    = (float*)alloc((size_t)NL * HD * 8 * 4);
  float* Mm      = (float*)alloc((size_t)NL * 6 * 8 * 4);
  float* cv      = (float*)alloc((size_t)NL * 8 * 4);
  int* cnt       = (int*)alloc((size_t)N * 4);
  int* cur       = (int*)alloc((size_t)N * 4);
  int* off       = (int*)alloc((size_t)(N + 1) * 4);
  int* partial   = (int*)alloc(512 * 4);
  int* eid       = (int*)alloc((size_t)E * 4);
  int* gstart    = (int*)alloc((size_t)(G + 1) * 4);
  float* pooled4 = (float*)alloc((size_t)G * 800 * 4);
  float* readouts= (float*)alloc((size_t)G * HD * 4);
  float* bsum    = (float*)alloc(HD * 4);
  // pre-split LDS-image weight buffers (u32 = 2 bf16; 7168 u32 per K-step)
  u32* nodePk    = (u32*)alloc((size_t)2 * 7168 * 4);
  u32* linPk     = (u32*)alloc((size_t)NL * 7 * 7168 * 4);
  u32* roPk      = (u32*)alloc((size_t)25 * 7168 * 4);
  u32* hw_hi     = (u32*)alloc((size_t)5 * 112 * 112 * 4);
  u32* hw_lo     = (u32*)alloc((size_t)5 * 112 * 112 * 4);
  (void)ws_size; (void)n_in;

  hipMemsetAsync(cnt, 0, (size_t)N * 4, stream);
  hipMemsetAsync(cur, 0, (size_t)N * 4, stream);

  int nb = (N + 255) / 256;
  k_hist<<<(E + 255) / 256, 256, 0, stream>>>(dstI, cnt, E);
  k_scan1<<<nb, 256, 0, stream>>>(cnt, off, partial, N);
  k_scan2<<<1, 512, 0, stream>>>(partial, nb, off, N);
  k_scan3<<<nb, 256, 0, stream>>>(off, partial, N);
  k_scatter<<<(E + 255) / 256, 256, 0, stream>>>(dstI, off, cur, eid, E);
  k_sort<<<nb, 256, 0, stream>>>(off, eid, N);
  k_meanea<<<(N + 127) / 128, 128, 0, stream>>>(edge_attr, off, eid, mean_ea, N);
  k_we2<<<(NL * HD * 8 + 255) / 256, 256, 0, stream>>>(lin_edge_w, lin_w, att_edge, att_src, att_dst,
                                                       we, wsrc, wdst);
  k_M<<<1, 256, 0, stream>>>(edge_w, edge_b, we, Mm, cv);
  k_ae_self<<<(N + 255) / 256, 256, 0, stream>>>(mean_ea, cnt, Mm, cv, ae_s, N);
  k_aep<<<(E + 255) / 256, 256, 0, stream>>>(edge_attr, eid, srcI, Mm, cv, src_csr, aep, E);

  // weight splits
  {
    k_split5<<<dim3((2 * 7168 + 255) / 256, 1), 256, 0, stream>>>(node_w, nodePk, 64, 2, 0,
                                                                  nullptr, nullptr);
    k_split5<<<dim3((7 * 7168 + 255) / 256, NL), 256, 0, stream>>>(lin_w, linPk, HD, 7, HD * HD,
                                                                   wsrc, wdst);
    k_split_ro5<<<(25 * 7168 + 255) / 256, 256, 0, stream>>>(readout_w, roPk);
    k_bsum<<<1, 256, 0, stream>>>(readout_b, bsum);
    dim3 g3((112 * 112 + 255) / 256, 5);
    k_split_hw<<<g3, 256, 0, stream>>>(head_w1, hw_hi, hw_lo);
  }

  const int gemmBlocks = (N + 63) / 64;
  k_gemm_v5<2, false><<<gemmBlocks, 256, 0, stream>>>(x, nodePk, node_b, h, nullptr, nullptr, N, 64);
  k_gstart<<<nb, 256, 0, stream>>>(batch, gstart, N, G);

  for (int l = 0; l < NL; ++l) {
    k_gemm_v5<7, true><<<gemmBlocks, 256, 0, stream>>>(h, linPk + (size_t)l * 7 * 7168,
                                                       nullptr, xs, a_src, a_dst, N, HD);
    k_aggr4<<<G, 256, 0, stream>>>(xs, a_src, a_dst, aep + (size_t)l * E * 8,
                                   ae_s + (size_t)l * N * 8, gat_bias + l * HD,
                                   off, src_csr, gstart, h, pooled4, l * HD, (l < NL - 1) ? 1 : 0);
  }
  // merged readout: readouts = pooled4 @ roW4 + sum_l b_l   (K = 800)
  k_gemm_v5<25, false><<<(G + 63) / 64, 256, 0, stream>>>(pooled4, roPk, bsum, readouts,
                                                          nullptr, nullptr, G, 800);
  {
    dim3 hg((G + 63) / 64, 5);
    k_headgemm<<<hg, 128, 0, stream>>>(readouts, hw_hi, hw_lo, head_b1, head_w2, head_b2,
                                       (float*)d_out, G);
  }
}